// Round 1
// baseline (2351.916 us; speedup 1.0000x reference)
//
#include <hip/hip_runtime.h>

#define DEV __device__ __forceinline__

constexpr int B = 16, T = 400, H = 400, V = 22000, S = 30, STEPS = 8, NG = 3;
constexpr int M  = S * B;      // 480 (slot,b) rows
constexpr int H3 = 3 * H;      // 1200
constexpr int KP = 416;        // K padded to 13*32
constexpr int VP = 22016;      // V padded to 172*128
constexpr int MP = 512;        // M padded to 4*128
constexpr int NWP = 1280;      // GRU weight rows padded to 10*128
constexpr long long PTS = (long long)S * B * STEPS * V;  // 84,480,000

typedef __attribute__((ext_vector_type(8))) short bfrag;   // 8 bf16 = 4 VGPR
typedef __attribute__((ext_vector_type(4))) float f32x4;
typedef unsigned short u16;

DEV u16 f2bf(float x) {                 // f32 -> bf16 bits, RNE
  unsigned u = __float_as_uint(x);
  u += 0x7FFFu + ((u >> 16) & 1u);
  return (u16)(u >> 16);
}
DEV float bf2f(u16 h) { return __uint_as_float(((unsigned)h) << 16); }
DEV float sigm(float x) { return 1.0f / (1.0f + __expf(-x)); }

// ---------------- init / conversion ----------------

__global__ void k_convert_emb(const float* __restrict__ emb, u16* __restrict__ ebf) {
  int i = blockIdx.x * 256 + threadIdx.x;            // VP*KP
  if (i >= VP * KP) return;
  int v = i / KP, k = i % KP;
  float val = (v < V && k < H) ? emb[(long long)v * H + k] : 0.f;
  ebf[i] = f2bf(val);
}

__global__ void k_convert_w(const float* __restrict__ Wih, const float* __restrict__ Whh,
                            u16* __restrict__ wihH, u16* __restrict__ wihL,
                            u16* __restrict__ whhH, u16* __restrict__ whhL) {
  int i = blockIdx.x * 256 + threadIdx.x;            // NWP*KP
  if (i >= NWP * KP) return;
  int n = i / KP, k = i % KP;
  float v1 = (n < H3 && k < H) ? Wih[n * H + k] : 0.f;
  u16 h1 = f2bf(v1);
  wihH[i] = h1; wihL[i] = f2bf(v1 - bf2f(h1));
  float v2 = (n < H3 && k < H) ? Whh[n * H + k] : 0.f;
  u16 h2 = f2bf(v2);
  whhH[i] = h2; whhL[i] = f2bf(v2 - bf2f(h2));
}

// dec_in for every step known ahead (teacher forcing)
__global__ void k_init_dec(const float* __restrict__ emb, const float* __restrict__ semb,
                           const int* __restrict__ tgt, float* __restrict__ dec,
                           u16* __restrict__ dH, u16* __restrict__ dL) {
  int i = blockIdx.x * 256 + threadIdx.x;            // STEPS*MP*KP
  if (i >= STEPS * MP * KP) return;
  int k = i % KP, m = (i / KP) % MP, s = i / (KP * MP);
  float val = 0.f;
  if (m < M && k < H) {
    int slot = m / B, b = m % B;
    if (s == 0) val = semb[slot * H + k];
    else        val = emb[(long long)tgt[(b * S + slot) * STEPS + (s - 1)] * H + k];
    dec[((long long)s * M + m) * H + k] = val;
  }
  u16 hi = f2bf(val);
  dH[i] = hi; dL[i] = f2bf(val - bf2f(hi));
}

__global__ void k_init_h(const float* __restrict__ ehid, float* __restrict__ h,
                         u16* __restrict__ hH, u16* __restrict__ hL) {
  int i = blockIdx.x * 256 + threadIdx.x;            // MP*KP
  if (i >= MP * KP) return;
  int k = i % KP, m = i / KP;
  float val = (m < M && k < H) ? ehid[(m % B) * H + k] : 0.f;
  if (m < M && k < H) h[m * H + k] = val;
  u16 hi = f2bf(val);
  hH[i] = hi; hL[i] = f2bf(val - bf2f(hi));
}

// ---------------- MFMA GEMM: C[M][N] = A[M][K] * Bm[N][K]^T (+bias) ----------------
// SPLIT=true: A,Bm given as hi/lo bf16 pair, 3-product compensation (~f32 accuracy).
// Block: 512 thr = 8 waves arranged 4(M)x2(N); wave tile 32x64; block tile 128x128.
template<bool SPLIT, bool BIAS>
__global__ __launch_bounds__(512) void k_mfma_gemm(
    const u16* __restrict__ Ahi, const u16* __restrict__ Alo,
    const u16* __restrict__ Bmh, const u16* __restrict__ Bml,
    const float* __restrict__ bias, float* __restrict__ C,
    int Mvalid, int Nvalid, int Cstride)
{
  __shared__ u16 BsH[128][40];                 // 32 k-halfs padded to 40 (80B rows: 2-way banks)
  __shared__ u16 BsL[SPLIT ? 128 : 1][40];
  const int tid = threadIdx.x;
  const int wave = tid >> 6, lane = tid & 63;
  const int wm = wave >> 1, wn = wave & 1;
  const int n0 = blockIdx.x * 128;
  const int m0 = blockIdx.y * 128;
  const int lrow = lane & 15;
  const int lk = (lane >> 4) << 3;             // k-group*8
  const int srow = tid >> 2;                   // staging row 0..127
  const int skoff = (tid & 3) << 3;
  f32x4 acc[2][4] = {};

  const u16* aH = Ahi + (size_t)(m0 + wm * 32 + lrow) * KP + lk;
  const u16* aL = SPLIT ? (Alo + (size_t)(m0 + wm * 32 + lrow) * KP + lk) : nullptr;
  const u16* bHp = Bmh + (size_t)(n0 + srow) * KP + skoff;
  const u16* bLp = SPLIT ? (Bml + (size_t)(n0 + srow) * KP + skoff) : nullptr;

  for (int kk = 0; kk < KP / 32; ++kk) {
    const int kb = kk * 32;
    *(bfrag*)&BsH[srow][skoff] = *(const bfrag*)(bHp + kb);
    if constexpr (SPLIT) *(bfrag*)&BsL[srow][skoff] = *(const bfrag*)(bLp + kb);
    __syncthreads();
    bfrag a0h = *(const bfrag*)(aH + kb);
    bfrag a1h = *(const bfrag*)(aH + 16 * KP + kb);
    bfrag a0l, a1l;
    if constexpr (SPLIT) {
      a0l = *(const bfrag*)(aL + kb);
      a1l = *(const bfrag*)(aL + 16 * KP + kb);
    }
#pragma unroll
    for (int nn = 0; nn < 4; ++nn) {
      const int brw = wn * 64 + nn * 16 + lrow;
      bfrag bh = *(const bfrag*)&BsH[brw][lk];
      acc[0][nn] = __builtin_amdgcn_mfma_f32_16x16x32_bf16(a0h, bh, acc[0][nn], 0, 0, 0);
      acc[1][nn] = __builtin_amdgcn_mfma_f32_16x16x32_bf16(a1h, bh, acc[1][nn], 0, 0, 0);
      if constexpr (SPLIT) {
        bfrag bl = *(const bfrag*)&BsL[brw][lk];
        acc[0][nn] = __builtin_amdgcn_mfma_f32_16x16x32_bf16(a0h, bl, acc[0][nn], 0, 0, 0);
        acc[1][nn] = __builtin_amdgcn_mfma_f32_16x16x32_bf16(a1h, bl, acc[1][nn], 0, 0, 0);
        acc[0][nn] = __builtin_amdgcn_mfma_f32_16x16x32_bf16(a0l, bh, acc[0][nn], 0, 0, 0);
        acc[1][nn] = __builtin_amdgcn_mfma_f32_16x16x32_bf16(a1l, bh, acc[1][nn], 0, 0, 0);
      }
    }
    __syncthreads();
  }
  // C/D layout: col = lane&15, row = (lane>>4)*4 + reg  [m89/m91 verified]
  const int orow = (lane >> 4) << 2, ocol = lane & 15;
#pragma unroll
  for (int am = 0; am < 2; ++am) {
#pragma unroll
    for (int nn = 0; nn < 4; ++nn) {
      const int gn = n0 + wn * 64 + nn * 16 + ocol;
      if (gn >= Nvalid) continue;
      const float badd = BIAS ? bias[gn] : 0.f;
#pragma unroll
      for (int r = 0; r < 4; ++r) {
        const int gm = m0 + wm * 32 + am * 16 + orow + r;
        if (gm < Mvalid) C[(long long)gm * Cstride + gn] = acc[am][nn][r] + badd;
      }
    }
  }
}

// ---------------- per-step elementwise / attention (f32) ----------------

__global__ void k_gru_combine(const float* __restrict__ gi, const float* __restrict__ gh,
                              float* __restrict__ h, u16* __restrict__ hH, u16* __restrict__ hL) {
  int i = blockIdx.x * 256 + threadIdx.x;            // M*H
  if (i >= M * H) return;
  int k = i % H, m = i / H;
  float ir = gi[m * H3 + k],       hr = gh[m * H3 + k];
  float iz = gi[m * H3 + H + k],   hz = gh[m * H3 + H + k];
  float in_ = gi[m * H3 + 2*H + k], hn = gh[m * H3 + 2*H + k];
  float r = sigm(ir + hr);
  float z = sigm(iz + hz);
  float n = tanhf(in_ + r * hn);
  float hv = (1.f - z) * n + z * h[i];
  h[i] = hv;                                         // in-place (elementwise dep only)
  u16 hb = f2bf(hv);
  hH[m * KP + k] = hb;
  hL[m * KP + k] = f2bf(hv - bf2f(hb));
}

// one wave per (m,t) dot: logits[m][t] = h[m] . enc[b][t]
__global__ __launch_bounds__(256) void k_attn_logits(const float* __restrict__ h,
                                                     const float* __restrict__ enc,
                                                     float* __restrict__ attn) {
  int w = (blockIdx.x * 256 + threadIdx.x) >> 6;
  int lane = threadIdx.x & 63;
  if (w >= M * T) return;
  int m = w / T, t = w % T, b = m % B;
  const float* hr = h + m * H;
  const float* er = enc + ((long long)b * T + t) * H;
  float acc = 0.f;
#pragma unroll
  for (int i = 0; i < 7; ++i) {
    int k = lane + 64 * i;
    if (k < H) acc = fmaf(hr[k], er[k], acc);
  }
#pragma unroll
  for (int off = 32; off; off >>= 1) acc += __shfl_down(acc, off);
  if (lane == 0) attn[w] = acc;
}

__global__ __launch_bounds__(256) void k_attn_softmax(float* __restrict__ attn,
                                                      const int* __restrict__ lens) {
  int m = blockIdx.x, b = m % B;
  int len = lens[b];
  __shared__ float red[256];
  float* row = attn + m * T;
  int t0 = threadIdx.x, t1 = threadIdx.x + 256;
  float v0 = (t0 < len) ? row[t0] : -1e30f;
  float v1 = (t1 < len) ? row[t1] : -1e30f;
  red[threadIdx.x] = fmaxf(v0, v1); __syncthreads();
  for (int st = 128; st; st >>= 1) {
    if (threadIdx.x < st) red[threadIdx.x] = fmaxf(red[threadIdx.x], red[threadIdx.x + st]);
    __syncthreads();
  }
  float mx = red[0]; __syncthreads();
  float e0 = (t0 < len) ? __expf(v0 - mx) : 0.f;
  float e1 = (t1 < len) ? __expf(v1 - mx) : 0.f;
  red[threadIdx.x] = e0 + e1; __syncthreads();
  for (int st = 128; st; st >>= 1) {
    if (threadIdx.x < st) red[threadIdx.x] += red[threadIdx.x + st];
    __syncthreads();
  }
  float inv = 1.f / red[0];
  row[t0] = e0 * inv;
  if (t1 < T) row[t1] = e1 * inv;
}

// context[m][k] = sum_t attn[m][t] * enc[b][t][k]
__global__ __launch_bounds__(256) void k_context(const float* __restrict__ attn,
                                                 const float* __restrict__ enc,
                                                 float* __restrict__ ctx) {
  int m = blockIdx.x, b = m % B;
  int k = threadIdx.x, k2 = k + 256;
  const float* arow = attn + m * T;
  const float* eb = enc + (long long)b * T * H;
  float a0 = 0.f, a1 = 0.f;
  for (int t = 0; t < T; ++t) {
    float a = arow[t];
    a0 = fmaf(a, eb[t * H + k], a0);
    if (k2 < H) a1 = fmaf(a, eb[t * H + k2], a1);
  }
  ctx[m * H + k] = a0;
  if (k2 < H) ctx[m * H + k2] = a1;
}

// p_gen = sigmoid([h, ctx, dec_in] . W_ratio + b) ; one wave per m
__global__ __launch_bounds__(256) void k_pgen(const float* __restrict__ h, const float* __restrict__ ctx,
                                              const float* __restrict__ dec_s,
                                              const float* __restrict__ Wr, const float* __restrict__ br,
                                              float* __restrict__ pgen) {
  int w = (blockIdx.x * 256 + threadIdx.x) >> 6;
  int lane = threadIdx.x & 63;
  if (w >= M) return;
  float acc = 0.f;
#pragma unroll
  for (int i = 0; i < 7; ++i) {
    int k = lane + 64 * i;
    if (k < H)
      acc += h[w * H + k] * Wr[k] + ctx[w * H + k] * Wr[H + k] + dec_s[w * H + k] * Wr[2 * H + k];
  }
#pragma unroll
  for (int off = 32; off; off >>= 1) acc += __shfl_down(acc, off);
  if (lane == 0) pgen[w] = sigm(acc + br[0]);
}

// online max+sum over V, then write p_gen * softmax to output row
__global__ __launch_bounds__(256) void k_vocab_softmax(const float* __restrict__ logits,
                                                       const float* __restrict__ pgen,
                                                       float* __restrict__ out, int s) {
  int m = blockIdx.x;
  const float* row = logits + (long long)m * VP;
  float mx = -1e30f, sm = 0.f;
  for (int v = threadIdx.x; v < V; v += 256) {
    float x = row[v];
    if (x > mx) { sm = sm * __expf(mx - x) + 1.f; mx = x; }
    else sm += __expf(x - mx);
  }
  __shared__ float rm[256], rs[256];
  rm[threadIdx.x] = mx; rs[threadIdx.x] = sm;
  __syncthreads();
  for (int st = 128; st; st >>= 1) {
    if (threadIdx.x < st) {
      float m1 = rm[threadIdx.x], s1 = rs[threadIdx.x];
      float m2 = rm[threadIdx.x + st], s2 = rs[threadIdx.x + st];
      float Mx = fmaxf(m1, m2);
      rs[threadIdx.x] = s1 * __expf(m1 - Mx) + s2 * __expf(m2 - Mx);
      rm[threadIdx.x] = Mx;
    }
    __syncthreads();
  }
  float Mx = rm[0];
  float scale = pgen[m] / rs[0];
  float* orow = out + ((long long)m * STEPS + s) * V;
  for (int v = threadIdx.x; v < V; v += 256) orow[v] = __expf(row[v] - Mx) * scale;
}

// p_ctx scatter: out[m,s,story[b][t]] += (1-pgen)*attn[m][t]
__global__ void k_scatter(const float* __restrict__ attn, const float* __restrict__ pgen,
                          const int* __restrict__ story, float* __restrict__ out, int s) {
  int i = blockIdx.x * 256 + threadIdx.x;            // M*T
  if (i >= M * T) return;
  int t = i % T, m = i / T, b = m % B;
  float a = attn[i];
  if (a == 0.f) return;
  int wd = story[b * T + t];
  atomicAdd(out + ((long long)m * STEPS + s) * V + wd, (1.f - pgen[m]) * a);
}

// gate = context(step0) @ W_gate^T + b_gate ; one wave per m
__global__ __launch_bounds__(256) void k_gates(const float* __restrict__ ctx,
                                               const float* __restrict__ Wg, const float* __restrict__ bg,
                                               float* __restrict__ out) {
  int w = (blockIdx.x * 256 + threadIdx.x) >> 6;
  int lane = threadIdx.x & 63;
  if (w >= M) return;
  float a0 = 0.f, a1 = 0.f, a2 = 0.f;
#pragma unroll
  for (int i = 0; i < 7; ++i) {
    int k = lane + 64 * i;
    if (k < H) {
      float c = ctx[w * H + k];
      a0 = fmaf(c, Wg[k], a0);
      a1 = fmaf(c, Wg[H + k], a1);
      a2 = fmaf(c, Wg[2 * H + k], a2);
    }
  }
#pragma unroll
  for (int off = 32; off; off >>= 1) {
    a0 += __shfl_down(a0, off);
    a1 += __shfl_down(a1, off);
    a2 += __shfl_down(a2, off);
  }
  if (lane == 0) {
    float* g = out + PTS + (long long)w * NG;
    g[0] = a0 + bg[0]; g[1] = a1 + bg[1]; g[2] = a2 + bg[2];
  }
}

// ---------------- launch ----------------

extern "C" void kernel_launch(void* const* d_in, const int* in_sizes, int n_in,
                              void* d_out, int out_size, void* d_ws, size_t ws_size,
                              hipStream_t stream) {
  (void)in_sizes; (void)n_in; (void)out_size; (void)ws_size;
  const float* emb  = (const float*)d_in[0];
  const float* Wih  = (const float*)d_in[1];
  const float* Whh  = (const float*)d_in[2];
  const float* bih  = (const float*)d_in[3];
  const float* bhh  = (const float*)d_in[4];
  const float* Wr   = (const float*)d_in[5];
  const float* br   = (const float*)d_in[6];
  const float* Wg   = (const float*)d_in[7];
  const float* bg   = (const float*)d_in[8];
  const float* semb = (const float*)d_in[9];
  const float* ehid = (const float*)d_in[10];
  const float* enc  = (const float*)d_in[11];
  const int*   lens = (const int*)d_in[12];
  const int*   story= (const int*)d_in[13];
  const int*   tgt  = (const int*)d_in[14];
  float* out = (float*)d_out;

  char* w = (char*)d_ws;
  size_t off = 0;
  auto alloc = [&](size_t n) -> void* {
    void* p = w + off;
    off = (off + n + 255) & ~(size_t)255;
    return p;
  };
  u16* ebf   = (u16*)alloc((size_t)VP * KP * 2);
  u16* wihH  = (u16*)alloc((size_t)NWP * KP * 2);
  u16* wihL  = (u16*)alloc((size_t)NWP * KP * 2);
  u16* whhH  = (u16*)alloc((size_t)NWP * KP * 2);
  u16* whhL  = (u16*)alloc((size_t)NWP * KP * 2);
  u16* decH  = (u16*)alloc((size_t)STEPS * MP * KP * 2);
  u16* decL  = (u16*)alloc((size_t)STEPS * MP * KP * 2);
  float* dec = (float*)alloc((size_t)STEPS * M * H * 4);
  float* h   = (float*)alloc((size_t)M * H * 4);
  u16* hH    = (u16*)alloc((size_t)MP * KP * 2);
  u16* hL    = (u16*)alloc((size_t)MP * KP * 2);
  float* gi  = (float*)alloc((size_t)M * H3 * 4);
  float* gh  = (float*)alloc((size_t)M * H3 * 4);
  float* attn= (float*)alloc((size_t)M * T * 4);
  float* ctx = (float*)alloc((size_t)M * H * 4);
  float* pgen= (float*)alloc((size_t)M * 4);
  float* lv  = (float*)alloc((size_t)M * VP * 4);
  // total ~86 MB

  k_convert_emb<<<VP * KP / 256, 256, 0, stream>>>(emb, ebf);
  k_convert_w<<<NWP * KP / 256, 256, 0, stream>>>(Wih, Whh, wihH, wihL, whhH, whhL);
  k_init_dec<<<STEPS * MP * KP / 256, 256, 0, stream>>>(emb, semb, tgt, dec, decH, decL);
  k_init_h<<<MP * KP / 256, 256, 0, stream>>>(ehid, h, hH, hL);

  for (int s = 0; s < STEPS; ++s) {
    const float* dec_s = dec + (size_t)s * M * H;
    // GRU pre-activations (hi/lo compensated bf16 MFMA ~ f32 accuracy)
    k_mfma_gemm<true, true><<<dim3(NWP / 128, MP / 128), 512, 0, stream>>>(
        decH + (size_t)s * MP * KP, decL + (size_t)s * MP * KP, wihH, wihL, bih, gi, M, H3, H3);
    k_mfma_gemm<true, true><<<dim3(NWP / 128, MP / 128), 512, 0, stream>>>(
        hH, hL, whhH, whhL, bhh, gh, M, H3, H3);
    k_gru_combine<<<M * H / 256, 256, 0, stream>>>(gi, gh, h, hH, hL);
    k_attn_logits<<<M * T / 4, 256, 0, stream>>>(h, enc, attn);
    k_attn_softmax<<<M, 256, 0, stream>>>(attn, lens);
    k_context<<<M, 256, 0, stream>>>(attn, enc, ctx);
    k_pgen<<<M / 4, 256, 0, stream>>>(h, ctx, dec_s, Wr, br, pgen);
    // vocab logits (plain bf16 MFMA; error budget fine)
    k_mfma_gemm<false, false><<<dim3(VP / 128, MP / 128), 512, 0, stream>>>(
        hH, nullptr, ebf, nullptr, nullptr, lv, M, V, VP);
    k_vocab_softmax<<<M, 256, 0, stream>>>(lv, pgen, out, s);
    k_scatter<<<M * T / 256, 256, 0, stream>>>(attn, pgen, story, out, s);
    if (s == 0) k_gates<<<M / 4, 256, 0, stream>>>(ctx, Wg, bg, out);
  }
}

// Round 2
// 1220.897 us; speedup vs baseline: 1.9264x; 1.9264x over previous
//
#include <hip/hip_runtime.h>

#define DEV __device__ __forceinline__

constexpr int B = 16, T = 400, H = 400, V = 22000, S = 30, STEPS = 8, NG = 3;
constexpr int M  = S * B;      // 480 (slot,b) rows
constexpr int H3 = 3 * H;      // 1200
constexpr int KP = 416;        // K padded to 13*32
constexpr int VP = 22016;      // V padded to 172*128
constexpr int MP = 512;        // M padded to 4*128
constexpr int NWP = 1280;      // GRU weight rows padded to 10*128
constexpr int NBLK = VP / 128; // 172 vocab col-blocks
constexpr long long PTS = (long long)S * B * STEPS * V;  // 84,480,000

typedef __attribute__((ext_vector_type(8))) short bfrag;   // 8 bf16 = 4 VGPR
typedef __attribute__((ext_vector_type(4))) float f32x4;
typedef unsigned short u16;

DEV u16 f2bf(float x) {                 // f32 -> bf16 bits, RNE
  unsigned u = __float_as_uint(x);
  u += 0x7FFFu + ((u >> 16) & 1u);
  return (u16)(u >> 16);
}
DEV float bf2f(u16 h) { return __uint_as_float(((unsigned)h) << 16); }
DEV float sigm(float x) { return 1.0f / (1.0f + __expf(-x)); }

// ---------------- init / conversion ----------------

__global__ void k_convert_emb(const float* __restrict__ emb, u16* __restrict__ ebf) {
  int i = blockIdx.x * 256 + threadIdx.x;            // VP*KP
  if (i >= VP * KP) return;
  int v = i / KP, k = i % KP;
  float val = (v < V && k < H) ? emb[(long long)v * H + k] : 0.f;
  ebf[i] = f2bf(val);
}

__global__ void k_convert_w(const float* __restrict__ Wih, const float* __restrict__ Whh,
                            u16* __restrict__ wihH, u16* __restrict__ wihL,
                            u16* __restrict__ whhH, u16* __restrict__ whhL) {
  int i = blockIdx.x * 256 + threadIdx.x;            // NWP*KP
  if (i >= NWP * KP) return;
  int n = i / KP, k = i % KP;
  float v1 = (n < H3 && k < H) ? Wih[n * H + k] : 0.f;
  u16 h1 = f2bf(v1);
  wihH[i] = h1; wihL[i] = f2bf(v1 - bf2f(h1));
  float v2 = (n < H3 && k < H) ? Whh[n * H + k] : 0.f;
  u16 h2 = f2bf(v2);
  whhH[i] = h2; whhL[i] = f2bf(v2 - bf2f(h2));
}

// dec_in for every step known ahead (teacher forcing)
__global__ void k_init_dec(const float* __restrict__ emb, const float* __restrict__ semb,
                           const int* __restrict__ tgt, float* __restrict__ dec,
                           u16* __restrict__ dH, u16* __restrict__ dL) {
  int i = blockIdx.x * 256 + threadIdx.x;            // STEPS*MP*KP
  if (i >= STEPS * MP * KP) return;
  int k = i % KP, m = (i / KP) % MP, s = i / (KP * MP);
  float val = 0.f;
  if (m < M && k < H) {
    int slot = m / B, b = m % B;
    if (s == 0) val = semb[slot * H + k];
    else        val = emb[(long long)tgt[(b * S + slot) * STEPS + (s - 1)] * H + k];
    dec[((long long)s * M + m) * H + k] = val;
  }
  u16 hi = f2bf(val);
  dH[i] = hi; dL[i] = f2bf(val - bf2f(hi));
}

__global__ void k_init_h(const float* __restrict__ ehid, float* __restrict__ h,
                         u16* __restrict__ hH, u16* __restrict__ hL) {
  int i = blockIdx.x * 256 + threadIdx.x;            // MP*KP
  if (i >= MP * KP) return;
  int k = i % KP, m = i / KP;
  float val = (m < M && k < H) ? ehid[(m % B) * H + k] : 0.f;
  if (m < M && k < H) h[m * H + k] = val;
  u16 hi = f2bf(val);
  hH[i] = hi; hL[i] = f2bf(val - bf2f(hi));
}

// ---------------- MFMA GEMM: C[M][N] = A[M][K] * Bm[N][K]^T (+bias) ----------------
// SPLIT: hi/lo bf16 pair, 3-product compensation (~f32 accuracy).
template<bool SPLIT, bool BIAS>
__global__ __launch_bounds__(512) void k_mfma_gemm(
    const u16* __restrict__ Ahi, const u16* __restrict__ Alo,
    const u16* __restrict__ Bmh, const u16* __restrict__ Bml,
    const float* __restrict__ bias, float* __restrict__ C,
    int Mvalid, int Nvalid, int Cstride)
{
  __shared__ u16 BsH[128][40];
  __shared__ u16 BsL[SPLIT ? 128 : 1][40];
  const int tid = threadIdx.x;
  const int wave = tid >> 6, lane = tid & 63;
  const int wm = wave >> 1, wn = wave & 1;
  const int n0 = blockIdx.x * 128;
  const int m0 = blockIdx.y * 128;
  const int lrow = lane & 15;
  const int lk = (lane >> 4) << 3;
  const int srow = tid >> 2;
  const int skoff = (tid & 3) << 3;
  f32x4 acc[2][4] = {};

  const u16* aH = Ahi + (size_t)(m0 + wm * 32 + lrow) * KP + lk;
  const u16* aL = SPLIT ? (Alo + (size_t)(m0 + wm * 32 + lrow) * KP + lk) : nullptr;
  const u16* bHp = Bmh + (size_t)(n0 + srow) * KP + skoff;
  const u16* bLp = SPLIT ? (Bml + (size_t)(n0 + srow) * KP + skoff) : nullptr;

  for (int kk = 0; kk < KP / 32; ++kk) {
    const int kb = kk * 32;
    *(bfrag*)&BsH[srow][skoff] = *(const bfrag*)(bHp + kb);
    if constexpr (SPLIT) *(bfrag*)&BsL[srow][skoff] = *(const bfrag*)(bLp + kb);
    __syncthreads();
    bfrag a0h = *(const bfrag*)(aH + kb);
    bfrag a1h = *(const bfrag*)(aH + 16 * KP + kb);
    bfrag a0l, a1l;
    if constexpr (SPLIT) {
      a0l = *(const bfrag*)(aL + kb);
      a1l = *(const bfrag*)(aL + 16 * KP + kb);
    }
#pragma unroll
    for (int nn = 0; nn < 4; ++nn) {
      const int brw = wn * 64 + nn * 16 + lrow;
      bfrag bh = *(const bfrag*)&BsH[brw][lk];
      acc[0][nn] = __builtin_amdgcn_mfma_f32_16x16x32_bf16(a0h, bh, acc[0][nn], 0, 0, 0);
      acc[1][nn] = __builtin_amdgcn_mfma_f32_16x16x32_bf16(a1h, bh, acc[1][nn], 0, 0, 0);
      if constexpr (SPLIT) {
        bfrag bl = *(const bfrag*)&BsL[brw][lk];
        acc[0][nn] = __builtin_amdgcn_mfma_f32_16x16x32_bf16(a0h, bl, acc[0][nn], 0, 0, 0);
        acc[1][nn] = __builtin_amdgcn_mfma_f32_16x16x32_bf16(a1h, bl, acc[1][nn], 0, 0, 0);
        acc[0][nn] = __builtin_amdgcn_mfma_f32_16x16x32_bf16(a0l, bh, acc[0][nn], 0, 0, 0);
        acc[1][nn] = __builtin_amdgcn_mfma_f32_16x16x32_bf16(a1l, bh, acc[1][nn], 0, 0, 0);
      }
    }
    __syncthreads();
  }
  const int orow = (lane >> 4) << 2, ocol = lane & 15;
#pragma unroll
  for (int am = 0; am < 2; ++am) {
#pragma unroll
    for (int nn = 0; nn < 4; ++nn) {
      const int gn = n0 + wn * 64 + nn * 16 + ocol;
      if (gn >= Nvalid) continue;
      const float badd = BIAS ? bias[gn] : 0.f;
#pragma unroll
      for (int r = 0; r < 4; ++r) {
        const int gm = m0 + wm * 32 + am * 16 + orow + r;
        if (gm < Mvalid) C[(long long)gm * Cstride + gn] = acc[am][nn][r] + badd;
      }
    }
  }
}

// ---------------- fused per-step attention chain ----------------
// One block per m: GRU cell -> logits -> softmax -> context -> p_gen -> (gates)
__global__ __launch_bounds__(512) void k_attn_all(
    const float* __restrict__ gi_s, const float* __restrict__ gh,
    float* __restrict__ h, u16* __restrict__ hH, u16* __restrict__ hL,
    const float* __restrict__ dec_s, const float* __restrict__ enc,
    const int* __restrict__ lens,
    const float* __restrict__ Wr, const float* __restrict__ br,
    const float* __restrict__ Wg, const float* __restrict__ bg,
    float* __restrict__ attn, float* __restrict__ pgen,
    float* __restrict__ out, int s)
{
  __shared__ float hs[H], sat[T], sctx[H], red[512];
  const int m = blockIdx.x, b = m % B;
  const int tid = threadIdx.x;
  const int len = lens[b];

  // phase 0: GRU cell (h update) -- elementwise
  if (tid < H) {
    const int k = tid;
    float ir = gi_s[m * H3 + k],         hr = gh[m * H3 + k];
    float iz = gi_s[m * H3 + H + k],     hz = gh[m * H3 + H + k];
    float in_ = gi_s[m * H3 + 2*H + k],  hn = gh[m * H3 + 2*H + k];
    float r = sigm(ir + hr);
    float z = sigm(iz + hz);
    float n = tanhf(in_ + r * hn);
    float hv = (1.f - z) * n + z * h[m * H + k];
    h[m * H + k] = hv;
    u16 hb = f2bf(hv);
    hH[m * KP + k] = hb;
    hL[m * KP + k] = f2bf(hv - bf2f(hb));
    hs[k] = hv;
  }
  __syncthreads();

  // phase 1: logits[t] = hs . enc[b][t]  (8 waves x 50 t each, lanes over k)
  const int wave = tid >> 6, lane = tid & 63;
  for (int t = wave * 50; t < wave * 50 + 50; ++t) {
    if (t >= len) { if (lane == 0) sat[t] = -1e30f; continue; }
    const float* er = enc + ((size_t)b * T + t) * H;
    float a = 0.f;
#pragma unroll
    for (int i = 0; i < 7; ++i) { int k = lane + 64 * i; if (k < H) a = fmaf(hs[k], er[k], a); }
#pragma unroll
    for (int off = 32; off; off >>= 1) a += __shfl_xor(a, off);
    if (lane == 0) sat[t] = a;
  }
  __syncthreads();

  // phase 2: softmax over T in LDS
  float v = (tid < T) ? sat[tid] : -1e30f;
  red[tid] = v; __syncthreads();
  for (int st = 256; st; st >>= 1) {
    if (tid < st) red[tid] = fmaxf(red[tid], red[tid + st]);
    __syncthreads();
  }
  float mx = red[0]; __syncthreads();
  float e = (tid < len) ? __expf(v - mx) : 0.f;
  red[tid] = e; __syncthreads();
  for (int st = 256; st; st >>= 1) {
    if (tid < st) red[tid] += red[tid + st];
    __syncthreads();
  }
  float inv = 1.f / red[0];
  __syncthreads();
  if (tid < T) { float av = e * inv; sat[tid] = av; attn[(size_t)m * T + tid] = av; }
  __syncthreads();

  // phase 3: context[k] = sum_t attn[t] * enc[b][t][k]
  if (tid < H) {
    float c = 0.f;
    for (int t = 0; t < len; ++t) c = fmaf(sat[t], enc[((size_t)b * T + t) * H + tid], c);
    sctx[tid] = c;
  }
  __syncthreads();

  // phase 4: p_gen
  float p = 0.f;
  if (tid < H) p = hs[tid] * Wr[tid] + sctx[tid] * Wr[H + tid] + dec_s[m * H + tid] * Wr[2 * H + tid];
  red[tid] = p; __syncthreads();
  for (int st = 256; st; st >>= 1) {
    if (tid < st) red[tid] += red[tid + st];
    __syncthreads();
  }
  if (tid == 0) pgen[m] = sigm(red[0] + br[0]);

  // phase 5: gates (step 0 only)
  if (s == 0) {
    for (int g = 0; g < NG; ++g) {
      __syncthreads();
      red[tid] = (tid < H) ? sctx[tid] * Wg[g * H + tid] : 0.f;
      __syncthreads();
      for (int st = 256; st; st >>= 1) {
        if (tid < st) red[tid] += red[tid + st];
        __syncthreads();
      }
      if (tid == 0) out[PTS + (long long)m * NG + g] = red[0] + bg[g];
    }
  }
}

// ---------------- vocab GEMM with fused softmax-pass-1 partials ----------------
__global__ __launch_bounds__(512) void k_vocab_gemm(
    const u16* __restrict__ Ahi, const u16* __restrict__ Bmh,
    float* __restrict__ C, float* __restrict__ pmax, float* __restrict__ psum)
{
  __shared__ u16 BsH[128][40];
  __shared__ float lpm[128][2], lps[128][2];
  const int tid = threadIdx.x;
  const int wave = tid >> 6, lane = tid & 63;
  const int wm = wave >> 1, wn = wave & 1;
  const int n0 = blockIdx.x * 128;
  const int m0 = blockIdx.y * 128;
  const int lrow = lane & 15;
  const int lk = (lane >> 4) << 3;
  const int srow = tid >> 2;
  const int skoff = (tid & 3) << 3;
  f32x4 acc[2][4] = {};

  const u16* aH = Ahi + (size_t)(m0 + wm * 32 + lrow) * KP + lk;
  const u16* bHp = Bmh + (size_t)(n0 + srow) * KP + skoff;

  for (int kk = 0; kk < KP / 32; ++kk) {
    const int kb = kk * 32;
    *(bfrag*)&BsH[srow][skoff] = *(const bfrag*)(bHp + kb);
    __syncthreads();
    bfrag a0h = *(const bfrag*)(aH + kb);
    bfrag a1h = *(const bfrag*)(aH + 16 * KP + kb);
#pragma unroll
    for (int nn = 0; nn < 4; ++nn) {
      const int brw = wn * 64 + nn * 16 + lrow;
      bfrag bh = *(const bfrag*)&BsH[brw][lk];
      acc[0][nn] = __builtin_amdgcn_mfma_f32_16x16x32_bf16(a0h, bh, acc[0][nn], 0, 0, 0);
      acc[1][nn] = __builtin_amdgcn_mfma_f32_16x16x32_bf16(a1h, bh, acc[1][nn], 0, 0, 0);
    }
    __syncthreads();
  }

  const int orow = (lane >> 4) << 2, ocol = lane & 15;
  // write logits tile
#pragma unroll
  for (int am = 0; am < 2; ++am) {
#pragma unroll
    for (int nn = 0; nn < 4; ++nn) {
      const int gn = n0 + wn * 64 + nn * 16 + ocol;
      if (gn >= V) continue;
#pragma unroll
      for (int r = 0; r < 4; ++r) {
        const int gm = m0 + wm * 32 + am * 16 + orow + r;
        if (gm < M) C[(long long)gm * VP + gn] = acc[am][nn][r];
      }
    }
  }
  // per-row (max, sumexp) partials over this block's 128 cols
#pragma unroll
  for (int am = 0; am < 2; ++am) {
#pragma unroll
    for (int r = 0; r < 4; ++r) {
      float vv[4]; bool ok[4];
      float mxv = -1e30f;
#pragma unroll
      for (int nn = 0; nn < 4; ++nn) {
        const int gn = n0 + wn * 64 + nn * 16 + ocol;
        ok[nn] = gn < V;
        vv[nn] = ok[nn] ? acc[am][nn][r] : -1e30f;
        mxv = fmaxf(mxv, vv[nn]);
      }
#pragma unroll
      for (int d = 1; d < 16; d <<= 1) mxv = fmaxf(mxv, __shfl_xor(mxv, d));
      float se = 0.f;
#pragma unroll
      for (int nn = 0; nn < 4; ++nn) if (ok[nn]) se += __expf(vv[nn] - mxv);
#pragma unroll
      for (int d = 1; d < 16; d <<= 1) se += __shfl_xor(se, d);
      if ((lane & 15) == 0) {
        const int rl = wm * 32 + am * 16 + orow + r;
        lpm[rl][wn] = mxv; lps[rl][wn] = se;
      }
    }
  }
  __syncthreads();
  if (tid < 128) {
    const int gm = m0 + tid;
    if (gm < M) {
      float m0v = lpm[tid][0], m1v = lpm[tid][1];
      float Mx = fmaxf(m0v, m1v);
      float Sv = lps[tid][0] * __expf(m0v - Mx) + lps[tid][1] * __expf(m1v - Mx);
      pmax[(size_t)gm * NBLK + blockIdx.x] = Mx;
      psum[(size_t)gm * NBLK + blockIdx.x] = Sv;
    }
  }
}

// ---------------- final: combine partials, write p_gen*softmax, scatter p_ctx ----------------
__global__ __launch_bounds__(256) void k_vocab_out(
    const float* __restrict__ lv, const float* __restrict__ pmax,
    const float* __restrict__ psum, const float* __restrict__ pgen,
    const float* __restrict__ attn, const int* __restrict__ story,
    float* __restrict__ out, int s)
{
  const int m = blockIdx.x, b = m % B, tid = threadIdx.x;
  __shared__ float rm[256], rs[256];
  float mxv = -1e30f, sv = 0.f;
  if (tid < NBLK) { mxv = pmax[(size_t)m * NBLK + tid]; sv = psum[(size_t)m * NBLK + tid]; }
  rm[tid] = mxv; rs[tid] = sv; __syncthreads();
  for (int st = 128; st; st >>= 1) {
    if (tid < st) {
      float m1 = rm[tid], m2 = rm[tid + st];
      float Mx = fmaxf(m1, m2);
      rs[tid] = rs[tid] * __expf(m1 - Mx) + rs[tid + st] * __expf(m2 - Mx);
      rm[tid] = Mx;
    }
    __syncthreads();
  }
  const float Mx = rm[0];
  const float pg = pgen[m];
  const float scale = pg / rs[0];
  const float* row = lv + (size_t)m * VP;
  float* orow = out + ((size_t)m * STEPS + s) * V;
  for (int v = tid; v < V; v += 256) orow[v] = __expf(row[v] - Mx) * scale;
  __syncthreads();
  const float om = 1.f - pg;
  for (int t = tid; t < T; t += 256) {
    float a = attn[(size_t)m * T + t];
    if (a != 0.f) atomicAdd(orow + story[b * T + t], om * a);
  }
}

// ---------------- launch ----------------

extern "C" void kernel_launch(void* const* d_in, const int* in_sizes, int n_in,
                              void* d_out, int out_size, void* d_ws, size_t ws_size,
                              hipStream_t stream) {
  (void)in_sizes; (void)n_in; (void)out_size; (void)ws_size;
  const float* emb  = (const float*)d_in[0];
  const float* Wih  = (const float*)d_in[1];
  const float* Whh  = (const float*)d_in[2];
  const float* bih  = (const float*)d_in[3];
  const float* bhh  = (const float*)d_in[4];
  const float* Wr   = (const float*)d_in[5];
  const float* br   = (const float*)d_in[6];
  const float* Wg   = (const float*)d_in[7];
  const float* bg   = (const float*)d_in[8];
  const float* semb = (const float*)d_in[9];
  const float* ehid = (const float*)d_in[10];
  const float* enc  = (const float*)d_in[11];
  const int*   lens = (const int*)d_in[12];
  const int*   story= (const int*)d_in[13];
  const int*   tgt  = (const int*)d_in[14];
  float* out = (float*)d_out;

  char* w = (char*)d_ws;
  size_t off = 0;
  auto alloc = [&](size_t n) -> void* {
    void* p = w + off;
    off = (off + n + 255) & ~(size_t)255;
    return p;
  };
  u16* ebf   = (u16*)alloc((size_t)VP * KP * 2);
  u16* wihH  = (u16*)alloc((size_t)NWP * KP * 2);
  u16* wihL  = (u16*)alloc((size_t)NWP * KP * 2);
  u16* whhH  = (u16*)alloc((size_t)NWP * KP * 2);
  u16* whhL  = (u16*)alloc((size_t)NWP * KP * 2);
  u16* decH  = (u16*)alloc((size_t)STEPS * MP * KP * 2);
  u16* decL  = (u16*)alloc((size_t)STEPS * MP * KP * 2);
  float* dec = (float*)alloc((size_t)STEPS * M * H * 4);
  float* h   = (float*)alloc((size_t)M * H * 4);
  u16* hH    = (u16*)alloc((size_t)MP * KP * 2);
  u16* hL    = (u16*)alloc((size_t)MP * KP * 2);
  float* gi  = (float*)alloc((size_t)STEPS * MP * H3 * 4);
  float* gh  = (float*)alloc((size_t)M * H3 * 4);
  float* attn= (float*)alloc((size_t)M * T * 4);
  float* pgen= (float*)alloc((size_t)M * 4);
  float* lv  = (float*)alloc((size_t)M * VP * 4);
  float* pmx = (float*)alloc((size_t)MP * NBLK * 4);
  float* psm = (float*)alloc((size_t)MP * NBLK * 4);
  // total ~104 MB (ws ~1 GB per harness poison size)

  k_convert_emb<<<VP * KP / 256, 256, 0, stream>>>(emb, ebf);
  k_convert_w<<<NWP * KP / 256, 256, 0, stream>>>(Wih, Whh, wihH, wihL, whhH, whhL);
  k_init_dec<<<STEPS * MP * KP / 256, 256, 0, stream>>>(emb, semb, tgt, dec, decH, decL);
  k_init_h<<<MP * KP / 256, 256, 0, stream>>>(ehid, h, hH, hL);
  // all-steps gi = dec @ Wih^T + bih  (batched, 320 blocks)
  k_mfma_gemm<true, true><<<dim3(NWP / 128, STEPS * MP / 128), 512, 0, stream>>>(
      decH, decL, wihH, wihL, bih, gi, STEPS * MP, H3, H3);

  for (int s = 0; s < STEPS; ++s) {
    const float* dec_s = dec + (size_t)s * M * H;
    const float* gi_s  = gi + (size_t)s * MP * H3;
    k_mfma_gemm<true, true><<<dim3(NWP / 128, MP / 128), 512, 0, stream>>>(
        hH, hL, whhH, whhL, bhh, gh, M, H3, H3);
    k_attn_all<<<M, 512, 0, stream>>>(gi_s, gh, h, hH, hL, dec_s, enc, lens,
                                      Wr, br, Wg, bg, attn, pgen, out, s);
    k_vocab_gemm<<<dim3(VP / 128, MP / 128), 512, 0, stream>>>(hH, ebf, lv, pmx, psm);
    k_vocab_out<<<M, 256, 0, stream>>>(lv, pmx, psm, pgen, attn, story, out, s);
  }
}

// Round 3
// 1047.864 us; speedup vs baseline: 2.2445x; 1.1651x over previous
//
#include <hip/hip_runtime.h>

#define DEV __device__ __forceinline__

constexpr int B = 16, T = 400, H = 400, V = 22000, S = 30, STEPS = 8, NG = 3;
constexpr int M  = S * B;      // 480 (slot,b) rows
constexpr int H3 = 3 * H;      // 1200
constexpr int KP = 416;        // K padded to 13*32
constexpr int VP = 22016;      // V padded to 172*128
constexpr int MP = 512;        // M padded to 4*128
constexpr int NWP = 1280;      // GRU weight rows padded
constexpr int NBLK = VP / 128; // 172 vocab col-blocks
constexpr long long PTS = (long long)S * B * STEPS * V;  // 84,480,000

typedef __attribute__((ext_vector_type(8))) short bfrag;
typedef __attribute__((ext_vector_type(4))) float f32x4;
typedef unsigned short u16;

DEV u16 f2bf(float x) {
  unsigned u = __float_as_uint(x);
  u += 0x7FFFu + ((u >> 16) & 1u);
  return (u16)(u >> 16);
}
DEV float bf2f(u16 h) { return __uint_as_float(((unsigned)h) << 16); }
DEV float sigm(float x) { return 1.0f / (1.0f + __expf(-x)); }

// ---------------- init / conversion ----------------

__global__ void k_convert_emb(const float* __restrict__ emb, u16* __restrict__ ebf) {
  int i = blockIdx.x * 256 + threadIdx.x;
  if (i >= VP * KP) return;
  int v = i / KP, k = i % KP;
  float val = (v < V && k < H) ? emb[(long long)v * H + k] : 0.f;
  ebf[i] = f2bf(val);
}

__global__ void k_convert_w(const float* __restrict__ Wih, const float* __restrict__ Whh,
                            u16* __restrict__ wihH, u16* __restrict__ wihL,
                            u16* __restrict__ whhH, u16* __restrict__ whhL) {
  int i = blockIdx.x * 256 + threadIdx.x;
  if (i >= NWP * KP) return;
  int n = i / KP, k = i % KP;
  float v1 = (n < H3 && k < H) ? Wih[n * H + k] : 0.f;
  u16 h1 = f2bf(v1);
  wihH[i] = h1; wihL[i] = f2bf(v1 - bf2f(h1));
  float v2 = (n < H3 && k < H) ? Whh[n * H + k] : 0.f;
  u16 h2 = f2bf(v2);
  whhH[i] = h2; whhL[i] = f2bf(v2 - bf2f(h2));
}

__global__ void k_init_dec(const float* __restrict__ emb, const float* __restrict__ semb,
                           const int* __restrict__ tgt, float* __restrict__ dec,
                           u16* __restrict__ dH, u16* __restrict__ dL) {
  int i = blockIdx.x * 256 + threadIdx.x;
  if (i >= STEPS * MP * KP) return;
  int k = i % KP, m = (i / KP) % MP, s = i / (KP * MP);
  float val = 0.f;
  if (m < M && k < H) {
    int slot = m / B, b = m % B;
    if (s == 0) val = semb[slot * H + k];
    else        val = emb[(long long)tgt[(b * S + slot) * STEPS + (s - 1)] * H + k];
    dec[((long long)s * M + m) * H + k] = val;
  }
  u16 hi = f2bf(val);
  dH[i] = hi; dL[i] = f2bf(val - bf2f(hi));
}

__global__ void k_init_h(const float* __restrict__ ehid, float* __restrict__ h,
                         u16* __restrict__ hH, u16* __restrict__ hL) {
  int i = blockIdx.x * 256 + threadIdx.x;
  if (i >= MP * KP) return;
  int k = i % KP, m = i / KP;
  float val = (m < M && k < H) ? ehid[(m % B) * H + k] : 0.f;
  if (m < M && k < H) h[m * H + k] = val;
  u16 hi = f2bf(val);
  hH[i] = hi; hL[i] = f2bf(val - bf2f(hi));
}

// ---------------- 64x64-tile SPLIT GEMM (GRU pre-activations) ----------------
// C[M][N] = A[M][K] * Bm[N][K]^T + bias, hi/lo 3-MFMA compensation.
__global__ __launch_bounds__(256) void k_gemm64s(
    const u16* __restrict__ Ahi, const u16* __restrict__ Alo,
    const u16* __restrict__ Bmh, const u16* __restrict__ Bml,
    const float* __restrict__ bias, float* __restrict__ C,
    int Mvalid, int Nvalid, int Cstride)
{
  __shared__ u16 BsH[64][40], BsL[64][40];
  const int tid = threadIdx.x;
  const int wave = tid >> 6, lane = tid & 63;
  const int wm = wave >> 1, wn = wave & 1;
  const int n0 = blockIdx.x * 64;
  const int m0 = blockIdx.y * 64;
  const int lrow = lane & 15;
  const int lk = (lane >> 4) << 3;
  const int srow = tid >> 2;
  const int skoff = (tid & 3) << 3;
  f32x4 acc[2][2] = {};

  const u16* aH = Ahi + (size_t)(m0 + wm * 32 + lrow) * KP + lk;
  const u16* aL = Alo + (size_t)(m0 + wm * 32 + lrow) * KP + lk;
  const u16* bHp = Bmh + (size_t)(n0 + srow) * KP + skoff;
  const u16* bLp = Bml + (size_t)(n0 + srow) * KP + skoff;

  for (int kk = 0; kk < KP / 32; ++kk) {
    const int kb = kk * 32;
    *(bfrag*)&BsH[srow][skoff] = *(const bfrag*)(bHp + kb);
    *(bfrag*)&BsL[srow][skoff] = *(const bfrag*)(bLp + kb);
    __syncthreads();
    bfrag a0h = *(const bfrag*)(aH + kb);
    bfrag a1h = *(const bfrag*)(aH + 16 * KP + kb);
    bfrag a0l = *(const bfrag*)(aL + kb);
    bfrag a1l = *(const bfrag*)(aL + 16 * KP + kb);
#pragma unroll
    for (int nn = 0; nn < 2; ++nn) {
      const int brw = wn * 32 + nn * 16 + lrow;
      bfrag bh = *(const bfrag*)&BsH[brw][lk];
      bfrag bl = *(const bfrag*)&BsL[brw][lk];
      acc[0][nn] = __builtin_amdgcn_mfma_f32_16x16x32_bf16(a0h, bh, acc[0][nn], 0, 0, 0);
      acc[1][nn] = __builtin_amdgcn_mfma_f32_16x16x32_bf16(a1h, bh, acc[1][nn], 0, 0, 0);
      acc[0][nn] = __builtin_amdgcn_mfma_f32_16x16x32_bf16(a0h, bl, acc[0][nn], 0, 0, 0);
      acc[1][nn] = __builtin_amdgcn_mfma_f32_16x16x32_bf16(a1h, bl, acc[1][nn], 0, 0, 0);
      acc[0][nn] = __builtin_amdgcn_mfma_f32_16x16x32_bf16(a0l, bh, acc[0][nn], 0, 0, 0);
      acc[1][nn] = __builtin_amdgcn_mfma_f32_16x16x32_bf16(a1l, bh, acc[1][nn], 0, 0, 0);
    }
    __syncthreads();
  }
  const int orow = (lane >> 4) << 2, ocol = lane & 15;
#pragma unroll
  for (int am = 0; am < 2; ++am) {
#pragma unroll
    for (int nn = 0; nn < 2; ++nn) {
      const int gn = n0 + wn * 32 + nn * 16 + ocol;
      if (gn >= Nvalid) continue;
      const float badd = bias[gn];
#pragma unroll
      for (int r = 0; r < 4; ++r) {
        const int gm = m0 + wm * 32 + am * 16 + orow + r;
        if (gm < Mvalid) C[(long long)gm * Cstride + gn] = acc[am][nn][r] + badd;
      }
    }
  }
}

// ---------------- fused per-step attention chain, 2 slots (same b) per block ----------------
__global__ __launch_bounds__(512) void k_attn_all(
    const float* __restrict__ gi_s, const float* __restrict__ gh,
    float* __restrict__ h, u16* __restrict__ hH, u16* __restrict__ hL,
    const float* __restrict__ dec_s, const float* __restrict__ enc,
    const int* __restrict__ lens,
    const float* __restrict__ Wr, const float* __restrict__ br,
    const float* __restrict__ Wg, const float* __restrict__ bg,
    float* __restrict__ attn, float* __restrict__ pgen,
    float* __restrict__ out, int s)
{
  __shared__ float hs[2][H], sat[2][T], sctx[2][H], red8[8];
  const int bi = blockIdx.x;
  const int b = bi % B;
  const int s0 = (bi / B) * 2;
  const int mm[2] = { s0 * B + b, (s0 + 1) * B + b };
  const int tid = threadIdx.x;
  const int wave = tid >> 6, lane = tid & 63;
  const int len = lens[b];

  // phase 0: GRU cell for both rows
#pragma unroll
  for (int r = 0; r < 2; ++r) {
    if (tid < H) {
      const int m = mm[r], k = tid;
      float ir = gi_s[m * H3 + k],         hr = gh[m * H3 + k];
      float iz = gi_s[m * H3 + H + k],     hz = gh[m * H3 + H + k];
      float in_ = gi_s[m * H3 + 2*H + k],  hn = gh[m * H3 + 2*H + k];
      float rr = sigm(ir + hr);
      float z = sigm(iz + hz);
      float n = tanhf(in_ + rr * hn);
      float hv = (1.f - z) * n + z * h[m * H + k];
      h[m * H + k] = hv;
      u16 hb = f2bf(hv);
      hH[m * KP + k] = hb;
      hL[m * KP + k] = f2bf(hv - bf2f(hb));
      hs[r][k] = hv;
    }
  }
  __syncthreads();

  // phase 1: logits for both rows; each enc load feeds 2 FMAs
  for (int t = wave * 50; t < wave * 50 + 50; ++t) {
    if (t >= len) { if (lane == 0) { sat[0][t] = -1e30f; sat[1][t] = -1e30f; } continue; }
    const float* er = enc + ((size_t)b * T + t) * H;
    float a0 = 0.f, a1 = 0.f;
#pragma unroll
    for (int i = 0; i < 7; ++i) {
      int k = lane + 64 * i;
      if (k < H) { float ev = er[k]; a0 = fmaf(hs[0][k], ev, a0); a1 = fmaf(hs[1][k], ev, a1); }
    }
#pragma unroll
    for (int off = 32; off; off >>= 1) { a0 += __shfl_xor(a0, off); a1 += __shfl_xor(a1, off); }
    if (lane == 0) { sat[0][t] = a0; sat[1][t] = a1; }
  }
  __syncthreads();

  // phase 2: softmax per row (wave-shfl + 8-slot LDS combine)
#pragma unroll
  for (int r = 0; r < 2; ++r) {
    float v = (tid < T) ? sat[r][tid] : -1e30f;
    float wv = v;
#pragma unroll
    for (int off = 32; off; off >>= 1) wv = fmaxf(wv, __shfl_xor(wv, off));
    if (lane == 0) red8[wave] = wv;
    __syncthreads();
    float mx = red8[0];
#pragma unroll
    for (int j = 1; j < 8; ++j) mx = fmaxf(mx, red8[j]);
    __syncthreads();
    float e = (tid < len) ? __expf(v - mx) : 0.f;
    float ws = e;
#pragma unroll
    for (int off = 32; off; off >>= 1) ws += __shfl_xor(ws, off);
    if (lane == 0) red8[wave] = ws;
    __syncthreads();
    float sm = 0.f;
#pragma unroll
    for (int j = 0; j < 8; ++j) sm += red8[j];
    float inv = 1.f / sm;
    __syncthreads();
    if (tid < T) {
      float av = e * inv;
      sat[r][tid] = av;
      attn[(size_t)mm[r] * T + tid] = av;
    }
  }
  __syncthreads();

  // phase 3: context for both rows; each enc load feeds 2 FMAs
  if (tid < H) {
    float c0 = 0.f, c1 = 0.f;
    const float* eb = enc + (size_t)b * T * H + tid;
    for (int t = 0; t < len; ++t) {
      float ev = eb[(size_t)t * H];
      c0 = fmaf(sat[0][t], ev, c0);
      c1 = fmaf(sat[1][t], ev, c1);
    }
    sctx[0][tid] = c0; sctx[1][tid] = c1;
  }
  __syncthreads();

  // phase 4: p_gen (waves 0,1) and gates (waves 2..7, step 0 only) via wave reductions
  if (wave < 2) {
    const int r = wave, m = mm[r];
    float p = 0.f;
#pragma unroll
    for (int i = 0; i < 7; ++i) {
      int k = lane + 64 * i;
      if (k < H)
        p += hs[r][k] * Wr[k] + sctx[r][k] * Wr[H + k] + dec_s[m * H + k] * Wr[2 * H + k];
    }
#pragma unroll
    for (int off = 32; off; off >>= 1) p += __shfl_xor(p, off);
    if (lane == 0) pgen[m] = sigm(p + br[0]);
  } else if (s == 0) {
    const int idx = wave - 2;            // 0..5 -> (r, g)
    const int r = idx / NG, g = idx % NG;
    float a = 0.f;
#pragma unroll
    for (int i = 0; i < 7; ++i) {
      int k = lane + 64 * i;
      if (k < H) a = fmaf(sctx[r][k], Wg[g * H + k], a);
    }
#pragma unroll
    for (int off = 32; off; off >>= 1) a += __shfl_xor(a, off);
    if (lane == 0) out[PTS + (long long)mm[r] * NG + g] = a + bg[g];
  }
}

// ---------------- vocab GEMM: writes exp(logit - blockmax) as bf16 + (max,sum) partials ----------------
__global__ __launch_bounds__(512) void k_vocab_gemm(
    const u16* __restrict__ Ahi, const u16* __restrict__ Bmh,
    u16* __restrict__ ebuf, float* __restrict__ pmax, float* __restrict__ psum)
{
  __shared__ u16 BsH[128][40];
  __shared__ float lpm[128][2], lps[128][2], bmax[128];
  const int tid = threadIdx.x;
  const int wave = tid >> 6, lane = tid & 63;
  const int wm = wave >> 1, wn = wave & 1;
  const int n0 = blockIdx.x * 128;
  const int m0 = blockIdx.y * 128;
  const int lrow = lane & 15;
  const int lk = (lane >> 4) << 3;
  const int srow = tid >> 2;
  const int skoff = (tid & 3) << 3;
  f32x4 acc[2][4] = {};

  const u16* aH = Ahi + (size_t)(m0 + wm * 32 + lrow) * KP + lk;
  const u16* bHp = Bmh + (size_t)(n0 + srow) * KP + skoff;

  for (int kk = 0; kk < KP / 32; ++kk) {
    const int kb = kk * 32;
    *(bfrag*)&BsH[srow][skoff] = *(const bfrag*)(bHp + kb);
    __syncthreads();
    bfrag a0h = *(const bfrag*)(aH + kb);
    bfrag a1h = *(const bfrag*)(aH + 16 * KP + kb);
#pragma unroll
    for (int nn = 0; nn < 4; ++nn) {
      const int brw = wn * 64 + nn * 16 + lrow;
      bfrag bh = *(const bfrag*)&BsH[brw][lk];
      acc[0][nn] = __builtin_amdgcn_mfma_f32_16x16x32_bf16(a0h, bh, acc[0][nn], 0, 0, 0);
      acc[1][nn] = __builtin_amdgcn_mfma_f32_16x16x32_bf16(a1h, bh, acc[1][nn], 0, 0, 0);
    }
    __syncthreads();
  }

  const int orow = (lane >> 4) << 2, ocol = lane & 15;
  // half-block (64-col) max per row
#pragma unroll
  for (int am = 0; am < 2; ++am) {
#pragma unroll
    for (int r = 0; r < 4; ++r) {
      float mxv = -1e30f;
#pragma unroll
      for (int nn = 0; nn < 4; ++nn) {
        const int gn = n0 + wn * 64 + nn * 16 + ocol;
        if (gn < V) mxv = fmaxf(mxv, acc[am][nn][r]);
      }
#pragma unroll
      for (int d = 1; d < 16; d <<= 1) mxv = fmaxf(mxv, __shfl_xor(mxv, d));
      if ((lane & 15) == 0) lpm[wm * 32 + am * 16 + orow + r][wn] = mxv;
    }
  }
  __syncthreads();
  if (tid < 128) bmax[tid] = fmaxf(lpm[tid][0], lpm[tid][1]);
  __syncthreads();
  // e = exp(v - blockmax): write bf16, accumulate sums
#pragma unroll
  for (int am = 0; am < 2; ++am) {
#pragma unroll
    for (int r = 0; r < 4; ++r) {
      const int rl = wm * 32 + am * 16 + orow + r;
      const int gm = m0 + rl;
      const float bm = bmax[rl];
      float se = 0.f;
#pragma unroll
      for (int nn = 0; nn < 4; ++nn) {
        const int gn = n0 + wn * 64 + nn * 16 + ocol;
        if (gn < V) {
          float e = __expf(acc[am][nn][r] - bm);
          se += e;
          if (gm < M) ebuf[(size_t)gm * VP + gn] = f2bf(e);
        }
      }
#pragma unroll
      for (int d = 1; d < 16; d <<= 1) se += __shfl_xor(se, d);
      if ((lane & 15) == 0) lps[rl][wn] = se;
    }
  }
  __syncthreads();
  if (tid < 128) {
    const int gm = m0 + tid;
    if (gm < M) {
      pmax[(size_t)gm * NBLK + blockIdx.x] = bmax[tid];
      psum[(size_t)gm * NBLK + blockIdx.x] = lps[tid][0] + lps[tid][1];
    }
  }
}

// ---------------- final: combine partials, scale bf16 e-values, scatter p_ctx ----------------
__global__ __launch_bounds__(512) void k_vocab_out(
    const u16* __restrict__ ebuf, const float* __restrict__ pmax,
    const float* __restrict__ psum, const float* __restrict__ pgen,
    const float* __restrict__ attn, const int* __restrict__ story,
    float* __restrict__ out, int s)
{
  const int m = blockIdx.x, b = m % B, tid = threadIdx.x;
  const int wave = tid >> 6, lane = tid & 63;
  __shared__ float fact[NBLK], red8[8];
  float pm = (tid < NBLK) ? pmax[(size_t)m * NBLK + tid] : -1e30f;
  float wv = pm;
#pragma unroll
  for (int off = 32; off; off >>= 1) wv = fmaxf(wv, __shfl_xor(wv, off));
  if (lane == 0) red8[wave] = wv;
  __syncthreads();
  float Mx = red8[0];
#pragma unroll
  for (int j = 1; j < 8; ++j) Mx = fmaxf(Mx, red8[j]);
  __syncthreads();
  float sv = (tid < NBLK) ? psum[(size_t)m * NBLK + tid] * __expf(pm - Mx) : 0.f;
  float ws = sv;
#pragma unroll
  for (int off = 32; off; off >>= 1) ws += __shfl_xor(ws, off);
  if (lane == 0) red8[wave] = ws;
  __syncthreads();
  float Sv = 0.f;
#pragma unroll
  for (int j = 0; j < 8; ++j) Sv += red8[j];
  const float pg = pgen[m];
  const float scale = pg / Sv;
  if (tid < NBLK) fact[tid] = __expf(pm - Mx) * scale;
  __syncthreads();

  const u16* erow = ebuf + (size_t)m * VP;
  float* orow = out + ((size_t)m * STEPS + s) * V;
  for (int v = tid; v < V; v += 512) orow[v] = bf2f(erow[v]) * fact[v >> 7];
  __syncthreads();
  const float om = 1.f - pg;
  for (int t = tid; t < T; t += 512) {
    float a = attn[(size_t)m * T + t];
    if (a != 0.f) atomicAdd(orow + story[b * T + t], om * a);
  }
}

// ---------------- launch ----------------

extern "C" void kernel_launch(void* const* d_in, const int* in_sizes, int n_in,
                              void* d_out, int out_size, void* d_ws, size_t ws_size,
                              hipStream_t stream) {
  (void)in_sizes; (void)n_in; (void)out_size; (void)ws_size;
  const float* emb  = (const float*)d_in[0];
  const float* Wih  = (const float*)d_in[1];
  const float* Whh  = (const float*)d_in[2];
  const float* bih  = (const float*)d_in[3];
  const float* bhh  = (const float*)d_in[4];
  const float* Wr   = (const float*)d_in[5];
  const float* br   = (const float*)d_in[6];
  const float* Wg   = (const float*)d_in[7];
  const float* bg   = (const float*)d_in[8];
  const float* semb = (const float*)d_in[9];
  const float* ehid = (const float*)d_in[10];
  const float* enc  = (const float*)d_in[11];
  const int*   lens = (const int*)d_in[12];
  const int*   story= (const int*)d_in[13];
  const int*   tgt  = (const int*)d_in[14];
  float* out = (float*)d_out;

  char* w = (char*)d_ws;
  size_t off = 0;
  auto alloc = [&](size_t n) -> void* {
    void* p = w + off;
    off = (off + n + 255) & ~(size_t)255;
    return p;
  };
  u16* ebf   = (u16*)alloc((size_t)VP * KP * 2);
  u16* wihH  = (u16*)alloc((size_t)NWP * KP * 2);
  u16* wihL  = (u16*)alloc((size_t)NWP * KP * 2);
  u16* whhH  = (u16*)alloc((size_t)NWP * KP * 2);
  u16* whhL  = (u16*)alloc((size_t)NWP * KP * 2);
  u16* decH  = (u16*)alloc((size_t)STEPS * MP * KP * 2);
  u16* decL  = (u16*)alloc((size_t)STEPS * MP * KP * 2);
  float* dec = (float*)alloc((size_t)STEPS * M * H * 4);
  float* h   = (float*)alloc((size_t)M * H * 4);
  u16* hH    = (u16*)alloc((size_t)MP * KP * 2);
  u16* hL    = (u16*)alloc((size_t)MP * KP * 2);
  float* gi  = (float*)alloc((size_t)STEPS * MP * H3 * 4);
  float* gh  = (float*)alloc((size_t)M * H3 * 4);
  float* attn= (float*)alloc((size_t)M * T * 4);
  float* pgen= (float*)alloc((size_t)M * 4);
  u16* ebuf  = (u16*)alloc((size_t)MP * VP * 2);
  float* pmx = (float*)alloc((size_t)MP * NBLK * 4);
  float* psm = (float*)alloc((size_t)MP * NBLK * 4);

  k_convert_emb<<<VP * KP / 256, 256, 0, stream>>>(emb, ebf);
  k_convert_w<<<NWP * KP / 256, 256, 0, stream>>>(Wih, Whh, wihH, wihL, whhH, whhL);
  k_init_dec<<<STEPS * MP * KP / 256, 256, 0, stream>>>(emb, semb, tgt, dec, decH, decL);
  k_init_h<<<MP * KP / 256, 256, 0, stream>>>(ehid, h, hH, hL);
  // all-steps gi = dec @ Wih^T + bih (batched, 1216 blocks)
  k_gemm64s<<<dim3((H3 + 63) / 64, STEPS * MP / 64), 256, 0, stream>>>(
      decH, decL, wihH, wihL, bih, gi, STEPS * MP, H3, H3);

  for (int s = 0; s < STEPS; ++s) {
    const float* dec_s = dec + (size_t)s * M * H;
    const float* gi_s  = gi + (size_t)s * MP * H3;
    k_gemm64s<<<dim3((H3 + 63) / 64, (M + 63) / 64), 256, 0, stream>>>(
        hH, hL, whhH, whhL, bhh, gh, M, H3, H3);
    k_attn_all<<<M / 2, 512, 0, stream>>>(gi_s, gh, h, hH, hL, dec_s, enc, lens,
                                          Wr, br, Wg, bg, attn, pgen, out, s);
    k_vocab_gemm<<<dim3(VP / 128, MP / 128), 512, 0, stream>>>(hH, ebf, ebuf, pmx, psm);
    k_vocab_out<<<M, 512, 0, stream>>>(ebuf, pmx, psm, pgen, attn, story, out, s);
  }
}

// Round 4
// 959.803 us; speedup vs baseline: 2.4504x; 1.0917x over previous
//
#include <hip/hip_runtime.h>

#define DEV __device__ __forceinline__

constexpr int B = 16, T = 400, H = 400, V = 22000, S = 30, STEPS = 8, NG = 3;
constexpr int M  = S * B;      // 480 (slot,b) rows
constexpr int H3 = 3 * H;      // 1200
constexpr int KP = 416;        // K padded to 13*32
constexpr int VP = 22016;      // V padded to 172*128
constexpr int MP = 512;        // M padded to 4*128
constexpr int NWP = 1280;      // GRU weight rows padded
constexpr int NBLK = VP / 128; // 172 vocab col-blocks
constexpr long long PTS = (long long)S * B * STEPS * V;  // 84,480,000

typedef __attribute__((ext_vector_type(8))) short bfrag;
typedef __attribute__((ext_vector_type(4))) float f32x4;
typedef unsigned short u16;

DEV u16 f2bf(float x) {
  unsigned u = __float_as_uint(x);
  u += 0x7FFFu + ((u >> 16) & 1u);
  return (u16)(u >> 16);
}
DEV float bf2f(u16 h) { return __uint_as_float(((unsigned)h) << 16); }
DEV float sigm(float x) { return 1.0f / (1.0f + __expf(-x)); }

// async global->LDS, 16B per lane; LDS dest = wave-uniform base + lane*16
DEV void gload16(const u16* g, u16* l) {
  __builtin_amdgcn_global_load_lds(
      (const __attribute__((address_space(1))) void*)g,
      (__attribute__((address_space(3))) void*)l, 16, 0, 0);
}

// ---------------- init / conversion ----------------

__global__ void k_convert_emb(const float* __restrict__ emb, u16* __restrict__ ebf) {
  int i = blockIdx.x * 256 + threadIdx.x;
  if (i >= VP * KP) return;
  int v = i / KP, k = i % KP;
  float val = (v < V && k < H) ? emb[(long long)v * H + k] : 0.f;
  ebf[i] = f2bf(val);
}

__global__ void k_convert_enc(const float* __restrict__ enc, u16* __restrict__ encb) {
  int i = blockIdx.x * 256 + threadIdx.x;
  if (i >= B * T * H) return;
  encb[i] = f2bf(enc[i]);
}

__global__ void k_convert_w(const float* __restrict__ Wih, const float* __restrict__ Whh,
                            u16* __restrict__ wihH, u16* __restrict__ wihL,
                            u16* __restrict__ whhH, u16* __restrict__ whhL) {
  int i = blockIdx.x * 256 + threadIdx.x;
  if (i >= NWP * KP) return;
  int n = i / KP, k = i % KP;
  float v1 = (n < H3 && k < H) ? Wih[n * H + k] : 0.f;
  u16 h1 = f2bf(v1);
  wihH[i] = h1; wihL[i] = f2bf(v1 - bf2f(h1));
  float v2 = (n < H3 && k < H) ? Whh[n * H + k] : 0.f;
  u16 h2 = f2bf(v2);
  whhH[i] = h2; whhL[i] = f2bf(v2 - bf2f(h2));
}

__global__ void k_init_dec(const float* __restrict__ emb, const float* __restrict__ semb,
                           const int* __restrict__ tgt, float* __restrict__ dec,
                           u16* __restrict__ dH, u16* __restrict__ dL) {
  int i = blockIdx.x * 256 + threadIdx.x;
  if (i >= STEPS * MP * KP) return;
  int k = i % KP, m = (i / KP) % MP, s = i / (KP * MP);
  float val = 0.f;
  if (m < M && k < H) {
    int slot = m / B, b = m % B;
    if (s == 0) val = semb[slot * H + k];
    else        val = emb[(long long)tgt[(b * S + slot) * STEPS + (s - 1)] * H + k];
    dec[((long long)s * M + m) * H + k] = val;
  }
  u16 hi = f2bf(val);
  dH[i] = hi; dL[i] = f2bf(val - bf2f(hi));
}

__global__ void k_init_h(const float* __restrict__ ehid, float* __restrict__ h,
                         u16* __restrict__ hH, u16* __restrict__ hL) {
  int i = blockIdx.x * 256 + threadIdx.x;
  if (i >= MP * KP) return;
  int k = i % KP, m = i / KP;
  float val = (m < M && k < H) ? ehid[(m % B) * H + k] : 0.f;
  if (m < M && k < H) h[m * H + k] = val;
  u16 hi = f2bf(val);
  hH[i] = hi; hL[i] = f2bf(val - bf2f(hi));
}

// ---------------- 64x64-tile SPLIT GEMM (GRU), gload_lds-staged B ----------------
// C[M][N] = A[M][K] * Bm[N][K]^T + bias, hi/lo 3-MFMA compensation.
// LDS [64 rows][32 k] linear; 16B-granule XOR swizzle: stored granule = logical ^ (row&3).
__global__ __launch_bounds__(256) void k_gemm64s(
    const u16* __restrict__ Ahi, const u16* __restrict__ Alo,
    const u16* __restrict__ Bmh, const u16* __restrict__ Bml,
    const float* __restrict__ bias, float* __restrict__ C,
    int Mvalid, int Nvalid, int Cstride)
{
  __shared__ u16 BsH[64 * 32], BsL[64 * 32];
  const int tid = threadIdx.x;
  const int wave = tid >> 6, lane = tid & 63;
  const int wm = wave >> 1, wn = wave & 1;
  const int n0 = blockIdx.x * 64;
  const int m0 = blockIdx.y * 64;
  const int lrow = lane & 15;
  const int c16 = lane >> 4;                 // logical 16B granule 0..3
  const int srow = tid >> 2;                 // staging row 0..63
  const int sg = (tid & 3) ^ (srow & 3);     // inverse-swizzled source granule
  f32x4 acc[2][2] = {};

  const u16* aH = Ahi + (size_t)(m0 + wm * 32 + lrow) * KP + c16 * 8;
  const u16* aL = Alo + (size_t)(m0 + wm * 32 + lrow) * KP + c16 * 8;
  const u16* bHs = Bmh + (size_t)(n0 + srow) * KP + sg * 8;
  const u16* bLs = Bml + (size_t)(n0 + srow) * KP + sg * 8;
  u16* lBH = BsH + wave * 512;               // 64 lanes * 16B = 512 u16 per wave
  u16* lBL = BsL + wave * 512;

  for (int kk = 0; kk < KP / 32; ++kk) {
    const int kb = kk * 32;
    gload16(bHs + kb, lBH);
    gload16(bLs + kb, lBL);
    __syncthreads();
    bfrag a0h = *(const bfrag*)(aH + kb);
    bfrag a1h = *(const bfrag*)(aH + 16 * KP + kb);
    bfrag a0l = *(const bfrag*)(aL + kb);
    bfrag a1l = *(const bfrag*)(aL + 16 * KP + kb);
#pragma unroll
    for (int nn = 0; nn < 2; ++nn) {
      const int br = wn * 32 + nn * 16 + lrow;
      const int goff = br * 32 + ((c16 ^ (br & 3)) << 3);
      bfrag bh = *(const bfrag*)&BsH[goff];
      bfrag bl = *(const bfrag*)&BsL[goff];
      acc[0][nn] = __builtin_amdgcn_mfma_f32_16x16x32_bf16(a0h, bh, acc[0][nn], 0, 0, 0);
      acc[1][nn] = __builtin_amdgcn_mfma_f32_16x16x32_bf16(a1h, bh, acc[1][nn], 0, 0, 0);
      acc[0][nn] = __builtin_amdgcn_mfma_f32_16x16x32_bf16(a0h, bl, acc[0][nn], 0, 0, 0);
      acc[1][nn] = __builtin_amdgcn_mfma_f32_16x16x32_bf16(a1h, bl, acc[1][nn], 0, 0, 0);
      acc[0][nn] = __builtin_amdgcn_mfma_f32_16x16x32_bf16(a0l, bh, acc[0][nn], 0, 0, 0);
      acc[1][nn] = __builtin_amdgcn_mfma_f32_16x16x32_bf16(a1l, bh, acc[1][nn], 0, 0, 0);
    }
    __syncthreads();
  }
  const int orow = (lane >> 4) << 2, ocol = lane & 15;
#pragma unroll
  for (int am = 0; am < 2; ++am) {
#pragma unroll
    for (int nn = 0; nn < 2; ++nn) {
      const int gn = n0 + wn * 32 + nn * 16 + ocol;
      if (gn >= Nvalid) continue;
      const float badd = bias[gn];
#pragma unroll
      for (int r = 0; r < 4; ++r) {
        const int gm = m0 + wm * 32 + am * 16 + orow + r;
        if (gm < Mvalid) C[(long long)gm * Cstride + gn] = acc[am][nn][r] + badd;
      }
    }
  }
}

// ---------------- fused per-step attention chain, 2 slots (same b) per block ----------------
__global__ __launch_bounds__(512) void k_attn_all(
    const float* __restrict__ gi_s, const float* __restrict__ gh,
    float* __restrict__ h, u16* __restrict__ hH, u16* __restrict__ hL,
    const float* __restrict__ dec_s, const u16* __restrict__ encb,
    const int* __restrict__ lens,
    const float* __restrict__ Wr, const float* __restrict__ br,
    const float* __restrict__ Wg, const float* __restrict__ bg,
    float* __restrict__ attn, float* __restrict__ pgen,
    float* __restrict__ out, int s)
{
  __shared__ float hs[2][H], sat[2][T], sctx[2][H], red8[8];
  const int bi = blockIdx.x;
  const int b = bi % B;
  const int s0 = (bi / B) * 2;
  const int mm[2] = { s0 * B + b, (s0 + 1) * B + b };
  const int tid = threadIdx.x;
  const int wave = tid >> 6, lane = tid & 63;
  const int len = lens[b];

  // phase 0: GRU cell for both rows
#pragma unroll
  for (int r = 0; r < 2; ++r) {
    if (tid < H) {
      const int m = mm[r], k = tid;
      float ir = gi_s[m * H3 + k],         hr = gh[m * H3 + k];
      float iz = gi_s[m * H3 + H + k],     hz = gh[m * H3 + H + k];
      float in_ = gi_s[m * H3 + 2*H + k],  hn = gh[m * H3 + 2*H + k];
      float rr = sigm(ir + hr);
      float z = sigm(iz + hz);
      float n = tanhf(in_ + rr * hn);
      float hv = (1.f - z) * n + z * h[m * H + k];
      h[m * H + k] = hv;
      u16 hb = f2bf(hv);
      hH[m * KP + k] = hb;
      hL[m * KP + k] = f2bf(hv - bf2f(hb));
      hs[r][k] = hv;
    }
  }
  __syncthreads();

  // phase 1: logits; h in registers (8 f32/lane/row), enc as bf16x8 vector loads
  float hreg[2][8];
  if (lane < 50) {
#pragma unroll
    for (int j = 0; j < 8; ++j) { hreg[0][j] = hs[0][lane * 8 + j]; hreg[1][j] = hs[1][lane * 8 + j]; }
  }
  for (int t = wave * 50; t < wave * 50 + 50; ++t) {
    if (t >= len) { if (lane == 0) { sat[0][t] = -1e30f; sat[1][t] = -1e30f; } continue; }
    float a0 = 0.f, a1 = 0.f;
    if (lane < 50) {
      bfrag ev = *(const bfrag*)(encb + ((size_t)b * T + t) * H + lane * 8);
#pragma unroll
      for (int j = 0; j < 8; ++j) {
        float e = bf2f((u16)ev[j]);
        a0 = fmaf(hreg[0][j], e, a0);
        a1 = fmaf(hreg[1][j], e, a1);
      }
    }
#pragma unroll
    for (int off = 32; off; off >>= 1) { a0 += __shfl_xor(a0, off); a1 += __shfl_xor(a1, off); }
    if (lane == 0) { sat[0][t] = a0; sat[1][t] = a1; }
  }
  __syncthreads();

  // phase 2: softmax per row (wave-shfl + 8-slot LDS combine)
#pragma unroll
  for (int r = 0; r < 2; ++r) {
    float v = (tid < T) ? sat[r][tid] : -1e30f;
    float wv = v;
#pragma unroll
    for (int off = 32; off; off >>= 1) wv = fmaxf(wv, __shfl_xor(wv, off));
    if (lane == 0) red8[wave] = wv;
    __syncthreads();
    float mx = red8[0];
#pragma unroll
    for (int j = 1; j < 8; ++j) mx = fmaxf(mx, red8[j]);
    __syncthreads();
    float e = (tid < len) ? __expf(v - mx) : 0.f;
    float ws = e;
#pragma unroll
    for (int off = 32; off; off >>= 1) ws += __shfl_xor(ws, off);
    if (lane == 0) red8[wave] = ws;
    __syncthreads();
    float sm = 0.f;
#pragma unroll
    for (int j = 0; j < 8; ++j) sm += red8[j];
    float inv = 1.f / sm;
    __syncthreads();
    if (tid < T) {
      float av = e * inv;
      sat[r][tid] = av;
      attn[(size_t)mm[r] * T + tid] = av;
    }
  }
  __syncthreads();

  // phase 3: context for both rows; each bf16 enc load feeds 2 FMAs
  if (tid < H) {
    float c0 = 0.f, c1 = 0.f;
    const u16* eb = encb + (size_t)b * T * H + tid;
    for (int t = 0; t < len; ++t) {
      float ev = bf2f(eb[(size_t)t * H]);
      c0 = fmaf(sat[0][t], ev, c0);
      c1 = fmaf(sat[1][t], ev, c1);
    }
    sctx[0][tid] = c0; sctx[1][tid] = c1;
  }
  __syncthreads();

  // phase 4: p_gen (waves 0,1) and gates (waves 2..7, step 0 only) via wave reductions
  if (wave < 2) {
    const int r = wave, m = mm[r];
    float p = 0.f;
#pragma unroll
    for (int i = 0; i < 7; ++i) {
      int k = lane + 64 * i;
      if (k < H)
        p += hs[r][k] * Wr[k] + sctx[r][k] * Wr[H + k] + dec_s[m * H + k] * Wr[2 * H + k];
    }
#pragma unroll
    for (int off = 32; off; off >>= 1) p += __shfl_xor(p, off);
    if (lane == 0) pgen[m] = sigm(p + br[0]);
  } else if (s == 0) {
    const int idx = wave - 2;            // 0..5 -> (r, g)
    const int r = idx / NG, g = idx % NG;
    float a = 0.f;
#pragma unroll
    for (int i = 0; i < 7; ++i) {
      int k = lane + 64 * i;
      if (k < H) a = fmaf(sctx[r][k], Wg[g * H + k], a);
    }
#pragma unroll
    for (int off = 32; off; off >>= 1) a += __shfl_xor(a, off);
    if (lane == 0) out[PTS + (long long)mm[r] * NG + g] = a + bg[g];
  }
}

// ---------------- vocab GEMM, gload_lds-staged A+B, fused exp + partials ----------------
__global__ __launch_bounds__(512) void k_vocab_gemm(
    const u16* __restrict__ Ahi, const u16* __restrict__ Bmh,
    u16* __restrict__ ebuf, float* __restrict__ pmax, float* __restrict__ psum)
{
  __shared__ u16 As[128 * 32], Bs[128 * 32];
  __shared__ float lpm[128][2], lps[128][2], bmax[128];
  const int tid = threadIdx.x;
  const int wave = tid >> 6, lane = tid & 63;
  const int wm = wave >> 1, wn = wave & 1;
  const int n0 = blockIdx.x * 128;
  const int m0 = blockIdx.y * 128;
  const int lrow = lane & 15;
  const int c16 = lane >> 4;                 // logical granule 0..3
  const int srow = tid >> 2;                 // staging row 0..127
  const int sg = (tid & 3) ^ (srow & 3);     // inverse-swizzled source granule
  f32x4 acc[2][4] = {};

  const u16* aS = Ahi + (size_t)(m0 + srow) * KP + sg * 8;
  const u16* bS = Bmh + (size_t)(n0 + srow) * KP + sg * 8;
  u16* lA = As + wave * 512;
  u16* lB = Bs + wave * 512;

  for (int kk = 0; kk < KP / 32; ++kk) {
    const int kb = kk * 32;
    gload16(aS + kb, lA);
    gload16(bS + kb, lB);
    __syncthreads();
    bfrag af[2], bfv[4];
#pragma unroll
    for (int am = 0; am < 2; ++am) {
      const int ar = wm * 32 + am * 16 + lrow;
      af[am] = *(const bfrag*)&As[ar * 32 + ((c16 ^ (ar & 3)) << 3)];
    }
#pragma unroll
    for (int nn = 0; nn < 4; ++nn) {
      const int brr = wn * 64 + nn * 16 + lrow;
      bfv[nn] = *(const bfrag*)&Bs[brr * 32 + ((c16 ^ (brr & 3)) << 3)];
    }
#pragma unroll
    for (int nn = 0; nn < 4; ++nn) {
      acc[0][nn] = __builtin_amdgcn_mfma_f32_16x16x32_bf16(af[0], bfv[nn], acc[0][nn], 0, 0, 0);
      acc[1][nn] = __builtin_amdgcn_mfma_f32_16x16x32_bf16(af[1], bfv[nn], acc[1][nn], 0, 0, 0);
    }
    __syncthreads();
  }

  const int orow = (lane >> 4) << 2, ocol = lane & 15;
  // half-block (64-col) max per row
#pragma unroll
  for (int am = 0; am < 2; ++am) {
#pragma unroll
    for (int r = 0; r < 4; ++r) {
      float mxv = -1e30f;
#pragma unroll
      for (int nn = 0; nn < 4; ++nn) {
        const int gn = n0 + wn * 64 + nn * 16 + ocol;
        if (gn < V) mxv = fmaxf(mxv, acc[am][nn][r]);
      }
#pragma unroll
      for (int d = 1; d < 16; d <<= 1) mxv = fmaxf(mxv, __shfl_xor(mxv, d));
      if ((lane & 15) == 0) lpm[wm * 32 + am * 16 + orow + r][wn] = mxv;
    }
  }
  __syncthreads();
  if (tid < 128) bmax[tid] = fmaxf(lpm[tid][0], lpm[tid][1]);
  __syncthreads();
  // e = exp(v - blockmax): write bf16, accumulate sums
#pragma unroll
  for (int am = 0; am < 2; ++am) {
#pragma unroll
    for (int r = 0; r < 4; ++r) {
      const int rl = wm * 32 + am * 16 + orow + r;
      const int gm = m0 + rl;
      const float bm = bmax[rl];
      float se = 0.f;
#pragma unroll
      for (int nn = 0; nn < 4; ++nn) {
        const int gn = n0 + wn * 64 + nn * 16 + ocol;
        if (gn < V) {
          float e = __expf(acc[am][nn][r] - bm);
          se += e;
          if (gm < M) ebuf[(size_t)gm * VP + gn] = f2bf(e);
        }
      }
#pragma unroll
      for (int d = 1; d < 16; d <<= 1) se += __shfl_xor(se, d);
      if ((lane & 15) == 0) lps[rl][wn] = se;
    }
  }
  __syncthreads();
  if (tid < 128) {
    const int gm = m0 + tid;
    if (gm < M) {
      pmax[(size_t)gm * NBLK + blockIdx.x] = bmax[tid];
      psum[(size_t)gm * NBLK + blockIdx.x] = lps[tid][0] + lps[tid][1];
    }
  }
}

// ---------------- final: combine partials, scale bf16 e-values, scatter p_ctx ----------------
__global__ __launch_bounds__(512) void k_vocab_out(
    const u16* __restrict__ ebuf, const float* __restrict__ pmax,
    const float* __restrict__ psum, const float* __restrict__ pgen,
    const float* __restrict__ attn, const int* __restrict__ story,
    float* __restrict__ out, int s)
{
  const int m = blockIdx.x, b = m % B, tid = threadIdx.x;
  const int wave = tid >> 6, lane = tid & 63;
  __shared__ float fact[NBLK], red8[8];
  float pm = (tid < NBLK) ? pmax[(size_t)m * NBLK + tid] : -1e30f;
  float wv = pm;
#pragma unroll
  for (int off = 32; off; off >>= 1) wv = fmaxf(wv, __shfl_xor(wv, off));
  if (lane == 0) red8[wave] = wv;
  __syncthreads();
  float Mx = red8[0];
#pragma unroll
  for (int j = 1; j < 8; ++j) Mx = fmaxf(Mx, red8[j]);
  __syncthreads();
  float sv = (tid < NBLK) ? psum[(size_t)m * NBLK + tid] * __expf(pm - Mx) : 0.f;
  float ws = sv;
#pragma unroll
  for (int off = 32; off; off >>= 1) ws += __shfl_xor(ws, off);
  if (lane == 0) red8[wave] = ws;
  __syncthreads();
  float Sv = 0.f;
#pragma unroll
  for (int j = 0; j < 8; ++j) Sv += red8[j];
  const float pg = pgen[m];
  const float scale = pg / Sv;
  if (tid < NBLK) fact[tid] = __expf(pm - Mx) * scale;
  __syncthreads();

  const u16* erow = ebuf + (size_t)m * VP;
  float* orow = out + ((size_t)m * STEPS + s) * V;
  for (int v = tid; v < V; v += 512) orow[v] = bf2f(erow[v]) * fact[v >> 7];
  __syncthreads();
  const float om = 1.f - pg;
  for (int t = tid; t < T; t += 512) {
    float a = attn[(size_t)m * T + t];
    if (a != 0.f) atomicAdd(orow + story[b * T + t], om * a);
  }
}

// ---------------- launch ----------------

extern "C" void kernel_launch(void* const* d_in, const int* in_sizes, int n_in,
                              void* d_out, int out_size, void* d_ws, size_t ws_size,
                              hipStream_t stream) {
  (void)in_sizes; (void)n_in; (void)out_size; (void)ws_size;
  const float* emb  = (const float*)d_in[0];
  const float* Wih  = (const float*)d_in[1];
  const float* Whh  = (const float*)d_in[2];
  const float* bih  = (const float*)d_in[3];
  const float* bhh  = (const float*)d_in[4];
  const float* Wr   = (const float*)d_in[5];
  const float* br   = (const float*)d_in[6];
  const float* Wg   = (const float*)d_in[7];
  const float* bg   = (const float*)d_in[8];
  const float* semb = (const float*)d_in[9];
  const float* ehid = (const float*)d_in[10];
  const float* enc  = (const float*)d_in[11];
  const int*   lens = (const int*)d_in[12];
  const int*   story= (const int*)d_in[13];
  const int*   tgt  = (const int*)d_in[14];
  float* out = (float*)d_out;

  char* w = (char*)d_ws;
  size_t off = 0;
  auto alloc = [&](size_t n) -> void* {
    void* p = w + off;
    off = (off + n + 255) & ~(size_t)255;
    return p;
  };
  u16* ebf   = (u16*)alloc((size_t)VP * KP * 2);
  u16* wihH  = (u16*)alloc((size_t)NWP * KP * 2);
  u16* wihL  = (u16*)alloc((size_t)NWP * KP * 2);
  u16* whhH  = (u16*)alloc((size_t)NWP * KP * 2);
  u16* whhL  = (u16*)alloc((size_t)NWP * KP * 2);
  u16* decH  = (u16*)alloc((size_t)STEPS * MP * KP * 2);
  u16* decL  = (u16*)alloc((size_t)STEPS * MP * KP * 2);
  float* dec = (float*)alloc((size_t)STEPS * M * H * 4);
  float* h   = (float*)alloc((size_t)M * H * 4);
  u16* hH    = (u16*)alloc((size_t)MP * KP * 2);
  u16* hL    = (u16*)alloc((size_t)MP * KP * 2);
  float* gi  = (float*)alloc((size_t)STEPS * MP * H3 * 4);
  float* gh  = (float*)alloc((size_t)M * H3 * 4);
  float* attn= (float*)alloc((size_t)M * T * 4);
  float* pgen= (float*)alloc((size_t)M * 4);
  u16* ebuf  = (u16*)alloc((size_t)MP * VP * 2);
  float* pmx = (float*)alloc((size_t)MP * NBLK * 4);
  float* psm = (float*)alloc((size_t)MP * NBLK * 4);
  u16* encb  = (u16*)alloc((size_t)B * T * H * 2);

  k_convert_emb<<<VP * KP / 256, 256, 0, stream>>>(emb, ebf);
  k_convert_enc<<<(B * T * H + 255) / 256, 256, 0, stream>>>(enc, encb);
  k_convert_w<<<NWP * KP / 256, 256, 0, stream>>>(Wih, Whh, wihH, wihL, whhH, whhL);
  k_init_dec<<<STEPS * MP * KP / 256, 256, 0, stream>>>(emb, semb, tgt, dec, decH, decL);
  k_init_h<<<MP * KP / 256, 256, 0, stream>>>(ehid, h, hH, hL);
  // all-steps gi = dec @ Wih^T + bih (batched, 19x64 = 1216 blocks)
  k_gemm64s<<<dim3((H3 + 63) / 64, STEPS * MP / 64), 256, 0, stream>>>(
      decH, decL, wihH, wihL, bih, gi, STEPS * MP, H3, H3);

  for (int s = 0; s < STEPS; ++s) {
    const float* dec_s = dec + (size_t)s * M * H;
    const float* gi_s  = gi + (size_t)s * MP * H3;
    k_gemm64s<<<dim3((H3 + 63) / 64, (M + 63) / 64), 256, 0, stream>>>(
        hH, hL, whhH, whhL, bhh, gh, M, H3, H3);
    k_attn_all<<<M / 2, 512, 0, stream>>>(gi_s, gh, h, hH, hL, dec_s, encb, lens,
                                          Wr, br, Wg, bg, attn, pgen, out, s);
    k_vocab_gemm<<<dim3(VP / 128, MP / 128), 512, 0, stream>>>(hH, ebf, ebuf, pmx, psm);
    k_vocab_out<<<M, 512, 0, stream>>>(ebuf, pmx, psm, pgen, attn, story, out, s);
  }
}

// Round 5
// 924.739 us; speedup vs baseline: 2.5433x; 1.0379x over previous
//
#include <hip/hip_runtime.h>

#define DEV __device__ __forceinline__

constexpr int B = 16, T = 400, H = 400, V = 22000, S = 30, STEPS = 8, NG = 3;
constexpr int M  = S * B;      // 480 (slot,b) rows
constexpr int H3 = 3 * H;      // 1200
constexpr int KP = 416;        // K padded to 13*32
constexpr int VP = 22016;      // V padded to 172*128
constexpr int MP = 512;        // M padded to 4*128
constexpr int NWP = 1280;      // GRU weight rows padded
constexpr int NBLK = VP / 128; // 172 vocab col-blocks
constexpr int NVB = NBLK * 4;  // 688 vocab blocks
constexpr int NAB = M / 2;     // 240 attn blocks
constexpr int NGB = (NWP / 128) * (MP / 128);  // 40 gh blocks
constexpr int CELLB = 96;      // cell blocks in k_merge
constexpr long long PTS = (long long)S * B * STEPS * V;  // 84,480,000

typedef __attribute__((ext_vector_type(8))) short bfrag;
typedef __attribute__((ext_vector_type(4))) float f32x4;
typedef unsigned short u16;

DEV u16 f2bf(float x) {
  unsigned u = __float_as_uint(x);
  u += 0x7FFFu + ((u >> 16) & 1u);
  return (u16)(u >> 16);
}
DEV float bf2f(u16 h) { return __uint_as_float(((unsigned)h) << 16); }
DEV float sigm(float x) { return 1.0f / (1.0f + __expf(-x)); }

DEV void gload16(const u16* g, u16* l) {
  __builtin_amdgcn_global_load_lds(
      (const __attribute__((address_space(1))) void*)g,
      (__attribute__((address_space(3))) void*)l, 16, 0, 0);
}

// ---------------- init / conversion ----------------

__global__ void k_convert_emb(const float* __restrict__ emb, u16* __restrict__ ebf) {
  int i = blockIdx.x * 256 + threadIdx.x;
  if (i >= VP * KP) return;
  int v = i / KP, k = i % KP;
  float val = (v < V && k < H) ? emb[(long long)v * H + k] : 0.f;
  ebf[i] = f2bf(val);
}

__global__ void k_convert_enc(const float* __restrict__ enc, u16* __restrict__ encb) {
  int i = blockIdx.x * 256 + threadIdx.x;
  if (i >= B * T * H) return;
  encb[i] = f2bf(enc[i]);
}

__global__ void k_convert_w(const float* __restrict__ Wih, const float* __restrict__ Whh,
                            u16* __restrict__ wihH, u16* __restrict__ wihL,
                            u16* __restrict__ whhH, u16* __restrict__ whhL) {
  int i = blockIdx.x * 256 + threadIdx.x;
  if (i >= NWP * KP) return;
  int n = i / KP, k = i % KP;
  float v1 = (n < H3 && k < H) ? Wih[n * H + k] : 0.f;
  u16 h1 = f2bf(v1);
  wihH[i] = h1; wihL[i] = f2bf(v1 - bf2f(h1));
  float v2 = (n < H3 && k < H) ? Whh[n * H + k] : 0.f;
  u16 h2 = f2bf(v2);
  whhH[i] = h2; whhL[i] = f2bf(v2 - bf2f(h2));
}

__global__ void k_init_dec(const float* __restrict__ emb, const float* __restrict__ semb,
                           const int* __restrict__ tgt, float* __restrict__ dec,
                           u16* __restrict__ dH, u16* __restrict__ dL) {
  int i = blockIdx.x * 256 + threadIdx.x;
  if (i >= STEPS * MP * KP) return;
  int k = i % KP, m = (i / KP) % MP, s = i / (KP * MP);
  float val = 0.f;
  if (m < M && k < H) {
    int slot = m / B, b = m % B;
    if (s == 0) val = semb[slot * H + k];
    else        val = emb[(long long)tgt[(b * S + slot) * STEPS + (s - 1)] * H + k];
    dec[((long long)s * M + m) * H + k] = val;
  }
  u16 hi = f2bf(val);
  dH[i] = hi; dL[i] = f2bf(val - bf2f(hi));
}

__global__ void k_init_h(const float* __restrict__ ehid, float* __restrict__ h,
                         u16* __restrict__ hH, u16* __restrict__ hL) {
  int i = blockIdx.x * 256 + threadIdx.x;
  if (i >= MP * KP) return;
  int k = i % KP, m = i / KP;
  float val = (m < M && k < H) ? ehid[(m % B) * H + k] : 0.f;
  if (m < M && k < H) h[m * H + k] = val;
  u16 hi = f2bf(val);
  hH[i] = hi; hL[i] = f2bf(val - bf2f(hi));
}

// ---------------- 64x64-tile SPLIT GEMM (init: gi batched, gh0) ----------------
__global__ __launch_bounds__(256) void k_gemm64s(
    const u16* __restrict__ Ahi, const u16* __restrict__ Alo,
    const u16* __restrict__ Bmh, const u16* __restrict__ Bml,
    const float* __restrict__ bias, float* __restrict__ C,
    int Mvalid, int Nvalid, int Cstride)
{
  __shared__ u16 BsH[64 * 32], BsL[64 * 32];
  const int tid = threadIdx.x;
  const int wave = tid >> 6, lane = tid & 63;
  const int wm = wave >> 1, wn = wave & 1;
  const int n0 = blockIdx.x * 64;
  const int m0 = blockIdx.y * 64;
  const int lrow = lane & 15;
  const int c16 = lane >> 4;
  const int srow = tid >> 2;
  const int sg = (tid & 3) ^ (srow & 3);
  f32x4 acc[2][2] = {};

  const u16* aH = Ahi + (size_t)(m0 + wm * 32 + lrow) * KP + c16 * 8;
  const u16* aL = Alo + (size_t)(m0 + wm * 32 + lrow) * KP + c16 * 8;
  const u16* bHs = Bmh + (size_t)(n0 + srow) * KP + sg * 8;
  const u16* bLs = Bml + (size_t)(n0 + srow) * KP + sg * 8;
  u16* lBH = BsH + wave * 512;
  u16* lBL = BsL + wave * 512;

  for (int kk = 0; kk < KP / 32; ++kk) {
    const int kb = kk * 32;
    gload16(bHs + kb, lBH);
    gload16(bLs + kb, lBL);
    __syncthreads();
    bfrag a0h = *(const bfrag*)(aH + kb);
    bfrag a1h = *(const bfrag*)(aH + 16 * KP + kb);
    bfrag a0l = *(const bfrag*)(aL + kb);
    bfrag a1l = *(const bfrag*)(aL + 16 * KP + kb);
#pragma unroll
    for (int nn = 0; nn < 2; ++nn) {
      const int br = wn * 32 + nn * 16 + lrow;
      const int goff = br * 32 + ((c16 ^ (br & 3)) << 3);
      bfrag bh = *(const bfrag*)&BsH[goff];
      bfrag bl = *(const bfrag*)&BsL[goff];
      acc[0][nn] = __builtin_amdgcn_mfma_f32_16x16x32_bf16(a0h, bh, acc[0][nn], 0, 0, 0);
      acc[1][nn] = __builtin_amdgcn_mfma_f32_16x16x32_bf16(a1h, bh, acc[1][nn], 0, 0, 0);
      acc[0][nn] = __builtin_amdgcn_mfma_f32_16x16x32_bf16(a0h, bl, acc[0][nn], 0, 0, 0);
      acc[1][nn] = __builtin_amdgcn_mfma_f32_16x16x32_bf16(a1h, bl, acc[1][nn], 0, 0, 0);
      acc[0][nn] = __builtin_amdgcn_mfma_f32_16x16x32_bf16(a0l, bh, acc[0][nn], 0, 0, 0);
      acc[1][nn] = __builtin_amdgcn_mfma_f32_16x16x32_bf16(a1l, bh, acc[1][nn], 0, 0, 0);
    }
    __syncthreads();
  }
  const int orow = (lane >> 4) << 2, ocol = lane & 15;
#pragma unroll
  for (int am = 0; am < 2; ++am) {
#pragma unroll
    for (int nn = 0; nn < 2; ++nn) {
      const int gn = n0 + wn * 32 + nn * 16 + ocol;
      if (gn >= Nvalid) continue;
      const float badd = bias[gn];
#pragma unroll
      for (int r = 0; r < 4; ++r) {
        const int gm = m0 + wm * 32 + am * 16 + orow + r;
        if (gm < Mvalid) C[(long long)gm * Cstride + gn] = acc[am][nn][r] + badd;
      }
    }
  }
}

// ---------------- GRU cell (device body) ----------------
DEV void cell_body(int i, const float* __restrict__ gi_s, const float* __restrict__ gh,
                   float* __restrict__ h, u16* __restrict__ hH, u16* __restrict__ hL) {
  int k = i % H, m = i / H;
  float ir = gi_s[m * H3 + k],         hr = gh[m * H3 + k];
  float iz = gi_s[m * H3 + H + k],     hz = gh[m * H3 + H + k];
  float in_ = gi_s[m * H3 + 2*H + k],  hn = gh[m * H3 + 2*H + k];
  float rr = sigm(ir + hr);
  float z = sigm(iz + hz);
  float n = tanhf(in_ + rr * hn);
  float hv = (1.f - z) * n + z * h[i];
  h[i] = hv;
  u16 hb = f2bf(hv);
  hH[m * KP + k] = hb;
  hL[m * KP + k] = f2bf(hv - bf2f(hb));
}

__global__ __launch_bounds__(512) void k_cell(const float* __restrict__ gi_s,
                                              const float* __restrict__ gh,
                                              float* __restrict__ h,
                                              u16* __restrict__ hH, u16* __restrict__ hL) {
  for (int i = blockIdx.x * 512 + threadIdx.x; i < M * H; i += CELLB * 512)
    cell_body(i, gi_s, gh, h, hH, hL);
}

// ---------------- k_big: [vocab GEMM ∥ attn chain ∥ gh GEMM(s+1)] ----------------
struct SMv { u16 As[128 * 32]; u16 Bs[128 * 32]; float lpm[128][2]; float lps[128][2]; float bmax[128]; };
struct SMa { float hs[2][H]; float sat[2][T]; float sctx[2][H]; float red8[8]; };
struct SMg { u16 BsH[128 * 32]; u16 BsL[128 * 32]; };
union SMU { SMv v; SMa a; SMg g; };

__global__ __launch_bounds__(512) void k_big(
    const float* __restrict__ h, const u16* __restrict__ hH, const u16* __restrict__ hL,
    const u16* __restrict__ encb, const int* __restrict__ lens,
    const float* __restrict__ dec, const float* __restrict__ Wr, const float* __restrict__ br,
    const float* __restrict__ Wg, const float* __restrict__ bg,
    const u16* __restrict__ ebf,
    const u16* __restrict__ whhH, const u16* __restrict__ whhL, const float* __restrict__ bhh,
    float* __restrict__ attn, float* __restrict__ pgen,
    u16* __restrict__ ebuf, float* __restrict__ pmax, float* __restrict__ psum,
    float* __restrict__ gh, float* __restrict__ out, int s)
{
  __shared__ SMU sm;
  const int bx = blockIdx.x;
  const int tid = threadIdx.x;
  const int wave = tid >> 6, lane = tid & 63;

  if (bx < NVB) {
    // ================= vocab GEMM branch =================
    const int wm = wave >> 1, wn = wave & 1;
    const int n0 = (bx % NBLK) * 128;
    const int m0 = (bx / NBLK) * 128;
    const int lrow = lane & 15;
    const int c16 = lane >> 4;
    const int srow = tid >> 2;
    const int sg = (tid & 3) ^ (srow & 3);
    f32x4 acc[2][4] = {};

    const u16* aS = hH + (size_t)(m0 + srow) * KP + sg * 8;
    const u16* bS = ebf + (size_t)(n0 + srow) * KP + sg * 8;
    u16* lA = sm.v.As + wave * 512;
    u16* lB = sm.v.Bs + wave * 512;

    for (int kk = 0; kk < KP / 32; ++kk) {
      const int kb = kk * 32;
      gload16(aS + kb, lA);
      gload16(bS + kb, lB);
      __syncthreads();
      bfrag af[2], bfv[4];
#pragma unroll
      for (int am = 0; am < 2; ++am) {
        const int ar = wm * 32 + am * 16 + lrow;
        af[am] = *(const bfrag*)&sm.v.As[ar * 32 + ((c16 ^ (ar & 3)) << 3)];
      }
#pragma unroll
      for (int nn = 0; nn < 4; ++nn) {
        const int brr = wn * 64 + nn * 16 + lrow;
        bfv[nn] = *(const bfrag*)&sm.v.Bs[brr * 32 + ((c16 ^ (brr & 3)) << 3)];
      }
#pragma unroll
      for (int nn = 0; nn < 4; ++nn) {
        acc[0][nn] = __builtin_amdgcn_mfma_f32_16x16x32_bf16(af[0], bfv[nn], acc[0][nn], 0, 0, 0);
        acc[1][nn] = __builtin_amdgcn_mfma_f32_16x16x32_bf16(af[1], bfv[nn], acc[1][nn], 0, 0, 0);
      }
      __syncthreads();
    }

    const int orow = (lane >> 4) << 2, ocol = lane & 15;
#pragma unroll
    for (int am = 0; am < 2; ++am) {
#pragma unroll
      for (int r = 0; r < 4; ++r) {
        float mxv = -1e30f;
#pragma unroll
        for (int nn = 0; nn < 4; ++nn) {
          const int gn = n0 + wn * 64 + nn * 16 + ocol;
          if (gn < V) mxv = fmaxf(mxv, acc[am][nn][r]);
        }
#pragma unroll
        for (int d = 1; d < 16; d <<= 1) mxv = fmaxf(mxv, __shfl_xor(mxv, d));
        if ((lane & 15) == 0) sm.v.lpm[wm * 32 + am * 16 + orow + r][wn] = mxv;
      }
    }
    __syncthreads();
    if (tid < 128) sm.v.bmax[tid] = fmaxf(sm.v.lpm[tid][0], sm.v.lpm[tid][1]);
    __syncthreads();
#pragma unroll
    for (int am = 0; am < 2; ++am) {
#pragma unroll
      for (int r = 0; r < 4; ++r) {
        const int rl = wm * 32 + am * 16 + orow + r;
        const int gm = m0 + rl;
        const float bm = sm.v.bmax[rl];
        float se = 0.f;
#pragma unroll
        for (int nn = 0; nn < 4; ++nn) {
          const int gn = n0 + wn * 64 + nn * 16 + ocol;
          if (gn < V) {
            float e = __expf(acc[am][nn][r] - bm);
            se += e;
            if (gm < M) ebuf[(size_t)gm * VP + gn] = f2bf(e);
          }
        }
#pragma unroll
        for (int d = 1; d < 16; d <<= 1) se += __shfl_xor(se, d);
        if ((lane & 15) == 0) sm.v.lps[rl][wn] = se;
      }
    }
    __syncthreads();
    if (tid < 128) {
      const int gm = m0 + tid;
      if (gm < M) {
        pmax[(size_t)gm * NBLK + (bx % NBLK)] = sm.v.bmax[tid];
        psum[(size_t)gm * NBLK + (bx % NBLK)] = sm.v.lps[tid][0] + sm.v.lps[tid][1];
      }
    }
  } else if (bx < NVB + NAB) {
    // ================= attn chain branch =================
    const int ab = bx - NVB;
    const int b = ab % B;
    const int s0 = (ab / B) * 2;
    const int mm[2] = { s0 * B + b, (s0 + 1) * B + b };
    const int len = lens[b];
    const float* dec_s = dec + (size_t)s * M * H;

    // load h into LDS
#pragma unroll
    for (int r = 0; r < 2; ++r)
      if (tid < H) sm.a.hs[r][tid] = h[mm[r] * H + tid];
    __syncthreads();

    // phase 1: logits
    float hreg[2][8];
    if (lane < 50) {
#pragma unroll
      for (int j = 0; j < 8; ++j) { hreg[0][j] = sm.a.hs[0][lane * 8 + j]; hreg[1][j] = sm.a.hs[1][lane * 8 + j]; }
    }
    for (int t = wave * 50; t < wave * 50 + 50; ++t) {
      if (t >= len) { if (lane == 0) { sm.a.sat[0][t] = -1e30f; sm.a.sat[1][t] = -1e30f; } continue; }
      float a0 = 0.f, a1 = 0.f;
      if (lane < 50) {
        bfrag ev = *(const bfrag*)(encb + ((size_t)b * T + t) * H + lane * 8);
#pragma unroll
        for (int j = 0; j < 8; ++j) {
          float e = bf2f((u16)ev[j]);
          a0 = fmaf(hreg[0][j], e, a0);
          a1 = fmaf(hreg[1][j], e, a1);
        }
      }
#pragma unroll
      for (int off = 32; off; off >>= 1) { a0 += __shfl_xor(a0, off); a1 += __shfl_xor(a1, off); }
      if (lane == 0) { sm.a.sat[0][t] = a0; sm.a.sat[1][t] = a1; }
    }
    __syncthreads();

    // phase 2: softmax
#pragma unroll
    for (int r = 0; r < 2; ++r) {
      float v = (tid < T) ? sm.a.sat[r][tid] : -1e30f;
      float wv = v;
#pragma unroll
      for (int off = 32; off; off >>= 1) wv = fmaxf(wv, __shfl_xor(wv, off));
      if (lane == 0) sm.a.red8[wave] = wv;
      __syncthreads();
      float mx = sm.a.red8[0];
#pragma unroll
      for (int j = 1; j < 8; ++j) mx = fmaxf(mx, sm.a.red8[j]);
      __syncthreads();
      float e = (tid < len) ? __expf(v - mx) : 0.f;
      float ws = e;
#pragma unroll
      for (int off = 32; off; off >>= 1) ws += __shfl_xor(ws, off);
      if (lane == 0) sm.a.red8[wave] = ws;
      __syncthreads();
      float smm = 0.f;
#pragma unroll
      for (int j = 0; j < 8; ++j) smm += sm.a.red8[j];
      float inv = 1.f / smm;
      __syncthreads();
      if (tid < T) {
        float av = e * inv;
        sm.a.sat[r][tid] = av;
        attn[(size_t)mm[r] * T + tid] = av;
      }
    }
    __syncthreads();

    // phase 3: context
    if (tid < H) {
      float c0 = 0.f, c1 = 0.f;
      const u16* eb = encb + (size_t)b * T * H + tid;
      for (int t = 0; t < len; ++t) {
        float ev = bf2f(eb[(size_t)t * H]);
        c0 = fmaf(sm.a.sat[0][t], ev, c0);
        c1 = fmaf(sm.a.sat[1][t], ev, c1);
      }
      sm.a.sctx[0][tid] = c0; sm.a.sctx[1][tid] = c1;
    }
    __syncthreads();

    // phase 4: p_gen / gates
    if (wave < 2) {
      const int r = wave, m = mm[r];
      float p = 0.f;
#pragma unroll
      for (int i = 0; i < 7; ++i) {
        int k = lane + 64 * i;
        if (k < H)
          p += sm.a.hs[r][k] * Wr[k] + sm.a.sctx[r][k] * Wr[H + k] + dec_s[m * H + k] * Wr[2 * H + k];
      }
#pragma unroll
      for (int off = 32; off; off >>= 1) p += __shfl_xor(p, off);
      if (lane == 0) pgen[m] = sigm(p + br[0]);
    } else if (s == 0) {
      const int idx = wave - 2;
      const int r = idx / NG, g = idx % NG;
      float a = 0.f;
#pragma unroll
      for (int i = 0; i < 7; ++i) {
        int k = lane + 64 * i;
        if (k < H) a = fmaf(sm.a.sctx[r][k], Wg[g * H + k], a);
      }
#pragma unroll
      for (int off = 32; off; off >>= 1) a += __shfl_xor(a, off);
      if (lane == 0) out[PTS + (long long)mm[r] * NG + g] = a + bg[g];
    }
  } else {
    // ================= gh GEMM branch (for step s+1) =================
    if (s >= STEPS - 1) return;
    const int gb = bx - NVB - NAB;
    const int wm = wave >> 1, wn = wave & 1;      // wm 0..3, wn 0..1
    const int n0 = (gb % (NWP / 128)) * 128;
    const int m0 = (gb / (NWP / 128)) * 128;
    const int lrow = lane & 15;
    const int c16 = lane >> 4;
    const int srow = tid >> 2;
    const int sg = (tid & 3) ^ (srow & 3);
    f32x4 acc[2][4] = {};

    const u16* aH = hH + (size_t)(m0 + wm * 32 + lrow) * KP + c16 * 8;
    const u16* aL = hL + (size_t)(m0 + wm * 32 + lrow) * KP + c16 * 8;
    const u16* bHs = whhH + (size_t)(n0 + srow) * KP + sg * 8;
    const u16* bLs = whhL + (size_t)(n0 + srow) * KP + sg * 8;
    u16* lBH = sm.g.BsH + wave * 512;
    u16* lBL = sm.g.BsL + wave * 512;

    for (int kk = 0; kk < KP / 32; ++kk) {
      const int kb = kk * 32;
      gload16(bHs + kb, lBH);
      gload16(bLs + kb, lBL);
      __syncthreads();
      bfrag a0h = *(const bfrag*)(aH + kb);
      bfrag a1h = *(const bfrag*)(aH + 16 * KP + kb);
      bfrag a0l = *(const bfrag*)(aL + kb);
      bfrag a1l = *(const bfrag*)(aL + 16 * KP + kb);
#pragma unroll
      for (int nn = 0; nn < 4; ++nn) {
        const int brw = wn * 64 + nn * 16 + lrow;
        const int goff = brw * 32 + ((c16 ^ (brw & 3)) << 3);
        bfrag bh = *(const bfrag*)&sm.g.BsH[goff];
        bfrag bl = *(const bfrag*)&sm.g.BsL[goff];
        acc[0][nn] = __builtin_amdgcn_mfma_f32_16x16x32_bf16(a0h, bh, acc[0][nn], 0, 0, 0);
        acc[1][nn] = __builtin_amdgcn_mfma_f32_16x16x32_bf16(a1h, bh, acc[1][nn], 0, 0, 0);
        acc[0][nn] = __builtin_amdgcn_mfma_f32_16x16x32_bf16(a0h, bl, acc[0][nn], 0, 0, 0);
        acc[1][nn] = __builtin_amdgcn_mfma_f32_16x16x32_bf16(a1h, bl, acc[1][nn], 0, 0, 0);
        acc[0][nn] = __builtin_amdgcn_mfma_f32_16x16x32_bf16(a0l, bh, acc[0][nn], 0, 0, 0);
        acc[1][nn] = __builtin_amdgcn_mfma_f32_16x16x32_bf16(a1l, bh, acc[1][nn], 0, 0, 0);
      }
      __syncthreads();
    }
    const int orow = (lane >> 4) << 2, ocol = lane & 15;
#pragma unroll
    for (int am = 0; am < 2; ++am) {
#pragma unroll
      for (int nn = 0; nn < 4; ++nn) {
        const int gn = n0 + wn * 64 + nn * 16 + ocol;
        if (gn >= H3) continue;
        const float badd = bhh[gn];
#pragma unroll
        for (int r = 0; r < 4; ++r) {
          const int gm = m0 + wm * 32 + am * 16 + orow + r;
          if (gm < M) gh[(long long)gm * H3 + gn] = acc[am][nn][r] + badd;
        }
      }
    }
  }
}

// ---------------- k_merge: [vocab_out(s) ∥ GRU cell(s+1)] ----------------
__global__ __launch_bounds__(512) void k_merge(
    const u16* __restrict__ ebuf, const float* __restrict__ pmax,
    const float* __restrict__ psum, const float* __restrict__ pgen,
    const float* __restrict__ attn, const int* __restrict__ story,
    const float* __restrict__ gi_next, const float* __restrict__ gh,
    float* __restrict__ h, u16* __restrict__ hH, u16* __restrict__ hL,
    float* __restrict__ out, int s, int do_cell)
{
  const int tid = threadIdx.x;
  if (blockIdx.x < (unsigned)M) {
    const int m = blockIdx.x, b = m % B;
    const int wave = tid >> 6, lane = tid & 63;
    __shared__ float fact[NBLK], red8[8];
    float pm = (tid < NBLK) ? pmax[(size_t)m * NBLK + tid] : -1e30f;
    float wv = pm;
#pragma unroll
    for (int off = 32; off; off >>= 1) wv = fmaxf(wv, __shfl_xor(wv, off));
    if (lane == 0) red8[wave] = wv;
    __syncthreads();
    float Mx = red8[0];
#pragma unroll
    for (int j = 1; j < 8; ++j) Mx = fmaxf(Mx, red8[j]);
    __syncthreads();
    float sv = (tid < NBLK) ? psum[(size_t)m * NBLK + tid] * __expf(pm - Mx) : 0.f;
    float ws = sv;
#pragma unroll
    for (int off = 32; off; off >>= 1) ws += __shfl_xor(ws, off);
    if (lane == 0) red8[wave] = ws;
    __syncthreads();
    float Sv = 0.f;
#pragma unroll
    for (int j = 0; j < 8; ++j) Sv += red8[j];
    const float pg = pgen[m];
    const float scale = pg / Sv;
    if (tid < NBLK) fact[tid] = __expf(pm - Mx) * scale;
    __syncthreads();

    const u16* erow = ebuf + (size_t)m * VP;
    float* orow = out + ((size_t)m * STEPS + s) * V;
    for (int v = tid; v < V; v += 512) orow[v] = bf2f(erow[v]) * fact[v >> 7];
    __syncthreads();
    const float om = 1.f - pg;
    for (int t = tid; t < T; t += 512) {
      float a = attn[(size_t)m * T + t];
      if (a != 0.f) atomicAdd(orow + story[b * T + t], om * a);
    }
  } else if (do_cell) {
    for (int i = (blockIdx.x - M) * 512 + tid; i < M * H; i += CELLB * 512)
      cell_body(i, gi_next, gh, h, hH, hL);
  }
}

// ---------------- launch ----------------

extern "C" void kernel_launch(void* const* d_in, const int* in_sizes, int n_in,
                              void* d_out, int out_size, void* d_ws, size_t ws_size,
                              hipStream_t stream) {
  (void)in_sizes; (void)n_in; (void)out_size; (void)ws_size;
  const float* emb  = (const float*)d_in[0];
  const float* Wih  = (const float*)d_in[1];
  const float* Whh  = (const float*)d_in[2];
  const float* bih  = (const float*)d_in[3];
  const float* bhh  = (const float*)d_in[4];
  const float* Wr   = (const float*)d_in[5];
  const float* br   = (const float*)d_in[6];
  const float* Wg   = (const float*)d_in[7];
  const float* bg   = (const float*)d_in[8];
  const float* semb = (const float*)d_in[9];
  const float* ehid = (const float*)d_in[10];
  const float* enc  = (const float*)d_in[11];
  const int*   lens = (const int*)d_in[12];
  const int*   story= (const int*)d_in[13];
  const int*   tgt  = (const int*)d_in[14];
  float* out = (float*)d_out;

  char* w = (char*)d_ws;
  size_t off = 0;
  auto alloc = [&](size_t n) -> void* {
    void* p = w + off;
    off = (off + n + 255) & ~(size_t)255;
    return p;
  };
  u16* ebf   = (u16*)alloc((size_t)VP * KP * 2);
  u16* wihH  = (u16*)alloc((size_t)NWP * KP * 2);
  u16* wihL  = (u16*)alloc((size_t)NWP * KP * 2);
  u16* whhH  = (u16*)alloc((size_t)NWP * KP * 2);
  u16* whhL  = (u16*)alloc((size_t)NWP * KP * 2);
  u16* decH  = (u16*)alloc((size_t)STEPS * MP * KP * 2);
  u16* decL  = (u16*)alloc((size_t)STEPS * MP * KP * 2);
  float* dec = (float*)alloc((size_t)STEPS * M * H * 4);
  float* h   = (float*)alloc((size_t)M * H * 4);
  u16* hH    = (u16*)alloc((size_t)MP * KP * 2);
  u16* hL    = (u16*)alloc((size_t)MP * KP * 2);
  float* gi  = (float*)alloc((size_t)STEPS * MP * H3 * 4);
  float* gh  = (float*)alloc((size_t)M * H3 * 4);
  float* attn= (float*)alloc((size_t)M * T * 4);
  float* pgen= (float*)alloc((size_t)M * 4);
  u16* ebuf  = (u16*)alloc((size_t)MP * VP * 2);
  float* pmx = (float*)alloc((size_t)MP * NBLK * 4);
  float* psm = (float*)alloc((size_t)MP * NBLK * 4);
  u16* encb  = (u16*)alloc((size_t)B * T * H * 2);

  k_convert_emb<<<VP * KP / 256, 256, 0, stream>>>(emb, ebf);
  k_convert_enc<<<(B * T * H + 255) / 256, 256, 0, stream>>>(enc, encb);
  k_convert_w<<<NWP * KP / 256, 256, 0, stream>>>(Wih, Whh, wihH, wihL, whhH, whhL);
  k_init_dec<<<STEPS * MP * KP / 256, 256, 0, stream>>>(emb, semb, tgt, dec, decH, decL);
  k_init_h<<<MP * KP / 256, 256, 0, stream>>>(ehid, h, hH, hL);
  // all-steps gi = dec @ Wih^T + bih
  k_gemm64s<<<dim3((H3 + 63) / 64, STEPS * MP / 64), 256, 0, stream>>>(
      decH, decL, wihH, wihL, bih, gi, STEPS * MP, H3, H3);
  // gh(0) = h_init @ Whh^T + bhh
  k_gemm64s<<<dim3((H3 + 63) / 64, (M + 63) / 64), 256, 0, stream>>>(
      hH, hL, whhH, whhL, bhh, gh, M, H3, H3);
  // cell(0): h_0
  k_cell<<<CELLB, 512, 0, stream>>>(gi, gh, h, hH, hL);

  for (int s = 0; s < STEPS; ++s) {
    k_big<<<NVB + NAB + NGB, 512, 0, stream>>>(
        h, hH, hL, encb, lens, dec, Wr, br, Wg, bg, ebf,
        whhH, whhL, bhh, attn, pgen, ebuf, pmx, psm, gh, out, s);
    const int do_cell = (s < STEPS - 1) ? 1 : 0;
    k_merge<<<M + (do_cell ? CELLB : 0), 512, 0, stream>>>(
        ebuf, pmx, psm, pgen, attn, story,
        gi + (size_t)(s + 1) * MP * H3, gh, h, hH, hL, out, s, do_cell);
  }
}

// Round 6
// 867.865 us; speedup vs baseline: 2.7100x; 1.0655x over previous
//
#include <hip/hip_runtime.h>

#define DEV __device__ __forceinline__

constexpr int B = 16, T = 400, H = 400, V = 22000, S = 30, STEPS = 8, NG = 3;
constexpr int M  = S * B;      // 480 (slot,b) rows
constexpr int H3 = 3 * H;      // 1200
constexpr int KP = 416;        // K padded to 13*32
constexpr int VP = 22016;      // V padded to 172*128
constexpr int MP = 512;        // M padded to 4*128
constexpr int NWP = 1280;      // GRU weight rows padded
constexpr int NBLK = VP / 128; // 172 vocab col-blocks
constexpr int NVB = NBLK * 2;  // 344 vocab blocks (256-row tiles)
constexpr int NAB = M / 2;     // 240 attn blocks
constexpr int NGB = (NWP / 128) * (MP / 128);  // 40 gh blocks
constexpr int CELLB = 96;      // cell blocks in k_merge
constexpr long long PTS = (long long)S * B * STEPS * V;  // 84,480,000

typedef __attribute__((ext_vector_type(8))) short bfrag;
typedef __attribute__((ext_vector_type(4))) float f32x4;
typedef unsigned short u16;

DEV u16 f2bf(float x) {
  unsigned u = __float_as_uint(x);
  u += 0x7FFFu + ((u >> 16) & 1u);
  return (u16)(u >> 16);
}
DEV float bf2f(u16 h) { return __uint_as_float(((unsigned)h) << 16); }
DEV float sigm(float x) { return 1.0f / (1.0f + __expf(-x)); }

DEV void gload16(const u16* g, u16* l) {
  __builtin_amdgcn_global_load_lds(
      (const __attribute__((address_space(1))) void*)g,
      (__attribute__((address_space(3))) void*)l, 16, 0, 0);
}

// ---------------- init / conversion ----------------

__global__ void k_convert_emb(const float* __restrict__ emb, u16* __restrict__ ebf) {
  int i = blockIdx.x * 256 + threadIdx.x;
  if (i >= VP * KP) return;
  int v = i / KP, k = i % KP;
  float val = (v < V && k < H) ? emb[(long long)v * H + k] : 0.f;
  ebf[i] = f2bf(val);
}

__global__ void k_convert_enc(const float* __restrict__ enc, u16* __restrict__ encb) {
  int i = blockIdx.x * 256 + threadIdx.x;
  if (i >= B * T * H) return;
  encb[i] = f2bf(enc[i]);
}

__global__ void k_convert_w(const float* __restrict__ Wih, const float* __restrict__ Whh,
                            u16* __restrict__ wihH, u16* __restrict__ wihL,
                            u16* __restrict__ whhH, u16* __restrict__ whhL) {
  int i = blockIdx.x * 256 + threadIdx.x;
  if (i >= NWP * KP) return;
  int n = i / KP, k = i % KP;
  float v1 = (n < H3 && k < H) ? Wih[n * H + k] : 0.f;
  u16 h1 = f2bf(v1);
  wihH[i] = h1; wihL[i] = f2bf(v1 - bf2f(h1));
  float v2 = (n < H3 && k < H) ? Whh[n * H + k] : 0.f;
  u16 h2 = f2bf(v2);
  whhH[i] = h2; whhL[i] = f2bf(v2 - bf2f(h2));
}

__global__ void k_init_dec(const float* __restrict__ emb, const float* __restrict__ semb,
                           const int* __restrict__ tgt, float* __restrict__ dec,
                           u16* __restrict__ dH, u16* __restrict__ dL) {
  int i = blockIdx.x * 256 + threadIdx.x;
  if (i >= STEPS * MP * KP) return;
  int k = i % KP, m = (i / KP) % MP, s = i / (KP * MP);
  float val = 0.f;
  if (m < M && k < H) {
    int slot = m / B, b = m % B;
    if (s == 0) val = semb[slot * H + k];
    else        val = emb[(long long)tgt[(b * S + slot) * STEPS + (s - 1)] * H + k];
    dec[((long long)s * M + m) * H + k] = val;
  }
  u16 hi = f2bf(val);
  dH[i] = hi; dL[i] = f2bf(val - bf2f(hi));
}

__global__ void k_init_h(const float* __restrict__ ehid, float* __restrict__ h,
                         u16* __restrict__ hH, u16* __restrict__ hL) {
  int i = blockIdx.x * 256 + threadIdx.x;
  if (i >= MP * KP) return;
  int k = i % KP, m = i / KP;
  float val = (m < M && k < H) ? ehid[(m % B) * H + k] : 0.f;
  if (m < M && k < H) h[m * H + k] = val;
  u16 hi = f2bf(val);
  hH[i] = hi; hL[i] = f2bf(val - bf2f(hi));
}

// ---------------- 64x64-tile SPLIT GEMM (init: gi batched, gh0) ----------------
__global__ __launch_bounds__(256) void k_gemm64s(
    const u16* __restrict__ Ahi, const u16* __restrict__ Alo,
    const u16* __restrict__ Bmh, const u16* __restrict__ Bml,
    const float* __restrict__ bias, float* __restrict__ C,
    int Mvalid, int Nvalid, int Cstride)
{
  __shared__ u16 BsH[64 * 32], BsL[64 * 32];
  const int tid = threadIdx.x;
  const int wave = tid >> 6, lane = tid & 63;
  const int wm = wave >> 1, wn = wave & 1;
  const int n0 = blockIdx.x * 64;
  const int m0 = blockIdx.y * 64;
  const int lrow = lane & 15;
  const int c16 = lane >> 4;
  const int srow = tid >> 2;
  const int sg = (tid & 3) ^ (srow & 3);
  f32x4 acc[2][2] = {};

  const u16* aH = Ahi + (size_t)(m0 + wm * 32 + lrow) * KP + c16 * 8;
  const u16* aL = Alo + (size_t)(m0 + wm * 32 + lrow) * KP + c16 * 8;
  const u16* bHs = Bmh + (size_t)(n0 + srow) * KP + sg * 8;
  const u16* bLs = Bml + (size_t)(n0 + srow) * KP + sg * 8;
  u16* lBH = BsH + wave * 512;
  u16* lBL = BsL + wave * 512;

  for (int kk = 0; kk < KP / 32; ++kk) {
    const int kb = kk * 32;
    gload16(bHs + kb, lBH);
    gload16(bLs + kb, lBL);
    __syncthreads();
    bfrag a0h = *(const bfrag*)(aH + kb);
    bfrag a1h = *(const bfrag*)(aH + 16 * KP + kb);
    bfrag a0l = *(const bfrag*)(aL + kb);
    bfrag a1l = *(const bfrag*)(aL + 16 * KP + kb);
#pragma unroll
    for (int nn = 0; nn < 2; ++nn) {
      const int br = wn * 32 + nn * 16 + lrow;
      const int goff = br * 32 + ((c16 ^ (br & 3)) << 3);
      bfrag bh = *(const bfrag*)&BsH[goff];
      bfrag bl = *(const bfrag*)&BsL[goff];
      acc[0][nn] = __builtin_amdgcn_mfma_f32_16x16x32_bf16(a0h, bh, acc[0][nn], 0, 0, 0);
      acc[1][nn] = __builtin_amdgcn_mfma_f32_16x16x32_bf16(a1h, bh, acc[1][nn], 0, 0, 0);
      acc[0][nn] = __builtin_amdgcn_mfma_f32_16x16x32_bf16(a0h, bl, acc[0][nn], 0, 0, 0);
      acc[1][nn] = __builtin_amdgcn_mfma_f32_16x16x32_bf16(a1h, bl, acc[1][nn], 0, 0, 0);
      acc[0][nn] = __builtin_amdgcn_mfma_f32_16x16x32_bf16(a0l, bh, acc[0][nn], 0, 0, 0);
      acc[1][nn] = __builtin_amdgcn_mfma_f32_16x16x32_bf16(a1l, bh, acc[1][nn], 0, 0, 0);
    }
    __syncthreads();
  }
  const int orow = (lane >> 4) << 2, ocol = lane & 15;
#pragma unroll
  for (int am = 0; am < 2; ++am) {
#pragma unroll
    for (int nn = 0; nn < 2; ++nn) {
      const int gn = n0 + wn * 32 + nn * 16 + ocol;
      if (gn >= Nvalid) continue;
      const float badd = bias[gn];
#pragma unroll
      for (int r = 0; r < 4; ++r) {
        const int gm = m0 + wm * 32 + am * 16 + orow + r;
        if (gm < Mvalid) C[(long long)gm * Cstride + gn] = acc[am][nn][r] + badd;
      }
    }
  }
}

// ---------------- GRU cell (device body) ----------------
DEV void cell_body(int i, const float* __restrict__ gi_s, const float* __restrict__ gh,
                   float* __restrict__ h, u16* __restrict__ hH, u16* __restrict__ hL) {
  int k = i % H, m = i / H;
  float ir = gi_s[m * H3 + k],         hr = gh[m * H3 + k];
  float iz = gi_s[m * H3 + H + k],     hz = gh[m * H3 + H + k];
  float in_ = gi_s[m * H3 + 2*H + k],  hn = gh[m * H3 + 2*H + k];
  float rr = sigm(ir + hr);
  float z = sigm(iz + hz);
  float n = tanhf(in_ + rr * hn);
  float hv = (1.f - z) * n + z * h[i];
  h[i] = hv;
  u16 hb = f2bf(hv);
  hH[m * KP + k] = hb;
  hL[m * KP + k] = f2bf(hv - bf2f(hb));
}

__global__ __launch_bounds__(512) void k_cell(const float* __restrict__ gi_s,
                                              const float* __restrict__ gh,
                                              float* __restrict__ h,
                                              u16* __restrict__ hH, u16* __restrict__ hL) {
  for (int i = blockIdx.x * 512 + threadIdx.x; i < M * H; i += CELLB * 512)
    cell_body(i, gi_s, gh, h, hH, hL);
}

// ---------------- k_big: [vocab GEMM ∥ attn chain ∥ gh GEMM(s+1)] ----------------
struct SMv { u16 Bs[2 * 4096]; float lpm[256][2]; float lps[256][2]; float bmax[256]; };
struct SMa { float hs[2][H]; float sat[2][T]; float sctx[2][H]; float red8[8]; };
struct SMg { u16 BsH[128 * 32]; u16 BsL[128 * 32]; };
union SMU { SMv v; SMa a; SMg g; };

__global__ __launch_bounds__(512) void k_big(
    const float* __restrict__ h, const u16* __restrict__ hH, const u16* __restrict__ hL,
    const u16* __restrict__ encb, const int* __restrict__ lens,
    const float* __restrict__ dec, const float* __restrict__ Wr, const float* __restrict__ br,
    const float* __restrict__ Wg, const float* __restrict__ bg,
    const u16* __restrict__ ebf,
    const u16* __restrict__ whhH, const u16* __restrict__ whhL, const float* __restrict__ bhh,
    float* __restrict__ attn, float* __restrict__ pgen,
    u16* __restrict__ ebuf, float* __restrict__ pmax, float* __restrict__ psum,
    float* __restrict__ gh, float* __restrict__ out, int s)
{
  __shared__ SMU sm;
  const int bx = blockIdx.x;
  const int tid = threadIdx.x;
  const int wave = tid >> 6, lane = tid & 63;

  if (bx < NVB) {
    // ===== vocab GEMM: 256x128 tile, A direct from L2, B 2-phase dbuf pipeline =====
    const int wm = wave >> 1, wn = wave & 1;     // wm 0..3 (64-row slab), wn 0..1
    const int nb = bx % NBLK;
    const int n0 = nb * 128;
    const int m0 = (bx / NBLK) * 256;
    const int lrow = lane & 15;
    const int c16 = lane >> 4;
    const int srow = tid >> 2;                   // B-stage row 0..127
    const int sg = (tid & 3) ^ (srow & 3);       // inverse-swizzled source granule
    f32x4 acc[4][4] = {};                        // [af 16-row][nn 16-col]

    const u16* aBase = hH + (size_t)(m0 + wm * 64 + lrow) * KP + c16 * 8;
    const u16* bS = ebf + (size_t)(n0 + srow) * KP + sg * 8;
    u16* lB0 = sm.v.Bs + wave * 512;             // buf0, this wave's 1KB chunk
    u16* lB1 = sm.v.Bs + 4096 + wave * 512;      // buf1

    gload16(bS, lB0);                            // prefetch k-tile 0
    int cur = 0;
#pragma unroll 1
    for (int kk = 0; kk < 13; ++kk) {
      // A-frags for this k-tile (issued before the stage so the stage stays newest)
      bfrag af0 = *(const bfrag*)(aBase + 0 * 16 * KP + kk * 32);
      bfrag af1 = *(const bfrag*)(aBase + 1 * 16 * KP + kk * 32);
      bfrag af2 = *(const bfrag*)(aBase + 2 * 16 * KP + kk * 32);
      bfrag af3 = *(const bfrag*)(aBase + 3 * 16 * KP + kk * 32);
      if (kk < 12) {
        gload16(bS + (kk + 1) * 32, cur ? lB0 : lB1);
        // oldest outstanding = stage(kk): forcing it leaves A(4)+stage(kk+1)=5 in flight
        asm volatile("s_waitcnt vmcnt(5)" ::: "memory");
      } else {
        asm volatile("s_waitcnt vmcnt(4)" ::: "memory");
      }
      __builtin_amdgcn_sched_barrier(0);
      __builtin_amdgcn_s_barrier();              // buf[cur] ready for all waves
      const u16* Bb = sm.v.Bs + (cur ? 4096 : 0);
      bfrag bfv[4];
#pragma unroll
      for (int nn = 0; nn < 4; ++nn) {
        const int brr = wn * 64 + nn * 16 + lrow;
        bfv[nn] = *(const bfrag*)&Bb[brr * 32 + ((c16 ^ (brr & 3)) << 3)];
      }
#pragma unroll
      for (int nn = 0; nn < 4; ++nn) {
        acc[0][nn] = __builtin_amdgcn_mfma_f32_16x16x32_bf16(af0, bfv[nn], acc[0][nn], 0, 0, 0);
        acc[1][nn] = __builtin_amdgcn_mfma_f32_16x16x32_bf16(af1, bfv[nn], acc[1][nn], 0, 0, 0);
        acc[2][nn] = __builtin_amdgcn_mfma_f32_16x16x32_bf16(af2, bfv[nn], acc[2][nn], 0, 0, 0);
        acc[3][nn] = __builtin_amdgcn_mfma_f32_16x16x32_bf16(af3, bfv[nn], acc[3][nn], 0, 0, 0);
      }
      __builtin_amdgcn_sched_barrier(0);
      __builtin_amdgcn_s_barrier();              // all waves done reading buf[cur]
      cur ^= 1;
    }
    __syncthreads();

    const int orow = (lane >> 4) << 2, ocol = lane & 15;
    // per-row max over this wave's 64 cols
#pragma unroll
    for (int af_i = 0; af_i < 4; ++af_i) {
#pragma unroll
      for (int r = 0; r < 4; ++r) {
        float mxv = -1e30f;
#pragma unroll
        for (int nn = 0; nn < 4; ++nn) {
          const int gn = n0 + wn * 64 + nn * 16 + ocol;
          if (gn < V) mxv = fmaxf(mxv, acc[af_i][nn][r]);
        }
#pragma unroll
        for (int d = 1; d < 16; d <<= 1) mxv = fmaxf(mxv, __shfl_xor(mxv, d));
        if ((lane & 15) == 0) sm.v.lpm[wm * 64 + af_i * 16 + orow + r][wn] = mxv;
      }
    }
    __syncthreads();
    if (tid < 256) sm.v.bmax[tid] = fmaxf(sm.v.lpm[tid][0], sm.v.lpm[tid][1]);
    __syncthreads();
#pragma unroll
    for (int af_i = 0; af_i < 4; ++af_i) {
#pragma unroll
      for (int r = 0; r < 4; ++r) {
        const int rl = wm * 64 + af_i * 16 + orow + r;
        const int gm = m0 + rl;
        const float bm = sm.v.bmax[rl];
        float se = 0.f;
#pragma unroll
        for (int nn = 0; nn < 4; ++nn) {
          const int gn = n0 + wn * 64 + nn * 16 + ocol;
          if (gn < V) {
            float e = __expf(acc[af_i][nn][r] - bm);
            se += e;
            if (gm < M) ebuf[(size_t)gm * VP + gn] = f2bf(e);
          }
        }
#pragma unroll
        for (int d = 1; d < 16; d <<= 1) se += __shfl_xor(se, d);
        if ((lane & 15) == 0) sm.v.lps[rl][wn] = se;
      }
    }
    __syncthreads();
    if (tid < 256) {
      const int gm = m0 + tid;
      if (gm < M) {
        pmax[(size_t)gm * NBLK + nb] = sm.v.bmax[tid];
        psum[(size_t)gm * NBLK + nb] = sm.v.lps[tid][0] + sm.v.lps[tid][1];
      }
    }
  } else if (bx < NVB + NAB) {
    // ================= attn chain branch =================
    const int ab = bx - NVB;
    const int b = ab % B;
    const int s0 = (ab / B) * 2;
    const int mm[2] = { s0 * B + b, (s0 + 1) * B + b };
    const int len = lens[b];
    const float* dec_s = dec + (size_t)s * M * H;

#pragma unroll
    for (int r = 0; r < 2; ++r)
      if (tid < H) sm.a.hs[r][tid] = h[mm[r] * H + tid];
    __syncthreads();

    // phase 1: logits
    float hreg[2][8];
    if (lane < 50) {
#pragma unroll
      for (int j = 0; j < 8; ++j) { hreg[0][j] = sm.a.hs[0][lane * 8 + j]; hreg[1][j] = sm.a.hs[1][lane * 8 + j]; }
    }
    for (int t = wave * 50; t < wave * 50 + 50; ++t) {
      if (t >= len) { if (lane == 0) { sm.a.sat[0][t] = -1e30f; sm.a.sat[1][t] = -1e30f; } continue; }
      float a0 = 0.f, a1 = 0.f;
      if (lane < 50) {
        bfrag ev = *(const bfrag*)(encb + ((size_t)b * T + t) * H + lane * 8);
#pragma unroll
        for (int j = 0; j < 8; ++j) {
          float e = bf2f((u16)ev[j]);
          a0 = fmaf(hreg[0][j], e, a0);
          a1 = fmaf(hreg[1][j], e, a1);
        }
      }
#pragma unroll
      for (int off = 32; off; off >>= 1) { a0 += __shfl_xor(a0, off); a1 += __shfl_xor(a1, off); }
      if (lane == 0) { sm.a.sat[0][t] = a0; sm.a.sat[1][t] = a1; }
    }
    __syncthreads();

    // phase 2: softmax
#pragma unroll
    for (int r = 0; r < 2; ++r) {
      float v = (tid < T) ? sm.a.sat[r][tid] : -1e30f;
      float wv = v;
#pragma unroll
      for (int off = 32; off; off >>= 1) wv = fmaxf(wv, __shfl_xor(wv, off));
      if (lane == 0) sm.a.red8[wave] = wv;
      __syncthreads();
      float mx = sm.a.red8[0];
#pragma unroll
      for (int j = 1; j < 8; ++j) mx = fmaxf(mx, sm.a.red8[j]);
      __syncthreads();
      float e = (tid < len) ? __expf(v - mx) : 0.f;
      float ws = e;
#pragma unroll
      for (int off = 32; off; off >>= 1) ws += __shfl_xor(ws, off);
      if (lane == 0) sm.a.red8[wave] = ws;
      __syncthreads();
      float smm = 0.f;
#pragma unroll
      for (int j = 0; j < 8; ++j) smm += sm.a.red8[j];
      float inv = 1.f / smm;
      __syncthreads();
      if (tid < T) {
        float av = e * inv;
        sm.a.sat[r][tid] = av;
        attn[(size_t)mm[r] * T + tid] = av;
      }
    }
    __syncthreads();

    // phase 3: context
    if (tid < H) {
      float c0 = 0.f, c1 = 0.f;
      const u16* eb = encb + (size_t)b * T * H + tid;
      for (int t = 0; t < len; ++t) {
        float ev = bf2f(eb[(size_t)t * H]);
        c0 = fmaf(sm.a.sat[0][t], ev, c0);
        c1 = fmaf(sm.a.sat[1][t], ev, c1);
      }
      sm.a.sctx[0][tid] = c0; sm.a.sctx[1][tid] = c1;
    }
    __syncthreads();

    // phase 4: p_gen / gates
    if (wave < 2) {
      const int r = wave, m = mm[r];
      float p = 0.f;
#pragma unroll
      for (int i = 0; i < 7; ++i) {
        int k = lane + 64 * i;
        if (k < H)
          p += sm.a.hs[r][k] * Wr[k] + sm.a.sctx[r][k] * Wr[H + k] + dec_s[m * H + k] * Wr[2 * H + k];
      }
#pragma unroll
      for (int off = 32; off; off >>= 1) p += __shfl_xor(p, off);
      if (lane == 0) pgen[m] = sigm(p + br[0]);
    } else if (s == 0) {
      const int idx = wave - 2;
      const int r = idx / NG, g = idx % NG;
      float a = 0.f;
#pragma unroll
      for (int i = 0; i < 7; ++i) {
        int k = lane + 64 * i;
        if (k < H) a = fmaf(sm.a.sctx[r][k], Wg[g * H + k], a);
      }
#pragma unroll
      for (int off = 32; off; off >>= 1) a += __shfl_xor(a, off);
      if (lane == 0) out[PTS + (long long)mm[r] * NG + g] = a + bg[g];
    }
  } else {
    // ================= gh GEMM branch (for step s+1) =================
    if (s >= STEPS - 1) return;
    const int gb = bx - NVB - NAB;
    const int wm = wave >> 1, wn = wave & 1;
    const int n0 = (gb % (NWP / 128)) * 128;
    const int m0 = (gb / (NWP / 128)) * 128;
    const int lrow = lane & 15;
    const int c16 = lane >> 4;
    const int srow = tid >> 2;
    const int sg = (tid & 3) ^ (srow & 3);
    f32x4 acc[2][4] = {};

    const u16* aH = hH + (size_t)(m0 + wm * 32 + lrow) * KP + c16 * 8;
    const u16* aL = hL + (size_t)(m0 + wm * 32 + lrow) * KP + c16 * 8;
    const u16* bHs = whhH + (size_t)(n0 + srow) * KP + sg * 8;
    const u16* bLs = whhL + (size_t)(n0 + srow) * KP + sg * 8;
    u16* lBH = sm.g.BsH + wave * 512;
    u16* lBL = sm.g.BsL + wave * 512;

    for (int kk = 0; kk < KP / 32; ++kk) {
      const int kb = kk * 32;
      gload16(bHs + kb, lBH);
      gload16(bLs + kb, lBL);
      __syncthreads();
      bfrag a0h = *(const bfrag*)(aH + kb);
      bfrag a1h = *(const bfrag*)(aH + 16 * KP + kb);
      bfrag a0l = *(const bfrag*)(aL + kb);
      bfrag a1l = *(const bfrag*)(aL + 16 * KP + kb);
#pragma unroll
      for (int nn = 0; nn < 4; ++nn) {
        const int brw = wn * 64 + nn * 16 + lrow;
        const int goff = brw * 32 + ((c16 ^ (brw & 3)) << 3);
        bfrag bh = *(const bfrag*)&sm.g.BsH[goff];
        bfrag bl = *(const bfrag*)&sm.g.BsL[goff];
        acc[0][nn] = __builtin_amdgcn_mfma_f32_16x16x32_bf16(a0h, bh, acc[0][nn], 0, 0, 0);
        acc[1][nn] = __builtin_amdgcn_mfma_f32_16x16x32_bf16(a1h, bh, acc[1][nn], 0, 0, 0);
        acc[0][nn] = __builtin_amdgcn_mfma_f32_16x16x32_bf16(a0h, bl, acc[0][nn], 0, 0, 0);
        acc[1][nn] = __builtin_amdgcn_mfma_f32_16x16x32_bf16(a1h, bl, acc[1][nn], 0, 0, 0);
        acc[0][nn] = __builtin_amdgcn_mfma_f32_16x16x32_bf16(a0l, bh, acc[0][nn], 0, 0, 0);
        acc[1][nn] = __builtin_amdgcn_mfma_f32_16x16x32_bf16(a1l, bh, acc[1][nn], 0, 0, 0);
      }
      __syncthreads();
    }
    const int orow = (lane >> 4) << 2, ocol = lane & 15;
#pragma unroll
    for (int am = 0; am < 2; ++am) {
#pragma unroll
      for (int nn = 0; nn < 4; ++nn) {
        const int gn = n0 + wn * 64 + nn * 16 + ocol;
        if (gn >= H3) continue;
        const float badd = bhh[gn];
#pragma unroll
        for (int r = 0; r < 4; ++r) {
          const int gm = m0 + wm * 32 + am * 16 + orow + r;
          if (gm < M) gh[(long long)gm * H3 + gn] = acc[am][nn][r] + badd;
        }
      }
    }
  }
}

// ---------------- k_merge: [vocab_out(s) ∥ GRU cell(s+1)] ----------------
__global__ __launch_bounds__(512) void k_merge(
    const u16* __restrict__ ebuf, const float* __restrict__ pmax,
    const float* __restrict__ psum, const float* __restrict__ pgen,
    const float* __restrict__ attn, const int* __restrict__ story,
    const float* __restrict__ gi_next, const float* __restrict__ gh,
    float* __restrict__ h, u16* __restrict__ hH, u16* __restrict__ hL,
    float* __restrict__ out, int s, int do_cell)
{
  const int tid = threadIdx.x;
  if (blockIdx.x < (unsigned)M) {
    const int m = blockIdx.x, b = m % B;
    const int wave = tid >> 6, lane = tid & 63;
    __shared__ float fact[NBLK], red8[8];
    float pm = (tid < NBLK) ? pmax[(size_t)m * NBLK + tid] : -1e30f;
    float wv = pm;
#pragma unroll
    for (int off = 32; off; off >>= 1) wv = fmaxf(wv, __shfl_xor(wv, off));
    if (lane == 0) red8[wave] = wv;
    __syncthreads();
    float Mx = red8[0];
#pragma unroll
    for (int j = 1; j < 8; ++j) Mx = fmaxf(Mx, red8[j]);
    __syncthreads();
    float sv = (tid < NBLK) ? psum[(size_t)m * NBLK + tid] * __expf(pm - Mx) : 0.f;
    float ws = sv;
#pragma unroll
    for (int off = 32; off; off >>= 1) ws += __shfl_xor(ws, off);
    if (lane == 0) red8[wave] = ws;
    __syncthreads();
    float Sv = 0.f;
#pragma unroll
    for (int j = 0; j < 8; ++j) Sv += red8[j];
    const float pg = pgen[m];
    const float scale = pg / Sv;
    if (tid < NBLK) fact[tid] = __expf(pm - Mx) * scale;
    __syncthreads();

    const u16* erow = ebuf + (size_t)m * VP;
    float* orow = out + ((size_t)m * STEPS + s) * V;
    for (int v = tid; v < V; v += 512) orow[v] = bf2f(erow[v]) * fact[v >> 7];
    __syncthreads();
    const float om = 1.f - pg;
    for (int t = tid; t < T; t += 512) {
      float a = attn[(size_t)m * T + t];
      if (a != 0.f) atomicAdd(orow + story[b * T + t], om * a);
    }
  } else if (do_cell) {
    for (int i = (blockIdx.x - M) * 512 + tid; i < M * H; i += CELLB * 512)
      cell_body(i, gi_next, gh, h, hH, hL);
  }
}

// ---------------- launch ----------------

extern "C" void kernel_launch(void* const* d_in, const int* in_sizes, int n_in,
                              void* d_out, int out_size, void* d_ws, size_t ws_size,
                              hipStream_t stream) {
  (void)in_sizes; (void)n_in; (void)out_size; (void)ws_size;
  const float* emb  = (const float*)d_in[0];
  const float* Wih  = (const float*)d_in[1];
  const float* Whh  = (const float*)d_in[2];
  const float* bih  = (const float*)d_in[3];
  const float* bhh  = (const float*)d_in[4];
  const float* Wr   = (const float*)d_in[5];
  const float* br   = (const float*)d_in[6];
  const float* Wg   = (const float*)d_in[7];
  const float* bg   = (const float*)d_in[8];
  const float* semb = (const float*)d_in[9];
  const float* ehid = (const float*)d_in[10];
  const float* enc  = (const float*)d_in[11];
  const int*   lens = (const int*)d_in[12];
  const int*   story= (const int*)d_in[13];
  const int*   tgt  = (const int*)d_in[14];
  float* out = (float*)d_out;

  char* w = (char*)d_ws;
  size_t off = 0;
  auto alloc = [&](size_t n) -> void* {
    void* p = w + off;
    off = (off + n + 255) & ~(size_t)255;
    return p;
  };
  u16* ebf   = (u16*)alloc((size_t)VP * KP * 2);
  u16* wihH  = (u16*)alloc((size_t)NWP * KP * 2);
  u16* wihL  = (u16*)alloc((size_t)NWP * KP * 2);
  u16* whhH  = (u16*)alloc((size_t)NWP * KP * 2);
  u16* whhL  = (u16*)alloc((size_t)NWP * KP * 2);
  u16* decH  = (u16*)alloc((size_t)STEPS * MP * KP * 2);
  u16* decL  = (u16*)alloc((size_t)STEPS * MP * KP * 2);
  float* dec = (float*)alloc((size_t)STEPS * M * H * 4);
  float* h   = (float*)alloc((size_t)M * H * 4);
  u16* hH    = (u16*)alloc((size_t)MP * KP * 2);
  u16* hL    = (u16*)alloc((size_t)MP * KP * 2);
  float* gi  = (float*)alloc((size_t)STEPS * MP * H3 * 4);
  float* gh  = (float*)alloc((size_t)M * H3 * 4);
  float* attn= (float*)alloc((size_t)M * T * 4);
  float* pgen= (float*)alloc((size_t)M * 4);
  u16* ebuf  = (u16*)alloc((size_t)MP * VP * 2);
  float* pmx = (float*)alloc((size_t)MP * NBLK * 4);
  float* psm = (float*)alloc((size_t)MP * NBLK * 4);
  u16* encb  = (u16*)alloc((size_t)B * T * H * 2);

  k_convert_emb<<<VP * KP / 256, 256, 0, stream>>>(emb, ebf);
  k_convert_enc<<<(B * T * H + 255) / 256, 256, 0, stream>>>(enc, encb);
  k_convert_w<<<NWP * KP / 256, 256, 0, stream>>>(Wih, Whh, wihH, wihL, whhH, whhL);
  k_init_dec<<<STEPS * MP * KP / 256, 256, 0, stream>>>(emb, semb, tgt, dec, decH, decL);
  k_init_h<<<MP * KP / 256, 256, 0, stream>>>(ehid, h, hH, hL);
  // all-steps gi = dec @ Wih^T + bih
  k_gemm64s<<<dim3((H3 + 63) / 64, STEPS * MP / 64), 256, 0, stream>>>(
      decH, decL, wihH, wihL, bih, gi, STEPS * MP, H3, H3);
  // gh(0) = h_init @ Whh^T + bhh
  k_gemm64s<<<dim3((H3 + 63) / 64, (M + 63) / 64), 256, 0, stream>>>(
      hH, hL, whhH, whhL, bhh, gh, M, H3, H3);
  // cell(0): h_0
  k_cell<<<CELLB, 512, 0, stream>>>(gi, gh, h, hH, hL);

  for (int s = 0; s < STEPS; ++s) {
    k_big<<<NVB + NAB + NGB, 512, 0, stream>>>(
        h, hH, hL, encb, lens, dec, Wr, br, Wg, bg, ebf,
        whhH, whhL, bhh, attn, pgen, ebuf, pmx, psm, gh, out, s);
    const int do_cell = (s < STEPS - 1) ? 1 : 0;
    k_merge<<<M + (do_cell ? CELLB : 0), 512, 0, stream>>>(
        ebuf, pmx, psm, pgen, attn, story,
        gi + (size_t)(s + 1) * MP * H3, gh, h, hH, hL, out, s, do_cell);
  }
}

// Round 7
// 756.676 us; speedup vs baseline: 3.1082x; 1.1469x over previous
//
#include <hip/hip_runtime.h>

#define DEV __device__ __forceinline__

constexpr int B = 16, T = 400, H = 400, V = 22000, S = 30, STEPS = 8, NG = 3;
constexpr int M  = S * B;      // 480 (slot,b) rows
constexpr int H3 = 3 * H;      // 1200
constexpr int KP = 416;        // K padded to 13*32
constexpr int VP = 22016;      // V padded to 172*128
constexpr int MP = 512;        // M padded (per step slot)
constexpr int MR = STEPS * MP; // 4096 batched rows for vocab GEMM
constexpr int NWP = 1280;      // GRU weight rows padded
constexpr int NBLK = VP / 128; // 172 vocab col-blocks
constexpr int NMP = MR / 256;  // 16 m-panels (256-row tiles)
constexpr int NVB = NBLK * NMP;// 2752 vocab blocks (8 | 2752)
constexpr int NAB = M / 2;     // 240 attn pair-blocks per step
constexpr int NABT = NAB * STEPS; // 1920 attn blocks total
constexpr long long PTS = (long long)S * B * STEPS * V;  // 84,480,000

typedef __attribute__((ext_vector_type(8))) short bfrag;
typedef __attribute__((ext_vector_type(4))) float f32x4;
typedef unsigned short u16;

DEV u16 f2bf(float x) {
  unsigned u = __float_as_uint(x);
  u += 0x7FFFu + ((u >> 16) & 1u);
  return (u16)(u >> 16);
}
DEV float bf2f(u16 h) { return __uint_as_float(((unsigned)h) << 16); }
DEV float sigm(float x) { return 1.0f / (1.0f + __expf(-x)); }

DEV void gload16(const u16* g, u16* l) {
  __builtin_amdgcn_global_load_lds(
      (const __attribute__((address_space(1))) void*)g,
      (__attribute__((address_space(3))) void*)l, 16, 0, 0);
}

// ---------------- init / conversion ----------------

__global__ void k_convert_emb(const float* __restrict__ emb, u16* __restrict__ ebf) {
  int i = blockIdx.x * 256 + threadIdx.x;
  if (i >= VP * KP) return;
  int v = i / KP, k = i % KP;
  float val = (v < V && k < H) ? emb[(long long)v * H + k] : 0.f;
  ebf[i] = f2bf(val);
}

__global__ void k_convert_enc(const float* __restrict__ enc, u16* __restrict__ encb) {
  int i = blockIdx.x * 256 + threadIdx.x;
  if (i >= B * T * H) return;
  encb[i] = f2bf(enc[i]);
}

__global__ void k_convert_w(const float* __restrict__ Wih, const float* __restrict__ Whh,
                            u16* __restrict__ wihH, u16* __restrict__ wihL,
                            u16* __restrict__ whhH, u16* __restrict__ whhL) {
  int i = blockIdx.x * 256 + threadIdx.x;
  if (i >= NWP * KP) return;
  int n = i / KP, k = i % KP;
  float v1 = (n < H3 && k < H) ? Wih[n * H + k] : 0.f;
  u16 h1 = f2bf(v1);
  wihH[i] = h1; wihL[i] = f2bf(v1 - bf2f(h1));
  float v2 = (n < H3 && k < H) ? Whh[n * H + k] : 0.f;
  u16 h2 = f2bf(v2);
  whhH[i] = h2; whhL[i] = f2bf(v2 - bf2f(h2));
}

__global__ void k_init_dec(const float* __restrict__ emb, const float* __restrict__ semb,
                           const int* __restrict__ tgt, float* __restrict__ dec,
                           u16* __restrict__ dH, u16* __restrict__ dL) {
  int i = blockIdx.x * 256 + threadIdx.x;
  if (i >= STEPS * MP * KP) return;
  int k = i % KP, m = (i / KP) % MP, s = i / (KP * MP);
  float val = 0.f;
  if (m < M && k < H) {
    int slot = m / B, b = m % B;
    if (s == 0) val = semb[slot * H + k];
    else        val = emb[(long long)tgt[(b * S + slot) * STEPS + (s - 1)] * H + k];
    dec[((long long)s * M + m) * H + k] = val;
  }
  u16 hi = f2bf(val);
  dH[i] = hi; dL[i] = f2bf(val - bf2f(hi));
}

// h0 (init hidden): f32 + hi/lo bf16 (pads zeroed)
__global__ void k_init_h(const float* __restrict__ ehid, float* __restrict__ h0F,
                         u16* __restrict__ hH, u16* __restrict__ hL) {
  int i = blockIdx.x * 256 + threadIdx.x;
  if (i >= MP * KP) return;
  int k = i % KP, m = i / KP;
  float val = (m < M && k < H) ? ehid[(m % B) * H + k] : 0.f;
  if (m < M && k < H) h0F[m * H + k] = val;
  u16 hi = f2bf(val);
  hH[i] = hi; hL[i] = f2bf(val - bf2f(hi));
}

// zero the pad rows (m in [M,MP)) of all step slots of hAllH/hAllL
__global__ void k_zero_pad(u16* __restrict__ hAllH, u16* __restrict__ hAllL) {
  int i = blockIdx.x * 256 + threadIdx.x;
  if (i >= STEPS * (MP - M) * KP) return;
  int k = i % KP;
  int row = M + (i / KP) % (MP - M);
  int s = i / (KP * (MP - M));
  size_t idx = ((size_t)s * MP + row) * KP + k;
  hAllH[idx] = 0; hAllL[idx] = 0;
}

// ---------------- 64x64-tile SPLIT GEMM (gi batched, gh per step) ----------------
__global__ __launch_bounds__(256) void k_gemm64s(
    const u16* __restrict__ Ahi, const u16* __restrict__ Alo,
    const u16* __restrict__ Bmh, const u16* __restrict__ Bml,
    const float* __restrict__ bias, float* __restrict__ C,
    int Mvalid, int Nvalid, int Cstride)
{
  __shared__ u16 BsH[64 * 32], BsL[64 * 32];
  const int tid = threadIdx.x;
  const int wave = tid >> 6, lane = tid & 63;
  const int wm = wave >> 1, wn = wave & 1;
  const int n0 = blockIdx.x * 64;
  const int m0 = blockIdx.y * 64;
  const int lrow = lane & 15;
  const int c16 = lane >> 4;
  const int srow = tid >> 2;
  const int sg = (tid & 3) ^ (srow & 3);
  f32x4 acc[2][2] = {};

  const u16* aH = Ahi + (size_t)(m0 + wm * 32 + lrow) * KP + c16 * 8;
  const u16* aL = Alo + (size_t)(m0 + wm * 32 + lrow) * KP + c16 * 8;
  const u16* bHs = Bmh + (size_t)(n0 + srow) * KP + sg * 8;
  const u16* bLs = Bml + (size_t)(n0 + srow) * KP + sg * 8;
  u16* lBH = BsH + wave * 512;
  u16* lBL = BsL + wave * 512;

  for (int kk = 0; kk < KP / 32; ++kk) {
    const int kb = kk * 32;
    gload16(bHs + kb, lBH);
    gload16(bLs + kb, lBL);
    __syncthreads();
    bfrag a0h = *(const bfrag*)(aH + kb);
    bfrag a1h = *(const bfrag*)(aH + 16 * KP + kb);
    bfrag a0l = *(const bfrag*)(aL + kb);
    bfrag a1l = *(const bfrag*)(aL + 16 * KP + kb);
#pragma unroll
    for (int nn = 0; nn < 2; ++nn) {
      const int br = wn * 32 + nn * 16 + lrow;
      const int goff = br * 32 + ((c16 ^ (br & 3)) << 3);
      bfrag bh = *(const bfrag*)&BsH[goff];
      bfrag bl = *(const bfrag*)&BsL[goff];
      acc[0][nn] = __builtin_amdgcn_mfma_f32_16x16x32_bf16(a0h, bh, acc[0][nn], 0, 0, 0);
      acc[1][nn] = __builtin_amdgcn_mfma_f32_16x16x32_bf16(a1h, bh, acc[1][nn], 0, 0, 0);
      acc[0][nn] = __builtin_amdgcn_mfma_f32_16x16x32_bf16(a0h, bl, acc[0][nn], 0, 0, 0);
      acc[1][nn] = __builtin_amdgcn_mfma_f32_16x16x32_bf16(a1h, bl, acc[1][nn], 0, 0, 0);
      acc[0][nn] = __builtin_amdgcn_mfma_f32_16x16x32_bf16(a0l, bh, acc[0][nn], 0, 0, 0);
      acc[1][nn] = __builtin_amdgcn_mfma_f32_16x16x32_bf16(a1l, bh, acc[1][nn], 0, 0, 0);
    }
    __syncthreads();
  }
  const int orow = (lane >> 4) << 2, ocol = lane & 15;
#pragma unroll
  for (int am = 0; am < 2; ++am) {
#pragma unroll
    for (int nn = 0; nn < 2; ++nn) {
      const int gn = n0 + wn * 32 + nn * 16 + ocol;
      if (gn >= Nvalid) continue;
      const float badd = bias[gn];
#pragma unroll
      for (int r = 0; r < 4; ++r) {
        const int gm = m0 + wm * 32 + am * 16 + orow + r;
        if (gm < Mvalid) C[(long long)gm * Cstride + gn] = acc[am][nn][r] + badd;
      }
    }
  }
}

// ---------------- GRU cell: hprevF -> hcurF (+ hi/lo slot for this step) ----------------
__global__ __launch_bounds__(512) void k_cell(const float* __restrict__ gi_s,
                                              const float* __restrict__ gh,
                                              const float* __restrict__ hprevF,
                                              float* __restrict__ hcurF,
                                              u16* __restrict__ hHc, u16* __restrict__ hLc) {
  int i = blockIdx.x * 512 + threadIdx.x;
  if (i >= M * H) return;
  int k = i % H, m = i / H;
  float ir = gi_s[m * H3 + k],         hr = gh[m * H3 + k];
  float iz = gi_s[m * H3 + H + k],     hz = gh[m * H3 + H + k];
  float in_ = gi_s[m * H3 + 2*H + k],  hn = gh[m * H3 + 2*H + k];
  float rr = sigm(ir + hr);
  float z = sigm(iz + hz);
  float n = tanhf(in_ + rr * hn);
  float hv = (1.f - z) * n + z * hprevF[i];
  hcurF[i] = hv;
  u16 hb = f2bf(hv);
  hHc[m * KP + k] = hb;
  hLc[m * KP + k] = f2bf(hv - bf2f(hb));
}

// ---------------- k_big: [batched vocab GEMM (all steps) ∥ attn (all steps)] ----------------
struct SMv { u16 Bs[2 * 4096]; float lpm[256][2]; float lps[256][2]; float bmax[256]; };
struct SMa { float hs[2][H]; float sat[2][T]; float sctx[2][H]; float red8[8]; };
union SMU { SMv v; SMa a; };

__global__ __launch_bounds__(512) void k_big(
    const u16* __restrict__ hAllH, const float* __restrict__ hallF,
    const u16* __restrict__ encb, const int* __restrict__ lens,
    const float* __restrict__ dec, const float* __restrict__ Wr, const float* __restrict__ br,
    const float* __restrict__ Wg, const float* __restrict__ bg,
    const u16* __restrict__ ebf,
    float* __restrict__ attnB, float* __restrict__ pgenB,
    u16* __restrict__ ebuf, float* __restrict__ pmax, float* __restrict__ psum,
    float* __restrict__ out)
{
  __shared__ SMU sm;
  const int bx = blockIdx.x;
  const int tid = threadIdx.x;
  const int wave = tid >> 6, lane = tid & 63;

  if (bx < NVB) {
    // ===== vocab GEMM: 256x128 tiles over MR=4096 rows; XCD-swizzled =====
    const int bxs = (bx & 7) * (NVB / 8) + (bx >> 3);   // bijective (NVB%8==0)
    const int nb = bxs / NMP;
    const int mp = bxs % NMP;
    const int n0 = nb * 128;
    const int m0 = mp * 256;
    const int wm = wave >> 1, wn = wave & 1;
    const int lrow = lane & 15;
    const int c16 = lane >> 4;
    const int srow = tid >> 2;
    const int sg = (tid & 3) ^ (srow & 3);
    f32x4 acc[4][4] = {};

    const u16* aBase = hAllH + (size_t)(m0 + wm * 64 + lrow) * KP + c16 * 8;
    const u16* bS = ebf + (size_t)(n0 + srow) * KP + sg * 8;
    u16* lB0 = sm.v.Bs + wave * 512;
    u16* lB1 = sm.v.Bs + 4096 + wave * 512;

    gload16(bS, lB0);
    int cur = 0;
#pragma unroll 1
    for (int kk = 0; kk < 13; ++kk) {
      bfrag af0 = *(const bfrag*)(aBase + 0 * 16 * KP + kk * 32);
      bfrag af1 = *(const bfrag*)(aBase + 1 * 16 * KP + kk * 32);
      bfrag af2 = *(const bfrag*)(aBase + 2 * 16 * KP + kk * 32);
      bfrag af3 = *(const bfrag*)(aBase + 3 * 16 * KP + kk * 32);
      if (kk < 12) {
        gload16(bS + (kk + 1) * 32, cur ? lB0 : lB1);
        asm volatile("s_waitcnt vmcnt(5)" ::: "memory");
      } else {
        asm volatile("s_waitcnt vmcnt(4)" ::: "memory");
      }
      __builtin_amdgcn_sched_barrier(0);
      __builtin_amdgcn_s_barrier();
      const u16* Bb = sm.v.Bs + (cur ? 4096 : 0);
      bfrag bfv[4];
#pragma unroll
      for (int nn = 0; nn < 4; ++nn) {
        const int brr = wn * 64 + nn * 16 + lrow;
        bfv[nn] = *(const bfrag*)&Bb[brr * 32 + ((c16 ^ (brr & 3)) << 3)];
      }
#pragma unroll
      for (int nn = 0; nn < 4; ++nn) {
        acc[0][nn] = __builtin_amdgcn_mfma_f32_16x16x32_bf16(af0, bfv[nn], acc[0][nn], 0, 0, 0);
        acc[1][nn] = __builtin_amdgcn_mfma_f32_16x16x32_bf16(af1, bfv[nn], acc[1][nn], 0, 0, 0);
        acc[2][nn] = __builtin_amdgcn_mfma_f32_16x16x32_bf16(af2, bfv[nn], acc[2][nn], 0, 0, 0);
        acc[3][nn] = __builtin_amdgcn_mfma_f32_16x16x32_bf16(af3, bfv[nn], acc[3][nn], 0, 0, 0);
      }
      __builtin_amdgcn_sched_barrier(0);
      __builtin_amdgcn_s_barrier();
      cur ^= 1;
    }
    __syncthreads();

    const int orow = (lane >> 4) << 2, ocol = lane & 15;
#pragma unroll
    for (int af_i = 0; af_i < 4; ++af_i) {
#pragma unroll
      for (int r = 0; r < 4; ++r) {
        float mxv = -1e30f;
#pragma unroll
        for (int nn = 0; nn < 4; ++nn) {
          const int gn = n0 + wn * 64 + nn * 16 + ocol;
          if (gn < V) mxv = fmaxf(mxv, acc[af_i][nn][r]);
        }
#pragma unroll
        for (int d = 1; d < 16; d <<= 1) mxv = fmaxf(mxv, __shfl_xor(mxv, d));
        if ((lane & 15) == 0) sm.v.lpm[wm * 64 + af_i * 16 + orow + r][wn] = mxv;
      }
    }
    __syncthreads();
    if (tid < 256) sm.v.bmax[tid] = fmaxf(sm.v.lpm[tid][0], sm.v.lpm[tid][1]);
    __syncthreads();
#pragma unroll
    for (int af_i = 0; af_i < 4; ++af_i) {
#pragma unroll
      for (int r = 0; r < 4; ++r) {
        const int rl = wm * 64 + af_i * 16 + orow + r;
        const int R = m0 + rl;                 // global batched row (s*MP + m)
        const bool ok = (R % MP) < M;
        const float bm = sm.v.bmax[rl];
        float se = 0.f;
#pragma unroll
        for (int nn = 0; nn < 4; ++nn) {
          const int gn = n0 + wn * 64 + nn * 16 + ocol;
          if (gn < V) {
            float e = __expf(acc[af_i][nn][r] - bm);
            se += e;
            if (ok) ebuf[(size_t)R * VP + gn] = f2bf(e);
          }
        }
#pragma unroll
        for (int d = 1; d < 16; d <<= 1) se += __shfl_xor(se, d);
        if ((lane & 15) == 0) sm.v.lps[rl][wn] = se;
      }
    }
    __syncthreads();
    if (tid < 256) {
      const int R = m0 + tid;
      if ((R % MP) < M) {
        pmax[(size_t)R * NBLK + nb] = sm.v.bmax[tid];
        psum[(size_t)R * NBLK + nb] = sm.v.lps[tid][0] + sm.v.lps[tid][1];
      }
    }
  } else {
    // ================= attn chain (one block = one step x slot-pair) =================
    const int ab0 = bx - NVB;
    const int s = ab0 / NAB;
    const int ab = ab0 % NAB;
    const int b = ab % B;
    const int s0 = (ab / B) * 2;
    const int mm[2] = { s0 * B + b, (s0 + 1) * B + b };
    const int len = lens[b];
    const float* dec_s = dec + (size_t)s * M * H;
    const float* hF = hallF + (size_t)s * M * H;

#pragma unroll
    for (int r = 0; r < 2; ++r)
      if (tid < H) sm.a.hs[r][tid] = hF[mm[r] * H + tid];
    __syncthreads();

    // phase 1: logits
    float hreg[2][8];
    if (lane < 50) {
#pragma unroll
      for (int j = 0; j < 8; ++j) { hreg[0][j] = sm.a.hs[0][lane * 8 + j]; hreg[1][j] = sm.a.hs[1][lane * 8 + j]; }
    }
    for (int t = wave * 50; t < wave * 50 + 50; ++t) {
      if (t >= len) { if (lane == 0) { sm.a.sat[0][t] = -1e30f; sm.a.sat[1][t] = -1e30f; } continue; }
      float a0 = 0.f, a1 = 0.f;
      if (lane < 50) {
        bfrag ev = *(const bfrag*)(encb + ((size_t)b * T + t) * H + lane * 8);
#pragma unroll
        for (int j = 0; j < 8; ++j) {
          float e = bf2f((u16)ev[j]);
          a0 = fmaf(hreg[0][j], e, a0);
          a1 = fmaf(hreg[1][j], e, a1);
        }
      }
#pragma unroll
      for (int off = 32; off; off >>= 1) { a0 += __shfl_xor(a0, off); a1 += __shfl_xor(a1, off); }
      if (lane == 0) { sm.a.sat[0][t] = a0; sm.a.sat[1][t] = a1; }
    }
    __syncthreads();

    // phase 2: softmax
#pragma unroll
    for (int r = 0; r < 2; ++r) {
      float v = (tid < T) ? sm.a.sat[r][tid] : -1e30f;
      float wv = v;
#pragma unroll
      for (int off = 32; off; off >>= 1) wv = fmaxf(wv, __shfl_xor(wv, off));
      if (lane == 0) sm.a.red8[wave] = wv;
      __syncthreads();
      float mx = sm.a.red8[0];
#pragma unroll
      for (int j = 1; j < 8; ++j) mx = fmaxf(mx, sm.a.red8[j]);
      __syncthreads();
      float e = (tid < len) ? __expf(v - mx) : 0.f;
      float ws = e;
#pragma unroll
      for (int off = 32; off; off >>= 1) ws += __shfl_xor(ws, off);
      if (lane == 0) sm.a.red8[wave] = ws;
      __syncthreads();
      float smm = 0.f;
#pragma unroll
      for (int j = 0; j < 8; ++j) smm += sm.a.red8[j];
      float inv = 1.f / smm;
      __syncthreads();
      if (tid < T) {
        float av = e * inv;
        sm.a.sat[r][tid] = av;
        attnB[((size_t)s * M + mm[r]) * T + tid] = av;
      }
    }
    __syncthreads();

    // phase 3: context
    if (tid < H) {
      float c0 = 0.f, c1 = 0.f;
      const u16* eb = encb + (size_t)b * T * H + tid;
      for (int t = 0; t < len; ++t) {
        float ev = bf2f(eb[(size_t)t * H]);
        c0 = fmaf(sm.a.sat[0][t], ev, c0);
        c1 = fmaf(sm.a.sat[1][t], ev, c1);
      }
      sm.a.sctx[0][tid] = c0; sm.a.sctx[1][tid] = c1;
    }
    __syncthreads();

    // phase 4: p_gen / gates
    if (wave < 2) {
      const int r = wave, m = mm[r];
      float p = 0.f;
#pragma unroll
      for (int i = 0; i < 7; ++i) {
        int k = lane + 64 * i;
        if (k < H)
          p += sm.a.hs[r][k] * Wr[k] + sm.a.sctx[r][k] * Wr[H + k] + dec_s[m * H + k] * Wr[2 * H + k];
      }
#pragma unroll
      for (int off = 32; off; off >>= 1) p += __shfl_xor(p, off);
      if (lane == 0) pgenB[s * M + m] = sigm(p + br[0]);
    } else if (s == 0) {
      const int idx = wave - 2;
      const int r = idx / NG, g = idx % NG;
      float a = 0.f;
#pragma unroll
      for (int i = 0; i < 7; ++i) {
        int k = lane + 64 * i;
        if (k < H) a = fmaf(sm.a.sctx[r][k], Wg[g * H + k], a);
      }
#pragma unroll
      for (int off = 32; off; off >>= 1) a += __shfl_xor(a, off);
      if (lane == 0) out[PTS + (long long)mm[r] * NG + g] = a + bg[g];
    }
  }
}

// ---------------- k_merge: all (s,m) output rows ----------------
__global__ __launch_bounds__(512) void k_merge(
    const u16* __restrict__ ebuf, const float* __restrict__ pmax,
    const float* __restrict__ psum, const float* __restrict__ pgenB,
    const float* __restrict__ attnB, const int* __restrict__ story,
    float* __restrict__ out)
{
  const int bxi = blockIdx.x;
  const int s = bxi / M, m = bxi % M, b = m % B;
  const size_t R = (size_t)s * MP + m;
  const int tid = threadIdx.x;
  const int wave = tid >> 6, lane = tid & 63;
  __shared__ float fact[NBLK], red8[8];
  float pm = (tid < NBLK) ? pmax[R * NBLK + tid] : -1e30f;
  float wv = pm;
#pragma unroll
  for (int off = 32; off; off >>= 1) wv = fmaxf(wv, __shfl_xor(wv, off));
  if (lane == 0) red8[wave] = wv;
  __syncthreads();
  float Mx = red8[0];
#pragma unroll
  for (int j = 1; j < 8; ++j) Mx = fmaxf(Mx, red8[j]);
  __syncthreads();
  float sv = (tid < NBLK) ? psum[R * NBLK + tid] * __expf(pm - Mx) : 0.f;
  float ws = sv;
#pragma unroll
  for (int off = 32; off; off >>= 1) ws += __shfl_xor(ws, off);
  if (lane == 0) red8[wave] = ws;
  __syncthreads();
  float Sv = 0.f;
#pragma unroll
  for (int j = 0; j < 8; ++j) Sv += red8[j];
  const float pg = pgenB[s * M + m];
  const float scale = pg / Sv;
  if (tid < NBLK) fact[tid] = __expf(pm - Mx) * scale;
  __syncthreads();

  const u16* erow = ebuf + R * VP;
  float* orow = out + ((size_t)m * STEPS + s) * V;
  for (int v = tid; v < V; v += 512) orow[v] = bf2f(erow[v]) * fact[v >> 7];
  __syncthreads();
  const float om = 1.f - pg;
  for (int t = tid; t < T; t += 512) {
    float a = attnB[((size_t)s * M + m) * T + t];
    if (a != 0.f) atomicAdd(orow + story[b * T + t], om * a);
  }
}

// ---------------- launch ----------------

extern "C" void kernel_launch(void* const* d_in, const int* in_sizes, int n_in,
                              void* d_out, int out_size, void* d_ws, size_t ws_size,
                              hipStream_t stream) {
  (void)in_sizes; (void)n_in; (void)out_size; (void)ws_size;
  const float* emb  = (const float*)d_in[0];
  const float* Wih  = (const float*)d_in[1];
  const float* Whh  = (const float*)d_in[2];
  const float* bih  = (const float*)d_in[3];
  const float* bhh  = (const float*)d_in[4];
  const float* Wr   = (const float*)d_in[5];
  const float* br   = (const float*)d_in[6];
  const float* Wg   = (const float*)d_in[7];
  const float* bg   = (const float*)d_in[8];
  const float* semb = (const float*)d_in[9];
  const float* ehid = (const float*)d_in[10];
  const float* enc  = (const float*)d_in[11];
  const int*   lens = (const int*)d_in[12];
  const int*   story= (const int*)d_in[13];
  const int*   tgt  = (const int*)d_in[14];
  float* out = (float*)d_out;

  char* w = (char*)d_ws;
  size_t off = 0;
  auto alloc = [&](size_t n) -> void* {
    void* p = w + off;
    off = (off + n + 255) & ~(size_t)255;
    return p;
  };
  u16* ebf    = (u16*)alloc((size_t)VP * KP * 2);
  u16* wihH   = (u16*)alloc((size_t)NWP * KP * 2);
  u16* wihL   = (u16*)alloc((size_t)NWP * KP * 2);
  u16* whhH   = (u16*)alloc((size_t)NWP * KP * 2);
  u16* whhL   = (u16*)alloc((size_t)NWP * KP * 2);
  u16* decH   = (u16*)alloc((size_t)STEPS * MP * KP * 2);
  u16* decL   = (u16*)alloc((size_t)STEPS * MP * KP * 2);
  float* dec  = (float*)alloc((size_t)STEPS * M * H * 4);
  float* h0F  = (float*)alloc((size_t)M * H * 4);
  u16* h0H    = (u16*)alloc((size_t)MP * KP * 2);
  u16* h0L    = (u16*)alloc((size_t)MP * KP * 2);
  u16* hAllH  = (u16*)alloc((size_t)MR * KP * 2);
  u16* hAllL  = (u16*)alloc((size_t)MR * KP * 2);
  float* hallF= (float*)alloc((size_t)STEPS * M * H * 4);
  float* gi   = (float*)alloc((size_t)STEPS * MP * H3 * 4);
  float* gh   = (float*)alloc((size_t)M * H3 * 4);
  float* attnB= (float*)alloc((size_t)STEPS * M * T * 4);
  float* pgenB= (float*)alloc((size_t)STEPS * M * 4);
  u16* ebuf   = (u16*)alloc((size_t)MR * VP * 2);      // ~180 MB
  float* pmx  = (float*)alloc((size_t)MR * NBLK * 4);
  float* psm  = (float*)alloc((size_t)MR * NBLK * 4);
  u16* encb   = (u16*)alloc((size_t)B * T * H * 2);

  k_convert_emb<<<VP * KP / 256, 256, 0, stream>>>(emb, ebf);
  k_convert_enc<<<(B * T * H + 255) / 256, 256, 0, stream>>>(enc, encb);
  k_convert_w<<<NWP * KP / 256, 256, 0, stream>>>(Wih, Whh, wihH, wihL, whhH, whhL);
  k_init_dec<<<STEPS * MP * KP / 256, 256, 0, stream>>>(emb, semb, tgt, dec, decH, decL);
  k_init_h<<<MP * KP / 256, 256, 0, stream>>>(ehid, h0F, h0H, h0L);
  k_zero_pad<<<(STEPS * (MP - M) * KP + 255) / 256, 256, 0, stream>>>(hAllH, hAllL);
  // all-steps gi = dec @ Wih^T + bih
  k_gemm64s<<<dim3((H3 + 63) / 64, MR / 64), 256, 0, stream>>>(
      decH, decL, wihH, wihL, bih, gi, MR, H3, H3);

  // ---- serial GRU spine: 8x [gh GEMM + cell] ----
  for (int s = 0; s < STEPS; ++s) {
    const u16* pH = (s == 0) ? h0H : hAllH + (size_t)(s - 1) * MP * KP;
    const u16* pL = (s == 0) ? h0L : hAllL + (size_t)(s - 1) * MP * KP;
    const float* pF = (s == 0) ? h0F : hallF + (size_t)(s - 1) * M * H;
    k_gemm64s<<<dim3((H3 + 63) / 64, (M + 63) / 64), 256, 0, stream>>>(
        pH, pL, whhH, whhL, bhh, gh, M, H3, H3);
    k_cell<<<(M * H + 511) / 512, 512, 0, stream>>>(
        gi + (size_t)s * MP * H3, gh, pF,
        hallF + (size_t)s * M * H,
        hAllH + (size_t)s * MP * KP, hAllL + (size_t)s * MP * KP);
  }

  // ---- batched parallel phase ----
  k_big<<<NVB + NABT, 512, 0, stream>>>(
      hAllH, hallF, encb, lens, dec, Wr, br, Wg, bg, ebf,
      attnB, pgenB, ebuf, pmx, psm, out);
  k_merge<<<STEPS * M, 512, 0, stream>>>(ebuf, pmx, psm, pgenB, attnB, story, out);
}

// Round 8
// 646.621 us; speedup vs baseline: 3.6372x; 1.1702x over previous
//
#include <hip/hip_runtime.h>

#define DEV __device__ __forceinline__

constexpr int B = 16, T = 400, H = 400, V = 22000, S = 30, STEPS = 8, NG = 3;
constexpr int M  = S * B;      // 480 (slot,b) rows
constexpr int H3 = 3 * H;      // 1200
constexpr int KP = 416;        // K padded to 13*32
constexpr int VP = 22016;      // V padded to 172*128
constexpr int MP = 512;        // M padded (per step slot)
constexpr int MR = STEPS * MP; // 4096 batched rows for vocab GEMM
constexpr int NWP = 1280;      // GRU weight rows padded
constexpr int NBLK = VP / 128; // 172 vocab col-blocks
constexpr int NMP = MR / 256;  // 16 m-panels
constexpr int NVB = NBLK * NMP;// 2752 vocab blocks
constexpr int TPAD = 416;      // t/k padded for attn buffers
constexpr int PLD = 424;       // P_lds row stride (u16), +8 for bank spread
constexpr long long PTS = (long long)S * B * STEPS * V;  // 84,480,000

typedef __attribute__((ext_vector_type(8))) short bfrag;
typedef __attribute__((ext_vector_type(4))) float f32x4;
typedef unsigned short u16;

DEV u16 f2bf(float x) {
  unsigned u = __float_as_uint(x);
  u += 0x7FFFu + ((u >> 16) & 1u);
  return (u16)(u >> 16);
}
DEV float bf2f(u16 h) { return __uint_as_float(((unsigned)h) << 16); }
DEV float sigm(float x) { return 1.0f / (1.0f + __expf(-x)); }

DEV void gload16(const u16* g, u16* l) {
  __builtin_amdgcn_global_load_lds(
      (const __attribute__((address_space(1))) void*)g,
      (__attribute__((address_space(3))) void*)l, 16, 0, 0);
}

// ---------------- init / conversion ----------------

__global__ void k_convert_emb(const float* __restrict__ emb, u16* __restrict__ ebf) {
  int i = blockIdx.x * 256 + threadIdx.x;
  if (i >= VP * KP) return;
  int v = i / KP, k = i % KP;
  float val = (v < V && k < H) ? emb[(long long)v * H + k] : 0.f;
  ebf[i] = f2bf(val);
}

// encbK[b][t][k] (K-padded) and encT[b][k][t] (t-padded), both bf16
__global__ void k_build_enc(const float* __restrict__ enc,
                            u16* __restrict__ encbK, u16* __restrict__ encT) {
  int i = blockIdx.x * 256 + threadIdx.x;
  if (i >= B * 400 * TPAD) return;
  int c = i % TPAD, r = (i / TPAD) % 400, b = i / (TPAD * 400);
  float v1 = (c < H) ? enc[((size_t)b * T + r) * H + c] : 0.f;
  encbK[i] = f2bf(v1);
  float v2 = (c < T) ? enc[((size_t)b * T + c) * H + r] : 0.f;
  encT[i] = f2bf(v2);
}

__global__ void k_convert_w(const float* __restrict__ Wih, const float* __restrict__ Whh,
                            u16* __restrict__ wihH, u16* __restrict__ wihL,
                            u16* __restrict__ whhH, u16* __restrict__ whhL) {
  int i = blockIdx.x * 256 + threadIdx.x;
  if (i >= NWP * KP) return;
  int n = i / KP, k = i % KP;
  float v1 = (n < H3 && k < H) ? Wih[n * H + k] : 0.f;
  u16 h1 = f2bf(v1);
  wihH[i] = h1; wihL[i] = f2bf(v1 - bf2f(h1));
  float v2 = (n < H3 && k < H) ? Whh[n * H + k] : 0.f;
  u16 h2 = f2bf(v2);
  whhH[i] = h2; whhL[i] = f2bf(v2 - bf2f(h2));
}

__global__ void k_init_dec(const float* __restrict__ emb, const float* __restrict__ semb,
                           const int* __restrict__ tgt, float* __restrict__ dec,
                           u16* __restrict__ dH, u16* __restrict__ dL) {
  int i = blockIdx.x * 256 + threadIdx.x;
  if (i >= STEPS * MP * KP) return;
  int k = i % KP, m = (i / KP) % MP, s = i / (KP * MP);
  float val = 0.f;
  if (m < M && k < H) {
    int slot = m / B, b = m % B;
    if (s == 0) val = semb[slot * H + k];
    else        val = emb[(long long)tgt[(b * S + slot) * STEPS + (s - 1)] * H + k];
    dec[((long long)s * M + m) * H + k] = val;
  }
  u16 hi = f2bf(val);
  dH[i] = hi; dL[i] = f2bf(val - bf2f(hi));
}

__global__ void k_init_h(const float* __restrict__ ehid, float* __restrict__ h0F,
                         u16* __restrict__ hH, u16* __restrict__ hL) {
  int i = blockIdx.x * 256 + threadIdx.x;
  if (i >= MP * KP) return;
  int k = i % KP, m = i / KP;
  float val = (m < M && k < H) ? ehid[(m % B) * H + k] : 0.f;
  if (m < M && k < H) h0F[m * H + k] = val;
  u16 hi = f2bf(val);
  hH[i] = hi; hL[i] = f2bf(val - bf2f(hi));
}

__global__ void k_zero_pad(u16* __restrict__ hAllH, u16* __restrict__ hAllL) {
  int i = blockIdx.x * 256 + threadIdx.x;
  if (i >= STEPS * (MP - M) * KP) return;
  int k = i % KP;
  int row = M + (i / KP) % (MP - M);
  int s = i / (KP * (MP - M));
  size_t idx = ((size_t)s * MP + row) * KP + k;
  hAllH[idx] = 0; hAllL[idx] = 0;
}

// ---------------- 64x64-tile SPLIT GEMM (gi batched, gh per step) ----------------
__global__ __launch_bounds__(256) void k_gemm64s(
    const u16* __restrict__ Ahi, const u16* __restrict__ Alo,
    const u16* __restrict__ Bmh, const u16* __restrict__ Bml,
    const float* __restrict__ bias, float* __restrict__ C,
    int Mvalid, int Nvalid, int Cstride)
{
  __shared__ u16 BsH[64 * 32], BsL[64 * 32];
  const int tid = threadIdx.x;
  const int wave = tid >> 6, lane = tid & 63;
  const int wm = wave >> 1, wn = wave & 1;
  const int n0 = blockIdx.x * 64;
  const int m0 = blockIdx.y * 64;
  const int lrow = lane & 15;
  const int c16 = lane >> 4;
  const int srow = tid >> 2;
  const int sg = (tid & 3) ^ (srow & 3);
  f32x4 acc[2][2] = {};

  const u16* aH = Ahi + (size_t)(m0 + wm * 32 + lrow) * KP + c16 * 8;
  const u16* aL = Alo + (size_t)(m0 + wm * 32 + lrow) * KP + c16 * 8;
  const u16* bHs = Bmh + (size_t)(n0 + srow) * KP + sg * 8;
  const u16* bLs = Bml + (size_t)(n0 + srow) * KP + sg * 8;
  u16* lBH = BsH + wave * 512;
  u16* lBL = BsL + wave * 512;

  for (int kk = 0; kk < KP / 32; ++kk) {
    const int kb = kk * 32;
    gload16(bHs + kb, lBH);
    gload16(bLs + kb, lBL);
    __syncthreads();
    bfrag a0h = *(const bfrag*)(aH + kb);
    bfrag a1h = *(const bfrag*)(aH + 16 * KP + kb);
    bfrag a0l = *(const bfrag*)(aL + kb);
    bfrag a1l = *(const bfrag*)(aL + 16 * KP + kb);
#pragma unroll
    for (int nn = 0; nn < 2; ++nn) {
      const int br = wn * 32 + nn * 16 + lrow;
      const int goff = br * 32 + ((c16 ^ (br & 3)) << 3);
      bfrag bh = *(const bfrag*)&BsH[goff];
      bfrag bl = *(const bfrag*)&BsL[goff];
      acc[0][nn] = __builtin_amdgcn_mfma_f32_16x16x32_bf16(a0h, bh, acc[0][nn], 0, 0, 0);
      acc[1][nn] = __builtin_amdgcn_mfma_f32_16x16x32_bf16(a1h, bh, acc[1][nn], 0, 0, 0);
      acc[0][nn] = __builtin_amdgcn_mfma_f32_16x16x32_bf16(a0h, bl, acc[0][nn], 0, 0, 0);
      acc[1][nn] = __builtin_amdgcn_mfma_f32_16x16x32_bf16(a1h, bl, acc[1][nn], 0, 0, 0);
      acc[0][nn] = __builtin_amdgcn_mfma_f32_16x16x32_bf16(a0l, bh, acc[0][nn], 0, 0, 0);
      acc[1][nn] = __builtin_amdgcn_mfma_f32_16x16x32_bf16(a1l, bh, acc[1][nn], 0, 0, 0);
    }
    __syncthreads();
  }
  const int orow = (lane >> 4) << 2, ocol = lane & 15;
#pragma unroll
  for (int am = 0; am < 2; ++am) {
#pragma unroll
    for (int nn = 0; nn < 2; ++nn) {
      const int gn = n0 + wn * 32 + nn * 16 + ocol;
      if (gn >= Nvalid) continue;
      const float badd = bias[gn];
#pragma unroll
      for (int r = 0; r < 4; ++r) {
        const int gm = m0 + wm * 32 + am * 16 + orow + r;
        if (gm < Mvalid) C[(long long)gm * Cstride + gn] = acc[am][nn][r] + badd;
      }
    }
  }
}

// ---------------- GRU cell ----------------
__global__ __launch_bounds__(512) void k_cell(const float* __restrict__ gi_s,
                                              const float* __restrict__ gh,
                                              const float* __restrict__ hprevF,
                                              float* __restrict__ hcurF,
                                              u16* __restrict__ hHc, u16* __restrict__ hLc) {
  int i = blockIdx.x * 512 + threadIdx.x;
  if (i >= M * H) return;
  int k = i % H, m = i / H;
  float ir = gi_s[m * H3 + k],         hr = gh[m * H3 + k];
  float iz = gi_s[m * H3 + H + k],     hz = gh[m * H3 + H + k];
  float in_ = gi_s[m * H3 + 2*H + k],  hn = gh[m * H3 + 2*H + k];
  float rr = sigm(ir + hr);
  float z = sigm(iz + hz);
  float n = tanhf(in_ + rr * hn);
  float hv = (1.f - z) * n + z * hprevF[i];
  hcurF[i] = hv;
  u16 hb = f2bf(hv);
  hHc[m * KP + k] = hb;
  hLc[m * KP + k] = f2bf(hv - bf2f(hb));
}

// ---------------- k_attn: MFMA attention, one block per (s,b) ----------------
// GEMM-1: logits[32m][400t] = h(hi/lo) x encbK^T ; softmax ; GEMM-2: ctx = P x encT^T
struct SMatt {
  u16 P[32 * PLD];               // bf16 P tile (27.1 KB)
  float partm[32][4];
  float parts[32][4];
  float rowred[32];
  float part2[32][4][4];         // [row][wavegroup][pgen,g0,g1,g2]
};

__global__ __launch_bounds__(512) void k_attn(
    const u16* __restrict__ hAllH, const u16* __restrict__ hAllL,
    const float* __restrict__ hallF,
    const u16* __restrict__ encbK, const u16* __restrict__ encT,
    const int* __restrict__ lens, const float* __restrict__ dec,
    const float* __restrict__ Wr, const float* __restrict__ br,
    const float* __restrict__ Wg, const float* __restrict__ bg,
    float* __restrict__ attnB, float* __restrict__ pgenB, float* __restrict__ out)
{
  __shared__ SMatt sm;
  const int s = blockIdx.x >> 4;
  const int b = blockIdx.x & 15;
  const int tid = threadIdx.x;
  const int wave = tid >> 6, lane = tid & 63;
  const int mt = wave & 1;              // m-tile (rows mt*16..mt*16+15)
  const int wg = wave >> 1;             // tile-group 0..3
  const int lrow = lane & 15;
  const int c16 = lane >> 4;
  const int len = lens[b];
  const int rbase = mt * 16 + c16 * 4;  // C-frag row base for this lane

  // zero P_lds t-pad cols [400,424) -- NaN safety for GEMM-2 A reads
  for (int idx = tid; idx < 32 * 24; idx += 512)
    sm.P[(idx / 24) * PLD + 400 + (idx % 24)] = 0;

  // ---- GEMM-1: logits ----
  f32x4 acc[7] = {};
  {
    const size_t arow = (size_t)s * MP + (size_t)(mt * 16 + lrow) * B + b;
    const u16* aHp = hAllH + arow * KP + c16 * 8;
    const u16* aLp = hAllL + arow * KP + c16 * 8;
    const u16* bBase = encbK + (size_t)b * 400 * TPAD + c16 * 8;
    for (int kk = 0; kk < 13; ++kk) {
      bfrag ah = *(const bfrag*)(aHp + kk * 32);
      bfrag al = *(const bfrag*)(aLp + kk * 32);
#pragma unroll
      for (int i = 0; i < 7; ++i) {
        const int jt = wg + 4 * i;
        if (jt < 25) {
          bfrag bv = *(const bfrag*)(bBase + (size_t)(jt * 16 + lrow) * TPAD + kk * 32);
          acc[i] = __builtin_amdgcn_mfma_f32_16x16x32_bf16(ah, bv, acc[i], 0, 0, 0);
          acc[i] = __builtin_amdgcn_mfma_f32_16x16x32_bf16(al, bv, acc[i], 0, 0, 0);
        }
      }
    }
  }

  // ---- softmax over t ----
  {
    float pm[4] = {-1e30f, -1e30f, -1e30f, -1e30f};
#pragma unroll
    for (int i = 0; i < 7; ++i) {
      const int jt = wg + 4 * i;
      if (jt >= 25) continue;
      const int t = jt * 16 + lrow;
      const bool ok = t < len;
#pragma unroll
      for (int rr = 0; rr < 4; ++rr) pm[rr] = fmaxf(pm[rr], ok ? acc[i][rr] : -1e30f);
    }
#pragma unroll
    for (int d = 1; d < 16; d <<= 1) {
#pragma unroll
      for (int rr = 0; rr < 4; ++rr) pm[rr] = fmaxf(pm[rr], __shfl_xor(pm[rr], d));
    }
    if (lrow == 0) {
#pragma unroll
      for (int rr = 0; rr < 4; ++rr) sm.partm[rbase + rr][wg] = pm[rr];
    }
  }
  __syncthreads();
  if (tid < 32)
    sm.rowred[tid] = fmaxf(fmaxf(sm.partm[tid][0], sm.partm[tid][1]),
                           fmaxf(sm.partm[tid][2], sm.partm[tid][3]));
  __syncthreads();
  float Mx[4];
#pragma unroll
  for (int rr = 0; rr < 4; ++rr) Mx[rr] = sm.rowred[rbase + rr];
  {
    float ps[4] = {0.f, 0.f, 0.f, 0.f};
#pragma unroll
    for (int i = 0; i < 7; ++i) {
      const int jt = wg + 4 * i;
      if (jt >= 25) continue;
      const int t = jt * 16 + lrow;
      const bool ok = t < len;
#pragma unroll
      for (int rr = 0; rr < 4; ++rr) {
        float e = ok ? __expf(acc[i][rr] - Mx[rr]) : 0.f;
        acc[i][rr] = e;
        ps[rr] += e;
      }
    }
#pragma unroll
    for (int d = 1; d < 16; d <<= 1) {
#pragma unroll
      for (int rr = 0; rr < 4; ++rr) ps[rr] += __shfl_xor(ps[rr], d);
    }
    if (lrow == 0) {
#pragma unroll
      for (int rr = 0; rr < 4; ++rr) sm.parts[rbase + rr][wg] = ps[rr];
    }
  }
  __syncthreads();
  if (tid < 32)
    sm.rowred[tid] = sm.parts[tid][0] + sm.parts[tid][1] + sm.parts[tid][2] + sm.parts[tid][3];
  __syncthreads();
  {
    float inv[4];
#pragma unroll
    for (int rr = 0; rr < 4; ++rr) inv[rr] = 1.f / sm.rowred[rbase + rr];
#pragma unroll
    for (int i = 0; i < 7; ++i) {
      const int jt = wg + 4 * i;
      if (jt >= 25) continue;
      const int t = jt * 16 + lrow;
#pragma unroll
      for (int rr = 0; rr < 4; ++rr) {
        const int row = rbase + rr;
        const float p = acc[i][rr] * inv[rr];
        sm.P[row * PLD + t] = f2bf(p);
        if (row < 30) attnB[((size_t)s * M + row * B + b) * T + t] = p;
      }
    }
  }
  __syncthreads();

  // ---- GEMM-2: ctx = P x encT^T, consumed directly into p_gen/gate partials ----
  f32x4 acc2[7] = {};
  {
    const u16* bBase = encT + (size_t)b * 400 * TPAD + c16 * 8;
    const u16* aP = sm.P + (mt * 16 + lrow) * PLD + c16 * 8;
    for (int kk = 0; kk < 13; ++kk) {
      bfrag ap = *(const bfrag*)(aP + kk * 32);
#pragma unroll
      for (int i = 0; i < 7; ++i) {
        const int jk = wg + 4 * i;
        if (jk < 25) {
          bfrag bv = *(const bfrag*)(bBase + (size_t)(jk * 16 + lrow) * TPAD + kk * 32);
          acc2[i] = __builtin_amdgcn_mfma_f32_16x16x32_bf16(ap, bv, acc2[i], 0, 0, 0);
        }
      }
    }
  }
  {
    float pw[4] = {0.f, 0.f, 0.f, 0.f};
    float pg0[4] = {0.f, 0.f, 0.f, 0.f};
    float pg1[4] = {0.f, 0.f, 0.f, 0.f};
    float pg2[4] = {0.f, 0.f, 0.f, 0.f};
    const bool do_g = (s == 0);
#pragma unroll
    for (int i = 0; i < 7; ++i) {
      const int jk = wg + 4 * i;
      if (jk >= 25) continue;
      const int k = jk * 16 + lrow;
      const float wr = Wr[H + k];
      float w0 = 0.f, w1 = 0.f, w2 = 0.f;
      if (do_g) { w0 = Wg[k]; w1 = Wg[H + k]; w2 = Wg[2 * H + k]; }
#pragma unroll
      for (int rr = 0; rr < 4; ++rr) {
        const float v = acc2[i][rr];
        pw[rr] = fmaf(v, wr, pw[rr]);
        if (do_g) {
          pg0[rr] = fmaf(v, w0, pg0[rr]);
          pg1[rr] = fmaf(v, w1, pg1[rr]);
          pg2[rr] = fmaf(v, w2, pg2[rr]);
        }
      }
    }
#pragma unroll
    for (int d = 1; d < 16; d <<= 1) {
#pragma unroll
      for (int rr = 0; rr < 4; ++rr) {
        pw[rr] += __shfl_xor(pw[rr], d);
        pg0[rr] += __shfl_xor(pg0[rr], d);
        pg1[rr] += __shfl_xor(pg1[rr], d);
        pg2[rr] += __shfl_xor(pg2[rr], d);
      }
    }
    if (lrow == 0) {
#pragma unroll
      for (int rr = 0; rr < 4; ++rr) {
        sm.part2[rbase + rr][wg][0] = pw[rr];
        sm.part2[rbase + rr][wg][1] = pg0[rr];
        sm.part2[rbase + rr][wg][2] = pg1[rr];
        sm.part2[rbase + rr][wg][3] = pg2[rr];
      }
    }
  }
  __syncthreads();

  // ---- p_gen (+gates at s==0) ----
  if (tid < 480) {
    const int row = tid >> 4;          // 0..29
    const int l16 = tid & 15;
    const int m = row * B + b;
    const float* hF = hallF + ((size_t)s * M + m) * H;
    const float* dF = dec + ((size_t)s * M + m) * H;
    float p = 0.f;
    for (int j = 0; j < 25; ++j) {
      const int k = l16 + 16 * j;
      p += hF[k] * Wr[k] + dF[k] * Wr[2 * H + k];
    }
#pragma unroll
    for (int d = 1; d < 16; d <<= 1) p += __shfl_xor(p, d);
    if (l16 == 0) {
      float cw = sm.part2[row][0][0] + sm.part2[row][1][0] +
                 sm.part2[row][2][0] + sm.part2[row][3][0];
      pgenB[s * M + m] = sigm(p + cw + br[0]);
    }
    if (s == 0 && l16 < NG) {
      float gv = sm.part2[row][0][1 + l16] + sm.part2[row][1][1 + l16] +
                 sm.part2[row][2][1 + l16] + sm.part2[row][3][1 + l16];
      out[PTS + (long long)m * NG + l16] = gv + bg[l16];
    }
  }
}

// ---------------- k_vocab: batched vocab GEMM (all steps), 256x128 tiles ----------------
__global__ __launch_bounds__(512) void k_vocab(
    const u16* __restrict__ hAllH, const u16* __restrict__ ebf,
    u16* __restrict__ ebuf, float* __restrict__ pmax, float* __restrict__ psum)
{
  __shared__ u16 Bs[2 * 4096];
  __shared__ float lpm[256][2], lps[256][2], bmax[256];
  const int bx = blockIdx.x;
  const int tid = threadIdx.x;
  const int wave = tid >> 6, lane = tid & 63;
  const int bxs = (bx & 7) * (NVB / 8) + (bx >> 3);   // bijective XCD swizzle
  const int nb = bxs / NMP;
  const int mp = bxs % NMP;
  const int n0 = nb * 128;
  const int m0 = mp * 256;
  const int wm = wave >> 1, wn = wave & 1;
  const int lrow = lane & 15;
  const int c16 = lane >> 4;
  const int srow = tid >> 2;
  const int sg = (tid & 3) ^ (srow & 3);
  f32x4 acc[4][4] = {};

  const u16* aBase = hAllH + (size_t)(m0 + wm * 64 + lrow) * KP + c16 * 8;
  const u16* bS = ebf + (size_t)(n0 + srow) * KP + sg * 8;
  u16* lB0 = Bs + wave * 512;
  u16* lB1 = Bs + 4096 + wave * 512;

  gload16(bS, lB0);
  int cur = 0;
#pragma unroll 1
  for (int kk = 0; kk < 13; ++kk) {
    bfrag af0 = *(const bfrag*)(aBase + 0 * 16 * KP + kk * 32);
    bfrag af1 = *(const bfrag*)(aBase + 1 * 16 * KP + kk * 32);
    bfrag af2 = *(const bfrag*)(aBase + 2 * 16 * KP + kk * 32);
    bfrag af3 = *(const bfrag*)(aBase + 3 * 16 * KP + kk * 32);
    if (kk < 12) {
      gload16(bS + (kk + 1) * 32, cur ? lB0 : lB1);
      asm volatile("s_waitcnt vmcnt(5)" ::: "memory");
    } else {
      asm volatile("s_waitcnt vmcnt(4)" ::: "memory");
    }
    __builtin_amdgcn_sched_barrier(0);
    __builtin_amdgcn_s_barrier();
    const u16* Bb = Bs + (cur ? 4096 : 0);
    bfrag bfv[4];
#pragma unroll
    for (int nn = 0; nn < 4; ++nn) {
      const int brr = wn * 64 + nn * 16 + lrow;
      bfv[nn] = *(const bfrag*)&Bb[brr * 32 + ((c16 ^ (brr & 3)) << 3)];
    }
#pragma unroll
    for (int nn = 0; nn < 4; ++nn) {
      acc[0][nn] = __builtin_amdgcn_mfma_f32_16x16x32_bf16(af0, bfv[nn], acc[0][nn], 0, 0, 0);
      acc[1][nn] = __builtin_amdgcn_mfma_f32_16x16x32_bf16(af1, bfv[nn], acc[1][nn], 0, 0, 0);
      acc[2][nn] = __builtin_amdgcn_mfma_f32_16x16x32_bf16(af2, bfv[nn], acc[2][nn], 0, 0, 0);
      acc[3][nn] = __builtin_amdgcn_mfma_f32_16x16x32_bf16(af3, bfv[nn], acc[3][nn], 0, 0, 0);
    }
    __builtin_amdgcn_sched_barrier(0);
    __builtin_amdgcn_s_barrier();
    cur ^= 1;
  }
  __syncthreads();

  const int orow = (lane >> 4) << 2, ocol = lane & 15;
#pragma unroll
  for (int af_i = 0; af_i < 4; ++af_i) {
#pragma unroll
    for (int r = 0; r < 4; ++r) {
      float mxv = -1e30f;
#pragma unroll
      for (int nn = 0; nn < 4; ++nn) {
        const int gn = n0 + wn * 64 + nn * 16 + ocol;
        if (gn < V) mxv = fmaxf(mxv, acc[af_i][nn][r]);
      }
#pragma unroll
      for (int d = 1; d < 16; d <<= 1) mxv = fmaxf(mxv, __shfl_xor(mxv, d));
      if ((lane & 15) == 0) lpm[wm * 64 + af_i * 16 + orow + r][wn] = mxv;
    }
  }
  __syncthreads();
  if (tid < 256) bmax[tid] = fmaxf(lpm[tid][0], lpm[tid][1]);
  __syncthreads();
#pragma unroll
  for (int af_i = 0; af_i < 4; ++af_i) {
#pragma unroll
    for (int r = 0; r < 4; ++r) {
      const int rl = wm * 64 + af_i * 16 + orow + r;
      const int R = m0 + rl;
      const bool ok = (R % MP) < M;
      const float bm = bmax[rl];
      float se = 0.f;
#pragma unroll
      for (int nn = 0; nn < 4; ++nn) {
        const int gn = n0 + wn * 64 + nn * 16 + ocol;
        if (gn < V) {
          float e = __expf(acc[af_i][nn][r] - bm);
          se += e;
          if (ok) ebuf[(size_t)R * VP + gn] = f2bf(e);
        }
      }
#pragma unroll
      for (int d = 1; d < 16; d <<= 1) se += __shfl_xor(se, d);
      if ((lane & 15) == 0) lps[rl][wn] = se;
    }
  }
  __syncthreads();
  if (tid < 256) {
    const int R = m0 + tid;
    if ((R % MP) < M) {
      pmax[(size_t)R * NBLK + nb] = bmax[tid];
      psum[(size_t)R * NBLK + nb] = lps[tid][0] + lps[tid][1];
    }
  }
}

// ---------------- k_merge: all (s,m) output rows ----------------
__global__ __launch_bounds__(512) void k_merge(
    const u16* __restrict__ ebuf, const float* __restrict__ pmax,
    const float* __restrict__ psum, const float* __restrict__ pgenB,
    const float* __restrict__ attnB, const int* __restrict__ story,
    float* __restrict__ out)
{
  const int bxi = blockIdx.x;
  const int s = bxi / M, m = bxi % M, b = m % B;
  const size_t R = (size_t)s * MP + m;
  const int tid = threadIdx.x;
  const int wave = tid >> 6, lane = tid & 63;
  __shared__ float fact[NBLK], red8[8];
  float pm = (tid < NBLK) ? pmax[R * NBLK + tid] : -1e30f;
  float wv = pm;
#pragma unroll
  for (int off = 32; off; off >>= 1) wv = fmaxf(wv, __shfl_xor(wv, off));
  if (lane == 0) red8[wave] = wv;
  __syncthreads();
  float Mx = red8[0];
#pragma unroll
  for (int j = 1; j < 8; ++j) Mx = fmaxf(Mx, red8[j]);
  __syncthreads();
  float sv = (tid < NBLK) ? psum[R * NBLK + tid] * __expf(pm - Mx) : 0.f;
  float ws = sv;
#pragma unroll
  for (int off = 32; off; off >>= 1) ws += __shfl_xor(ws, off);
  if (lane == 0) red8[wave] = ws;
  __syncthreads();
  float Sv = 0.f;
#pragma unroll
  for (int j = 0; j < 8; ++j) Sv += red8[j];
  const float pg = pgenB[s * M + m];
  const float scale = pg / Sv;
  if (tid < NBLK) fact[tid] = __expf(pm - Mx) * scale;
  __syncthreads();

  const u16* erow = ebuf + R * VP;
  float* orow = out + ((size_t)m * STEPS + s) * V;
  for (int v = tid; v < V; v += 512) orow[v] = bf2f(erow[v]) * fact[v >> 7];
  __syncthreads();
  const float om = 1.f - pg;
  for (int t = tid; t < T; t += 512) {
    float a = attnB[((size_t)s * M + m) * T + t];
    if (a != 0.f) atomicAdd(orow + story[b * T + t], om * a);
  }
}

// ---------------- launch ----------------

extern "C" void kernel_launch(void* const* d_in, const int* in_sizes, int n_in,
                              void* d_out, int out_size, void* d_ws, size_t ws_size,
                              hipStream_t stream) {
  (void)in_sizes; (void)n_in; (void)out_size; (void)ws_size;
  const float* emb  = (const float*)d_in[0];
  const float* Wih  = (const float*)d_in[1];
  const float* Whh  = (const float*)d_in[2];
  const float* bih  = (const float*)d_in[3];
  const float* bhh  = (const float*)d_in[4];
  const float* Wr   = (const float*)d_in[5];
  const float* br   = (const float*)d_in[6];
  const float* Wg   = (const float*)d_in[7];
  const float* bg   = (const float*)d_in[8];
  const float* semb = (const float*)d_in[9];
  const float* ehid = (const float*)d_in[10];
  const float* enc  = (const float*)d_in[11];
  const int*   lens = (const int*)d_in[12];
  const int*   story= (const int*)d_in[13];
  const int*   tgt  = (const int*)d_in[14];
  float* out = (float*)d_out;

  char* w = (char*)d_ws;
  size_t off = 0;
  auto alloc = [&](size_t n) -> void* {
    void* p = w + off;
    off = (off + n + 255) & ~(size_t)255;
    return p;
  };
  u16* ebf    = (u16*)alloc((size_t)VP * KP * 2);
  u16* wihH   = (u16*)alloc((size_t)NWP * KP * 2);
  u16* wihL   = (u16*)alloc((size_t)NWP * KP * 2);
  u16* whhH   = (u16*)alloc((size_t)NWP * KP * 2);
  u16* whhL   = (u16*)alloc((size_t)NWP * KP * 2);
  u16* decH   = (u16*)alloc((size_t)STEPS * MP * KP * 2);
  u16* decL   = (u16*)alloc((size_t)STEPS * MP * KP * 2);
  float* dec  = (float*)alloc((size_t)STEPS * M * H * 4);
  float* h0F  = (float*)alloc((size_t)M * H * 4);
  u16* h0H    = (u16*)alloc((size_t)MP * KP * 2);
  u16* h0L    = (u16*)alloc((size_t)MP * KP * 2);
  u16* hAllH  = (u16*)alloc((size_t)MR * KP * 2);
  u16* hAllL  = (u16*)alloc((size_t)MR * KP * 2);
  float* hallF= (float*)alloc((size_t)STEPS * M * H * 4);
  float* gi   = (float*)alloc((size_t)STEPS * MP * H3 * 4);
  float* gh   = (float*)alloc((size_t)M * H3 * 4);
  float* attnB= (float*)alloc((size_t)STEPS * M * T * 4);
  float* pgenB= (float*)alloc((size_t)STEPS * M * 4);
  u16* ebuf   = (u16*)alloc((size_t)MR * VP * 2);      // ~180 MB
  float* pmx  = (float*)alloc((size_t)MR * NBLK * 4);
  float* psm  = (float*)alloc((size_t)MR * NBLK * 4);
  u16* encbK  = (u16*)alloc((size_t)B * 400 * TPAD * 2);
  u16* encT   = (u16*)alloc((size_t)B * 400 * TPAD * 2);

  k_convert_emb<<<VP * KP / 256, 256, 0, stream>>>(emb, ebf);
  k_build_enc<<<(B * 400 * TPAD + 255) / 256, 256, 0, stream>>>(enc, encbK, encT);
  k_convert_w<<<NWP * KP / 256, 256, 0, stream>>>(Wih, Whh, wihH, wihL, whhH, whhL);
  k_init_dec<<<STEPS * MP * KP / 256, 256, 0, stream>>>(emb, semb, tgt, dec, decH, decL);
  k_init_h<<<MP * KP / 256, 256, 0, stream>>>(ehid, h0F, h0H, h0L);
  k_zero_pad<<<(STEPS * (MP - M) * KP + 255) / 256, 256, 0, stream>>>(hAllH, hAllL);
  k_gemm64s<<<dim3((H3 + 63) / 64, MR / 64), 256, 0, stream>>>(
      decH, decL, wihH, wihL, bih, gi, MR, H3, H3);

  // serial GRU spine
  for (int s = 0; s < STEPS; ++s) {
    const u16* pH = (s == 0) ? h0H : hAllH + (size_t)(s - 1) * MP * KP;
    const u16* pL = (s == 0) ? h0L : hAllL + (size_t)(s - 1) * MP * KP;
    const float* pF = (s == 0) ? h0F : hallF + (size_t)(s - 1) * M * H;
    k_gemm64s<<<dim3((H3 + 63) / 64, (M + 63) / 64), 256, 0, stream>>>(
        pH, pL, whhH, whhL, bhh, gh, M, H3, H3);
    k_cell<<<(M * H + 511) / 512, 512, 0, stream>>>(
        gi + (size_t)s * MP * H3, gh, pF,
        hallF + (size_t)s * M * H,
        hAllH + (size_t)s * MP * KP, hAllL + (size_t)s * MP * KP);
  }

  // batched parallel phase
  k_attn<<<STEPS * B, 512, 0, stream>>>(hAllH, hAllL, hallF, encbK, encT, lens,
                                        dec, Wr, br, Wg, bg, attnB, pgenB, out);
  k_vocab<<<NVB, 512, 0, stream>>>(hAllH, ebf, ebuf, pmx, psm);
  k_merge<<<STEPS * M, 512, 0, stream>>>(ebuf, pmx, psm, pgenB, attnB, story, out);
}